// Round 2
// baseline (12058.107 us; speedup 1.0000x reference)
//
#include <hip/hip_runtime.h>
#include <hip/hip_bf16.h>

// Problem constants
#define N_ 20000
#define E_ 320000
#define G_ 128
#define H_ 4
#define C_ 64
#define D_ 256
#define ED_ 64
#define L_ 4
#define EN_TOT (E_ + N_)   // edges + self loops
#define KEDGE (2*D_ + ED_) // 576

#define TBM 64
#define TBN 64
#define TBK 32

// ---------------- encoders ----------------
__global__ __launch_bounds__(256) void atom_enc(const float* __restrict__ x,
                                                const float* __restrict__ W,
                                                const float* __restrict__ b,
                                                float* __restrict__ h) {
    int n = blockIdx.x, t = threadIdx.x;
    float acc = b[t];
#pragma unroll
    for (int k = 0; k < 9; ++k) acc += x[n * 9 + k] * W[k * D_ + t];
    h[(size_t)n * D_ + t] = acc;
}

__global__ __launch_bounds__(256) void bond_enc(const float* __restrict__ ea,
                                                const float* __restrict__ W,
                                                const float* __restrict__ b,
                                                float* __restrict__ e) {
    int idx = blockIdx.x * 256 + threadIdx.x;
    if (idx >= E_ * ED_) return;
    int ed = idx >> 6, j = idx & 63;
    float acc = b[j];
#pragma unroll
    for (int k = 0; k < 3; ++k) acc += ea[ed * 3 + k] * W[k * ED_ + j];
    e[idx] = acc;
}

// ---------------- degree + self-loop edge attr ----------------
__global__ __launch_bounds__(256) void deg_loop_kernel(const float* __restrict__ e,
                                                       const int* __restrict__ dst,
                                                       float* __restrict__ loop_e,
                                                       float* __restrict__ cnt) {
    int idx = blockIdx.x * 256 + threadIdx.x;
    if (idx >= E_ * ED_) return;
    int ed = idx >> 6, j = idx & 63;
    int dn = dst[ed];
    atomicAdd(&loop_e[(size_t)dn * ED_ + j], e[idx]);
    if (j == 0) atomicAdd(&cnt[dn], 1.f);
}

__global__ __launch_bounds__(256) void loop_div_kernel(float* __restrict__ loop_e,
                                                       const float* __restrict__ cnt) {
    int idx = blockIdx.x * 256 + threadIdx.x;
    if (idx >= N_ * ED_) return;
    loop_e[idx] /= fmaxf(cnt[idx >> 6], 1.f);
}

// ---------------- generic tiled f32 GEMM: C = A @ B + bias ----------------
struct DenseA {
    const float* A; int K;
    __device__ float operator()(int r, int k) const { return A[(size_t)r * K + k]; }
};
struct JkA {
    const float* outs;
    __device__ float operator()(int r, int k) const {
        return outs[(size_t)(k >> 8) * N_ * D_ + (size_t)r * D_ + (k & 255)];
    }
};

template <typename AFetch>
__global__ __launch_bounds__(256) void gemm64(AFetch af, const float* __restrict__ B,
                                              const float* __restrict__ bias,
                                              float* __restrict__ C,
                                              int M, int K, int Nn) {
    __shared__ float As[TBK][TBM + 1];
    __shared__ float Bs[TBK][TBN];
    int t = threadIdx.x;
    int bm = blockIdx.x * TBM;
    int bn = blockIdx.y * TBN;
    int tx = t & 15, ty = t >> 4;
    float acc[4][4] = {};
    for (int k0 = 0; k0 < K; k0 += TBK) {
#pragma unroll
        for (int i = 0; i < 8; ++i) {
            int lid = t + 256 * i;
            int r = lid >> 5, kk = lid & 31;
            int row = bm + r;
            As[kk][r] = (row < M) ? af(row, k0 + kk) : 0.f;
        }
#pragma unroll
        for (int i = 0; i < 8; ++i) {
            int lid = t + 256 * i;
            int kk = lid >> 6, c = lid & 63;
            Bs[kk][c] = B[(size_t)(k0 + kk) * Nn + (bn + c)];
        }
        __syncthreads();
#pragma unroll
        for (int kk = 0; kk < TBK; ++kk) {
            float a[4], b[4];
#pragma unroll
            for (int i = 0; i < 4; ++i) a[i] = As[kk][ty * 4 + i];
#pragma unroll
            for (int j = 0; j < 4; ++j) b[j] = Bs[kk][tx * 4 + j];
#pragma unroll
            for (int i = 0; i < 4; ++i)
#pragma unroll
                for (int j = 0; j < 4; ++j) acc[i][j] += a[i] * b[j];
        }
        __syncthreads();
    }
#pragma unroll
    for (int i = 0; i < 4; ++i) {
        int row = bm + ty * 4 + i;
        if (row >= M) continue;
#pragma unroll
        for (int j = 0; j < 4; ++j) {
            int col = bn + tx * 4 + j;
            C[(size_t)row * Nn + col] = acc[i][j] + bias[col];
        }
    }
}

// ---------------- fused edge GEMM + silu + LN (in-place into e) ----------------
// A = [hn[src] | hn[dst] | e] (E x 576), B = eW (576 x 64). Each block owns 64
// complete rows, so the row-LN is block-local and the in-place write to e is
// safe: only this block reads its own e rows, and all reads precede the writes.
__global__ __launch_bounds__(256) void edge_gemm_fused(const float* __restrict__ hn,
                                                       float* __restrict__ e,
                                                       const int* __restrict__ src,
                                                       const int* __restrict__ dst,
                                                       const float* __restrict__ B,
                                                       const float* __restrict__ bias,
                                                       const float* __restrict__ gs,
                                                       const float* __restrict__ gb) {
    __shared__ float As[TBK][TBM + 1];
    __shared__ float Bs[TBK][TBN];
    int t = threadIdx.x;
    int bm = blockIdx.x * TBM;  // E_ % 64 == 0, no tail
    int tx = t & 15, ty = t >> 4;
    float acc[4][4] = {};
    for (int k0 = 0; k0 < KEDGE; k0 += TBK) {
#pragma unroll
        for (int i = 0; i < 8; ++i) {
            int lid = t + 256 * i;
            int r = lid >> 5, kk = lid & 31;
            int row = bm + r;
            int k = k0 + kk;
            float v;
            if (k < D_)          v = hn[(size_t)src[row] * D_ + k];
            else if (k < 2 * D_) v = hn[(size_t)dst[row] * D_ + (k - D_)];
            else                 v = e[(size_t)row * ED_ + (k - 2 * D_)];
            As[kk][r] = v;
        }
#pragma unroll
        for (int i = 0; i < 8; ++i) {
            int lid = t + 256 * i;
            int kk = lid >> 6, c = lid & 63;
            Bs[kk][c] = B[(size_t)(k0 + kk) * TBN + c];
        }
        __syncthreads();
#pragma unroll
        for (int kk = 0; kk < TBK; ++kk) {
            float a[4], b[4];
#pragma unroll
            for (int i = 0; i < 4; ++i) a[i] = As[kk][ty * 4 + i];
#pragma unroll
            for (int j = 0; j < 4; ++j) b[j] = Bs[kk][tx * 4 + j];
#pragma unroll
            for (int i = 0; i < 4; ++i)
#pragma unroll
                for (int j = 0; j < 4; ++j) acc[i][j] += a[i] * b[j];
        }
        __syncthreads();
    }
    // epilogue: bias + silu + LN per row; 16 lanes (same ty) own one row group
#pragma unroll
    for (int i = 0; i < 4; ++i) {
        float v4[4], s = 0.f;
#pragma unroll
        for (int j = 0; j < 4; ++j) {
            float v = acc[i][j] + bias[tx * 4 + j];
            v = v / (1.f + expf(-v));
            v4[j] = v;
            s += v;
        }
        s += __shfl_xor(s, 8); s += __shfl_xor(s, 4);
        s += __shfl_xor(s, 2); s += __shfl_xor(s, 1);
        float mu = s * (1.f / 64.f);
        float q = 0.f;
#pragma unroll
        for (int j = 0; j < 4; ++j) { float dv = v4[j] - mu; q += dv * dv; }
        q += __shfl_xor(q, 8); q += __shfl_xor(q, 4);
        q += __shfl_xor(q, 2); q += __shfl_xor(q, 1);
        float rs = rsqrtf(q * (1.f / 64.f) + 1e-5f);
        int row = bm + ty * 4 + i;
#pragma unroll
        for (int j = 0; j < 4; ++j) {
            int col = tx * 4 + j;
            e[(size_t)row * ED_ + col] = (v4[j] - mu) * rs * gs[col] + gb[col];
        }
    }
}

// ---------------- GATv2 logits + denom ----------------
__global__ __launch_bounds__(256) void edge_logits(const float* __restrict__ xl,
                                                   const float* __restrict__ xr,
                                                   const float* __restrict__ e,
                                                   const float* __restrict__ loop_e,
                                                   const int* __restrict__ src,
                                                   const int* __restrict__ dst,
                                                   const float* __restrict__ We,
                                                   const float* __restrict__ att,
                                                   float* __restrict__ logits,
                                                   float* __restrict__ denom) {
    int base = blockIdx.x * 4;
    int t = threadIdx.x;
    __shared__ float efs[4][ED_];
    __shared__ int sS[4], sD[4];
    {
        int q = t >> 6, j = t & 63;
        int ge = base + q;
        float v = 0.f;
        if (ge < EN_TOT) v = (ge < E_) ? e[(size_t)ge * ED_ + j] : loop_e[(size_t)(ge - E_) * ED_ + j];
        efs[q][j] = v;
    }
    if (t < 4) {
        int ge = base + t;
        int s = 0, d = 0;
        if (ge < EN_TOT) {
            s = (ge < E_) ? src[ge] : ge - E_;
            d = (ge < E_) ? dst[ge] : ge - E_;
        }
        sS[t] = s; sD[t] = d;
    }
    __syncthreads();
    float accq[4] = {0.f, 0.f, 0.f, 0.f};
    for (int k = 0; k < ED_; ++k) {
        float w = We[k * D_ + t];
#pragma unroll
        for (int q = 0; q < 4; ++q) accq[q] += efs[q][k] * w;
    }
    int hh = t >> 6, c = t & 63;
    float av = att[hh * C_ + c];
#pragma unroll
    for (int q = 0; q < 4; ++q) {
        int ge = base + q;
        if (ge >= EN_TOT) break;
        float m = xl[(size_t)sS[q] * D_ + t] + xr[(size_t)sD[q] * D_ + t] + accq[q];
        m = (m > 0.f) ? m : 0.2f * m;
        float v = m * av;
#pragma unroll
        for (int o = 32; o; o >>= 1) v += __shfl_xor(v, o);
        if (c == 0) {
            logits[(size_t)ge * H_ + hh] = v;
            atomicAdd(&denom[sD[q] * H_ + hh], expf(v));
        }
    }
}

// ---------------- GAT aggregation (atomic scatter) ----------------
__global__ __launch_bounds__(256) void aggregate_kernel(const float* __restrict__ xl,
                                                        const float* __restrict__ logits,
                                                        const float* __restrict__ denom,
                                                        const int* __restrict__ src,
                                                        const int* __restrict__ dst,
                                                        float* __restrict__ nodeout) {
    int base = blockIdx.x * 4;
    int t = threadIdx.x;
    int hh = t >> 6;
#pragma unroll
    for (int q = 0; q < 4; ++q) {
        int ge = base + q;
        if (ge >= EN_TOT) break;
        int s = (ge < E_) ? src[ge] : ge - E_;
        int d = (ge < E_) ? dst[ge] : ge - E_;
        float alpha = expf(logits[(size_t)ge * H_ + hh]) / (denom[d * H_ + hh] + 1e-16f);
        atomicAdd(&nodeout[(size_t)d * D_ + t], alpha * xl[(size_t)s * D_ + t]);
    }
}

// ---------------- node silu + LN ----------------
__global__ __launch_bounds__(256) void node_silu_ln(const float* __restrict__ inp,
                                                    const float* __restrict__ bias, int hasBias,
                                                    const float* __restrict__ gs,
                                                    const float* __restrict__ gb,
                                                    float* __restrict__ outp) {
    int n = blockIdx.x, t = threadIdx.x;
    float v = inp[(size_t)n * D_ + t];
    if (hasBias) v += bias[t];
    v = v / (1.f + expf(-v));  // silu
    __shared__ float red[4];
    float s = v;
#pragma unroll
    for (int o = 32; o; o >>= 1) s += __shfl_xor(s, o);
    if ((t & 63) == 0) red[t >> 6] = s;
    __syncthreads();
    float mu = (red[0] + red[1] + red[2] + red[3]) * (1.f / 256.f);
    __syncthreads();
    float dv = v - mu;
    float q = dv * dv;
#pragma unroll
    for (int o = 32; o; o >>= 1) q += __shfl_xor(q, o);
    if ((t & 63) == 0) red[t >> 6] = q;
    __syncthreads();
    float var = (red[0] + red[1] + red[2] + red[3]) * (1.f / 256.f);
    outp[(size_t)n * D_ + t] = dv * rsqrtf(var + 1e-5f) * gs[t] + gb[t];
}

// ---------------- gate MLP + softmax denom ----------------
__global__ __launch_bounds__(128) void gate_kernel(const float* __restrict__ h,
                                                   const float* __restrict__ gW1,
                                                   const float* __restrict__ gb1,
                                                   const float* __restrict__ gW2,
                                                   const float* __restrict__ gb2,
                                                   const int* __restrict__ batch,
                                                   float* __restrict__ g,
                                                   float* __restrict__ gden) {
    int n = blockIdx.x, t = threadIdx.x; // 128 threads
    const float* hn = h + (size_t)n * D_;
    float acc = gb1[t];
    for (int k = 0; k < D_; ++k) acc += hn[k] * gW1[k * 128 + t];
    acc = acc / (1.f + expf(-acc));
    float v = acc * gW2[t];
#pragma unroll
    for (int o = 32; o; o >>= 1) v += __shfl_xor(v, o);
    __shared__ float r2[2];
    if ((t & 63) == 0) r2[t >> 6] = v;
    __syncthreads();
    if (t == 0) {
        float gg = r2[0] + r2[1] + gb2[0];
        g[n] = gg;
        atomicAdd(&gden[batch[n]], expf(gg));
    }
}

__global__ __launch_bounds__(256) void pool_kernel(const float* __restrict__ h,
                                                   const float* __restrict__ g,
                                                   const float* __restrict__ gden,
                                                   const int* __restrict__ batch,
                                                   float* __restrict__ hgraph) {
    int idx = blockIdx.x * 256 + threadIdx.x;
    if (idx >= N_ * D_) return;
    int n = idx >> 8;
    int b = batch[n];
    float w = expf(g[n]) / (gden[b] + 1e-16f);
    atomicAdd(&hgraph[(size_t)b * D_ + (idx & 255)], w * h[idx]);
}

__global__ __launch_bounds__(256) void head_kernel(const float* __restrict__ hgraph,
                                                   const float* __restrict__ hW,
                                                   const float* __restrict__ hb,
                                                   float* __restrict__ out) {
    int gp = blockIdx.x, t = threadIdx.x;
    float v = hgraph[(size_t)gp * D_ + t] * hW[t];
#pragma unroll
    for (int o = 32; o; o >>= 1) v += __shfl_xor(v, o);
    __shared__ float r4[4];
    if ((t & 63) == 0) r4[t >> 6] = v;
    __syncthreads();
    if (t == 0) out[gp] = r4[0] + r4[1] + r4[2] + r4[3] + hb[0];
}

// ---------------- host launch ----------------
extern "C" void kernel_launch(void* const* d_in, const int* in_sizes, int n_in,
                              void* d_out, int out_size, void* d_ws, size_t ws_size,
                              hipStream_t stream) {
    const float* x     = (const float*)d_in[0];
    const int*   eidx  = (const int*)d_in[1];
    const float* eattr = (const float*)d_in[2];
    const int*   batch = (const int*)d_in[3];
    const float* atomW = (const float*)d_in[4];
    const float* atomB = (const float*)d_in[5];
    const float* bondW = (const float*)d_in[6];
    const float* bondB = (const float*)d_in[7];
    const float* Wl    = (const float*)d_in[8];
    const float* bl    = (const float*)d_in[9];
    const float* Wr    = (const float*)d_in[10];
    const float* br    = (const float*)d_in[11];
    const float* We    = (const float*)d_in[12];
    const float* att   = (const float*)d_in[13];
    const float* bias  = (const float*)d_in[14];
    const float* ln1s  = (const float*)d_in[15];
    const float* ln1b  = (const float*)d_in[16];
    const float* eW    = (const float*)d_in[17];
    const float* eb    = (const float*)d_in[18];
    const float* ln2s  = (const float*)d_in[19];
    const float* ln2b  = (const float*)d_in[20];
    const float* jkW   = (const float*)d_in[21];
    const float* jkb   = (const float*)d_in[22];
    const float* ln3s  = (const float*)d_in[23];
    const float* ln3b  = (const float*)d_in[24];
    const float* gW1   = (const float*)d_in[25];
    const float* gb1   = (const float*)d_in[26];
    const float* gW2   = (const float*)d_in[27];
    const float* gb2   = (const float*)d_in[28];
    const float* hW    = (const float*)d_in[29];
    const float* hb    = (const float*)d_in[30];

    const int* src = eidx;
    const int* dst = eidx + E_;

    // ---- workspace layout (~236.5 MB, fits 256 MiB) ----
    char* wp = (char*)d_ws;
    auto take = [&](size_t bytes) {
        char* p = wp;
        wp += (bytes + 255) & ~(size_t)255;
        return (float*)p;
    };
    float* e_cur   = take((size_t)E_ * ED_ * 4);        // 81.92 MB
    float* outs    = take((size_t)L_ * N_ * D_ * 4);    // 81.92 MB
    float* xl      = take((size_t)N_ * D_ * 4);         // 20.48 MB (also hfin at end)
    float* xr      = take((size_t)N_ * D_ * 4);         // 20.48 MB
    float* nodebuf = take((size_t)N_ * D_ * 4);         // 20.48 MB (h0 / nodeout / JK out)
    float* loop_e  = take((size_t)N_ * ED_ * 4);        // 5.12 MB
    float* cnt     = take((size_t)N_ * 4);
    float* logits  = take((size_t)EN_TOT * H_ * 4);     // 5.44 MB
    float* denom   = take((size_t)N_ * H_ * 4);
    float* g       = take((size_t)N_ * 4);
    float* gden    = take((size_t)G_ * 4);
    float* hgraph  = take((size_t)G_ * D_ * 4);

    // encoders
    atom_enc<<<N_, 256, 0, stream>>>(x, atomW, atomB, nodebuf);  // h0 lives in nodebuf
    bond_enc<<<(E_ * ED_ + 255) / 256, 256, 0, stream>>>(eattr, bondW, bondB, e_cur);

    const float* h_prev = nodebuf;
    for (int l = 0; l < L_; ++l) {
        const float* Wl_l = Wl + (size_t)l * D_ * D_;
        const float* bl_l = bl + (size_t)l * D_;
        const float* Wr_l = Wr + (size_t)l * D_ * D_;
        const float* br_l = br + (size_t)l * D_;
        const float* We_l = We + (size_t)l * ED_ * D_;
        const float* att_l = att + (size_t)l * H_ * C_;
        const float* bias_l = bias + (size_t)l * D_;
        const float* ln1s_l = ln1s + (size_t)l * D_;
        const float* ln1b_l = ln1b + (size_t)l * D_;
        const float* eW_l = eW + (size_t)l * KEDGE * ED_;
        const float* eb_l = eb + (size_t)l * ED_;
        const float* ln2s_l = ln2s + (size_t)l * ED_;
        const float* ln2b_l = ln2b + (size_t)l * ED_;
        float* hn_l = outs + (size_t)l * N_ * D_;

        // xl/xr GEMMs first: they read h_prev (== nodebuf when l == 0), and the
        // nodeout memset below would clobber it.
        {
            DenseA a{h_prev, D_};
            dim3 grid((N_ + TBM - 1) / TBM, D_ / TBN);
            gemm64<DenseA><<<grid, 256, 0, stream>>>(a, Wl_l, bl_l, xl, N_, D_, D_);
            gemm64<DenseA><<<grid, 256, 0, stream>>>(a, Wr_l, br_l, xr, N_, D_, D_);
        }

        hipMemsetAsync(loop_e, 0, (size_t)N_ * ED_ * 4, stream);
        hipMemsetAsync(cnt, 0, (size_t)N_ * 4, stream);
        hipMemsetAsync(denom, 0, (size_t)N_ * H_ * 4, stream);
        hipMemsetAsync(nodebuf, 0, (size_t)N_ * D_ * 4, stream);

        deg_loop_kernel<<<(E_ * ED_ + 255) / 256, 256, 0, stream>>>(e_cur, dst, loop_e, cnt);
        loop_div_kernel<<<(N_ * ED_ + 255) / 256, 256, 0, stream>>>(loop_e, cnt);

        edge_logits<<<(EN_TOT + 3) / 4, 256, 0, stream>>>(xl, xr, e_cur, loop_e, src, dst,
                                                          We_l, att_l, logits, denom);
        aggregate_kernel<<<(EN_TOT + 3) / 4, 256, 0, stream>>>(xl, logits, denom, src, dst, nodebuf);

        node_silu_ln<<<N_, 256, 0, stream>>>(nodebuf, bias_l, 1, ln1s_l, ln1b_l, hn_l);

        // fused edge update (GEMM + silu + LN), writes e_cur in place
        edge_gemm_fused<<<E_ / TBM, 256, 0, stream>>>(hn_l, e_cur, src, dst,
                                                      eW_l, eb_l, ln2s_l, ln2b_l);

        h_prev = hn_l;
    }

    // JK -> jk GEMM -> silu -> LN (hfin overlays xl)
    {
        JkA a{outs};
        dim3 grid((N_ + TBM - 1) / TBM, D_ / TBN);
        gemm64<JkA><<<grid, 256, 0, stream>>>(a, jkW, jkb, nodebuf, N_, L_ * D_, D_);
    }
    float* hfin = xl;
    node_silu_ln<<<N_, 256, 0, stream>>>(nodebuf, nullptr, 0, ln3s, ln3b, hfin);

    hipMemsetAsync(gden, 0, (size_t)G_ * 4, stream);
    hipMemsetAsync(hgraph, 0, (size_t)G_ * D_ * 4, stream);
    gate_kernel<<<N_, 128, 0, stream>>>(hfin, gW1, gb1, gW2, gb2, batch, g, gden);
    pool_kernel<<<(N_ * D_ + 255) / 256, 256, 0, stream>>>(hfin, g, gden, batch, hgraph);
    head_kernel<<<G_, 256, 0, stream>>>(hgraph, hW, hb, (float*)d_out);
}

// Round 3
// 8179.075 us; speedup vs baseline: 1.4743x; 1.4743x over previous
//
#include <hip/hip_runtime.h>
#include <hip/hip_bf16.h>

// Problem constants
#define N_ 20000
#define E_ 320000
#define G_ 128
#define H_ 4
#define C_ 64
#define D_ 256
#define ED_ 64
#define L_ 4
#define KEDGE (2*D_ + ED_) // 576

#define TBM 64
#define TBN 64
#define TBK 32

// ---------------- encoders ----------------
__global__ __launch_bounds__(256) void atom_enc(const float* __restrict__ x,
                                                const float* __restrict__ W,
                                                const float* __restrict__ b,
                                                float* __restrict__ h) {
    int n = blockIdx.x, t = threadIdx.x;
    float acc = b[t];
#pragma unroll
    for (int k = 0; k < 9; ++k) acc += x[n * 9 + k] * W[k * D_ + t];
    h[(size_t)n * D_ + t] = acc;
}

// bond encoder writing into CSR-permuted order: e[pos] = enc(edge_attr[perm[pos]])
__global__ __launch_bounds__(256) void bond_enc_perm(const float* __restrict__ ea,
                                                     const float* __restrict__ W,
                                                     const float* __restrict__ b,
                                                     const int* __restrict__ perm,
                                                     float* __restrict__ e) {
    int idx = blockIdx.x * 256 + threadIdx.x;
    if (idx >= E_ * ED_) return;
    int pos = idx >> 6, j = idx & 63;
    int orig = perm[pos];
    float acc = b[j];
#pragma unroll
    for (int k = 0; k < 3; ++k) acc += ea[orig * 3 + k] * W[k * ED_ + j];
    e[idx] = acc;
}

// ---------------- CSR build (dst-sorted) ----------------
__global__ __launch_bounds__(256) void count_kernel(const int* __restrict__ dst,
                                                    int* __restrict__ deg) {
    int e = blockIdx.x * 256 + threadIdx.x;
    if (e >= E_) return;
    atomicAdd(&deg[dst[e]], 1);
}

__global__ __launch_bounds__(1024) void scan_kernel(const int* __restrict__ deg,
                                                    int* __restrict__ row_off) {
    __shared__ int part[1024];
    int t = threadIdx.x;
    const int CH = (N_ + 1023) / 1024;  // 20
    int s = 0;
    for (int i = 0; i < CH; ++i) {
        int idx = t * CH + i;
        if (idx < N_) s += deg[idx];
    }
    part[t] = s;
    __syncthreads();
    for (int off = 1; off < 1024; off <<= 1) {
        int v = (t >= off) ? part[t - off] : 0;
        __syncthreads();
        part[t] += v;
        __syncthreads();
    }
    int base = (t == 0) ? 0 : part[t - 1];
    for (int i = 0; i < CH; ++i) {
        int idx = t * CH + i;
        if (idx < N_) { row_off[idx] = base; base += deg[idx]; }
    }
    if (t == 0) row_off[N_] = part[1023];
}

__global__ __launch_bounds__(256) void fill_kernel(const int* __restrict__ src,
                                                   const int* __restrict__ dst,
                                                   const int* __restrict__ row_off,
                                                   int* __restrict__ fill,
                                                   int* __restrict__ perm,
                                                   int* __restrict__ srcp,
                                                   int* __restrict__ dstp) {
    int e = blockIdx.x * 256 + threadIdx.x;
    if (e >= E_) return;
    int d = dst[e];
    int pos = row_off[d] + atomicAdd(&fill[d], 1);
    perm[pos] = e;
    srcp[pos] = src[e];
    dstp[pos] = d;
}

// ---------------- generic tiled f32 GEMM: C = A @ B + bias ----------------
struct DenseA {
    const float* A; int K;
    __device__ float operator()(int r, int k) const { return A[(size_t)r * K + k]; }
};
struct JkA {
    const float* outs;
    __device__ float operator()(int r, int k) const {
        return outs[(size_t)(k >> 8) * N_ * D_ + (size_t)r * D_ + (k & 255)];
    }
};

template <typename AFetch>
__global__ __launch_bounds__(256) void gemm64(AFetch af, const float* __restrict__ B,
                                              const float* __restrict__ bias,
                                              float* __restrict__ C,
                                              int M, int K, int Nn) {
    __shared__ float As[TBK][TBM + 1];
    __shared__ float Bs[TBK][TBN];
    int t = threadIdx.x;
    int bm = blockIdx.x * TBM;
    int bn = blockIdx.y * TBN;
    int tx = t & 15, ty = t >> 4;
    float acc[4][4] = {};
    for (int k0 = 0; k0 < K; k0 += TBK) {
#pragma unroll
        for (int i = 0; i < 8; ++i) {
            int lid = t + 256 * i;
            int r = lid >> 5, kk = lid & 31;
            int row = bm + r;
            As[kk][r] = (row < M) ? af(row, k0 + kk) : 0.f;
        }
#pragma unroll
        for (int i = 0; i < 8; ++i) {
            int lid = t + 256 * i;
            int kk = lid >> 6, c = lid & 63;
            Bs[kk][c] = B[(size_t)(k0 + kk) * Nn + (bn + c)];
        }
        __syncthreads();
#pragma unroll
        for (int kk = 0; kk < TBK; ++kk) {
            float a[4], b[4];
#pragma unroll
            for (int i = 0; i < 4; ++i) a[i] = As[kk][ty * 4 + i];
#pragma unroll
            for (int j = 0; j < 4; ++j) b[j] = Bs[kk][tx * 4 + j];
#pragma unroll
            for (int i = 0; i < 4; ++i)
#pragma unroll
                for (int j = 0; j < 4; ++j) acc[i][j] += a[i] * b[j];
        }
        __syncthreads();
    }
#pragma unroll
    for (int i = 0; i < 4; ++i) {
        int row = bm + ty * 4 + i;
        if (row >= M) continue;
#pragma unroll
        for (int j = 0; j < 4; ++j) {
            int col = bn + tx * 4 + j;
            C[(size_t)row * Nn + col] = acc[i][j] + bias[col];
        }
    }
}

// ---------------- fused per-dst GATv2 layer ----------------
// One block per dst node. CSR edges stream sequentially (e is stored permuted).
// Computes: per-edge ef@We, GATv2 logits (shfl-reduced), softmax denom in regs,
// self-loop via mean(efW), weighted aggregation, bias+silu+LN epilogue.
__global__ __launch_bounds__(256) void gat_fused(const float* __restrict__ xl,
                                                 const float* __restrict__ xr,
                                                 const float* __restrict__ e,
                                                 const int* __restrict__ row_off,
                                                 const int* __restrict__ srcp,
                                                 const float* __restrict__ We,
                                                 const float* __restrict__ att,
                                                 const float* __restrict__ bias,
                                                 const float* __restrict__ gs,
                                                 const float* __restrict__ gb,
                                                 float* __restrict__ elog,
                                                 float* __restrict__ hn) {
    int d = blockIdx.x, t = threadIdx.x;
    int beg = row_off[d], end = row_off[d + 1];
    int deg = end - beg;
    int hh = t >> 6, c = t & 63;
    float av = att[hh * C_ + c];
    float xr_d = xr[(size_t)d * D_ + t];
    float xl_d = xl[(size_t)d * D_ + t];
    float wsum = 0.f, den = 0.f;
    __shared__ float efs[4][ED_];
    __shared__ int ss[4];
    // Pass B: logits + exp + denom
    for (int g = beg; g < end; g += 4) {
        int nq = min(4, end - g);
        __syncthreads();
        {
            int q = t >> 6, j = t & 63;
            if (q < nq) efs[q][j] = e[(size_t)(g + q) * ED_ + j];
        }
        if (t < nq) ss[t] = srcp[g + t];
        __syncthreads();
        float accW[4] = {0.f, 0.f, 0.f, 0.f};
        for (int k = 0; k < ED_; ++k) {
            float w = We[k * D_ + t];
#pragma unroll
            for (int q = 0; q < 4; ++q) accW[q] += efs[q][k] * w;
        }
        for (int q = 0; q < nq; ++q) {
            wsum += accW[q];
            float m = xl[(size_t)ss[q] * D_ + t] + xr_d + accW[q];
            m = (m > 0.f) ? m : 0.2f * m;
            float v = m * av;
#pragma unroll
            for (int o = 32; o; o >>= 1) v += __shfl_xor(v, o);
            float ex = expf(v);
            den += ex;
            if (c == 0) elog[(size_t)(g + q) * H_ + hh] = ex;
        }
    }
    // self loop: loop_e@We = mean over incoming of ef@We
    float loopW = (deg > 0) ? wsum / (float)deg : 0.f;
    float eself;
    {
        float m = xl_d + xr_d + loopW;
        m = (m > 0.f) ? m : 0.2f * m;
        float v = m * av;
#pragma unroll
        for (int o = 32; o; o >>= 1) v += __shfl_xor(v, o);
        eself = expf(v);
        den += eself;
    }
    float inv = 1.f / (den + 1e-16f);
    float out = eself * inv * xl_d;
    // Pass C: weighted aggregation
    for (int i = beg; i < end; ++i) {
        int s = srcp[i];
        float al = elog[(size_t)i * H_ + hh] * inv;
        out += al * xl[(size_t)s * D_ + t];
    }
    // epilogue: bias + silu + LN over 256 features
    float v = out + bias[t];
    v = v / (1.f + expf(-v));
    __shared__ float red[4];
    float s = v;
#pragma unroll
    for (int o = 32; o; o >>= 1) s += __shfl_xor(s, o);
    if ((t & 63) == 0) red[t >> 6] = s;
    __syncthreads();
    float mu = (red[0] + red[1] + red[2] + red[3]) * (1.f / 256.f);
    __syncthreads();
    float dv = v - mu;
    float q = dv * dv;
#pragma unroll
    for (int o = 32; o; o >>= 1) q += __shfl_xor(q, o);
    if ((t & 63) == 0) red[t >> 6] = q;
    __syncthreads();
    float var = (red[0] + red[1] + red[2] + red[3]) * (1.f / 256.f);
    hn[(size_t)d * D_ + t] = dv * rsqrtf(var + 1e-5f) * gs[t] + gb[t];
}

// ---------------- fused edge GEMM + silu + LN (in-place into e) ----------------
__global__ __launch_bounds__(256) void edge_gemm_fused(const float* __restrict__ hn,
                                                       float* __restrict__ e,
                                                       const int* __restrict__ src,
                                                       const int* __restrict__ dst,
                                                       const float* __restrict__ B,
                                                       const float* __restrict__ bias,
                                                       const float* __restrict__ gs,
                                                       const float* __restrict__ gb) {
    __shared__ float As[TBK][TBM + 1];
    __shared__ float Bs[TBK][TBN];
    int t = threadIdx.x;
    int bm = blockIdx.x * TBM;  // E_ % 64 == 0, no tail
    int tx = t & 15, ty = t >> 4;
    float acc[4][4] = {};
    for (int k0 = 0; k0 < KEDGE; k0 += TBK) {
#pragma unroll
        for (int i = 0; i < 8; ++i) {
            int lid = t + 256 * i;
            int r = lid >> 5, kk = lid & 31;
            int row = bm + r;
            int k = k0 + kk;
            float v;
            if (k < D_)          v = hn[(size_t)src[row] * D_ + k];
            else if (k < 2 * D_) v = hn[(size_t)dst[row] * D_ + (k - D_)];
            else                 v = e[(size_t)row * ED_ + (k - 2 * D_)];
            As[kk][r] = v;
        }
#pragma unroll
        for (int i = 0; i < 8; ++i) {
            int lid = t + 256 * i;
            int kk = lid >> 6, c = lid & 63;
            Bs[kk][c] = B[(size_t)(k0 + kk) * TBN + c];
        }
        __syncthreads();
#pragma unroll
        for (int kk = 0; kk < TBK; ++kk) {
            float a[4], b[4];
#pragma unroll
            for (int i = 0; i < 4; ++i) a[i] = As[kk][ty * 4 + i];
#pragma unroll
            for (int j = 0; j < 4; ++j) b[j] = Bs[kk][tx * 4 + j];
#pragma unroll
            for (int i = 0; i < 4; ++i)
#pragma unroll
                for (int j = 0; j < 4; ++j) acc[i][j] += a[i] * b[j];
        }
        __syncthreads();
    }
#pragma unroll
    for (int i = 0; i < 4; ++i) {
        float v4[4], s = 0.f;
#pragma unroll
        for (int j = 0; j < 4; ++j) {
            float v = acc[i][j] + bias[tx * 4 + j];
            v = v / (1.f + expf(-v));
            v4[j] = v;
            s += v;
        }
        s += __shfl_xor(s, 8); s += __shfl_xor(s, 4);
        s += __shfl_xor(s, 2); s += __shfl_xor(s, 1);
        float mu = s * (1.f / 64.f);
        float q = 0.f;
#pragma unroll
        for (int j = 0; j < 4; ++j) { float dv = v4[j] - mu; q += dv * dv; }
        q += __shfl_xor(q, 8); q += __shfl_xor(q, 4);
        q += __shfl_xor(q, 2); q += __shfl_xor(q, 1);
        float rs = rsqrtf(q * (1.f / 64.f) + 1e-5f);
        int row = bm + ty * 4 + i;
#pragma unroll
        for (int j = 0; j < 4; ++j) {
            int col = tx * 4 + j;
            e[(size_t)row * ED_ + col] = (v4[j] - mu) * rs * gs[col] + gb[col];
        }
    }
}

// ---------------- node silu + LN (used for final JK output) ----------------
__global__ __launch_bounds__(256) void node_silu_ln(const float* __restrict__ inp,
                                                    const float* __restrict__ gs,
                                                    const float* __restrict__ gb,
                                                    float* __restrict__ outp) {
    int n = blockIdx.x, t = threadIdx.x;
    float v = inp[(size_t)n * D_ + t];
    v = v / (1.f + expf(-v));
    __shared__ float red[4];
    float s = v;
#pragma unroll
    for (int o = 32; o; o >>= 1) s += __shfl_xor(s, o);
    if ((t & 63) == 0) red[t >> 6] = s;
    __syncthreads();
    float mu = (red[0] + red[1] + red[2] + red[3]) * (1.f / 256.f);
    __syncthreads();
    float dv = v - mu;
    float q = dv * dv;
#pragma unroll
    for (int o = 32; o; o >>= 1) q += __shfl_xor(q, o);
    if ((t & 63) == 0) red[t >> 6] = q;
    __syncthreads();
    float var = (red[0] + red[1] + red[2] + red[3]) * (1.f / 256.f);
    outp[(size_t)n * D_ + t] = dv * rsqrtf(var + 1e-5f) * gs[t] + gb[t];
}

// ---------------- gate MLP + softmax denom ----------------
__global__ __launch_bounds__(128) void gate_kernel(const float* __restrict__ h,
                                                   const float* __restrict__ gW1,
                                                   const float* __restrict__ gb1,
                                                   const float* __restrict__ gW2,
                                                   const float* __restrict__ gb2,
                                                   const int* __restrict__ batch,
                                                   float* __restrict__ g,
                                                   float* __restrict__ gden) {
    int n = blockIdx.x, t = threadIdx.x; // 128 threads
    const float* hn = h + (size_t)n * D_;
    float acc = gb1[t];
    for (int k = 0; k < D_; ++k) acc += hn[k] * gW1[k * 128 + t];
    acc = acc / (1.f + expf(-acc));
    float v = acc * gW2[t];
#pragma unroll
    for (int o = 32; o; o >>= 1) v += __shfl_xor(v, o);
    __shared__ float r2[2];
    if ((t & 63) == 0) r2[t >> 6] = v;
    __syncthreads();
    if (t == 0) {
        float gg = r2[0] + r2[1] + gb2[0];
        g[n] = gg;
        atomicAdd(&gden[batch[n]], expf(gg));
    }
}

__global__ __launch_bounds__(256) void pool_kernel(const float* __restrict__ h,
                                                   const float* __restrict__ g,
                                                   const float* __restrict__ gden,
                                                   const int* __restrict__ batch,
                                                   float* __restrict__ hgraph) {
    int idx = blockIdx.x * 256 + threadIdx.x;
    if (idx >= N_ * D_) return;
    int n = idx >> 8;
    int b = batch[n];
    float w = expf(g[n]) / (gden[b] + 1e-16f);
    atomicAdd(&hgraph[(size_t)b * D_ + (idx & 255)], w * h[idx]);
}

__global__ __launch_bounds__(256) void head_kernel(const float* __restrict__ hgraph,
                                                   const float* __restrict__ hW,
                                                   const float* __restrict__ hb,
                                                   float* __restrict__ out) {
    int gp = blockIdx.x, t = threadIdx.x;
    float v = hgraph[(size_t)gp * D_ + t] * hW[t];
#pragma unroll
    for (int o = 32; o; o >>= 1) v += __shfl_xor(v, o);
    __shared__ float r4[4];
    if ((t & 63) == 0) r4[t >> 6] = v;
    __syncthreads();
    if (t == 0) out[gp] = r4[0] + r4[1] + r4[2] + r4[3] + hb[0];
}

// ---------------- host launch ----------------
extern "C" void kernel_launch(void* const* d_in, const int* in_sizes, int n_in,
                              void* d_out, int out_size, void* d_ws, size_t ws_size,
                              hipStream_t stream) {
    const float* x     = (const float*)d_in[0];
    const int*   eidx  = (const int*)d_in[1];
    const float* eattr = (const float*)d_in[2];
    const int*   batch = (const int*)d_in[3];
    const float* atomW = (const float*)d_in[4];
    const float* atomB = (const float*)d_in[5];
    const float* bondW = (const float*)d_in[6];
    const float* bondB = (const float*)d_in[7];
    const float* Wl    = (const float*)d_in[8];
    const float* bl    = (const float*)d_in[9];
    const float* Wr    = (const float*)d_in[10];
    const float* br    = (const float*)d_in[11];
    const float* We    = (const float*)d_in[12];
    const float* att   = (const float*)d_in[13];
    const float* bias  = (const float*)d_in[14];
    const float* ln1s  = (const float*)d_in[15];
    const float* ln1b  = (const float*)d_in[16];
    const float* eW    = (const float*)d_in[17];
    const float* eb    = (const float*)d_in[18];
    const float* ln2s  = (const float*)d_in[19];
    const float* ln2b  = (const float*)d_in[20];
    const float* jkW   = (const float*)d_in[21];
    const float* jkb   = (const float*)d_in[22];
    const float* ln3s  = (const float*)d_in[23];
    const float* ln3b  = (const float*)d_in[24];
    const float* gW1   = (const float*)d_in[25];
    const float* gb1   = (const float*)d_in[26];
    const float* gW2   = (const float*)d_in[27];
    const float* gb2   = (const float*)d_in[28];
    const float* hW    = (const float*)d_in[29];
    const float* hb    = (const float*)d_in[30];

    const int* src = eidx;
    const int* dst = eidx + E_;

    // ---- workspace layout (~236 MB) ----
    char* wp = (char*)d_ws;
    auto take = [&](size_t bytes) {
        char* p = wp;
        wp += (bytes + 255) & ~(size_t)255;
        return (void*)p;
    };
    float* e_cur   = (float*)take((size_t)E_ * ED_ * 4);     // 81.92 MB, CSR-permuted
    float* outs    = (float*)take((size_t)L_ * N_ * D_ * 4); // 81.92 MB
    float* xl      = (float*)take((size_t)N_ * D_ * 4);      // 20.48 MB (hfin at end)
    float* xr      = (float*)take((size_t)N_ * D_ * 4);      // 20.48 MB
    float* nodebuf = (float*)take((size_t)N_ * D_ * 4);      // 20.48 MB (h0 / JK out)
    float* elog    = (float*)take((size_t)E_ * H_ * 4);      // 5.12 MB
    int*   deg_i   = (int*)take((size_t)N_ * 4);
    int*   fill    = (int*)take((size_t)N_ * 4);
    int*   row_off = (int*)take((size_t)(N_ + 1) * 4);
    int*   perm    = (int*)take((size_t)E_ * 4);
    int*   srcp    = (int*)take((size_t)E_ * 4);
    int*   dstp    = (int*)take((size_t)E_ * 4);
    float* g       = (float*)take((size_t)N_ * 4);
    float* gden    = (float*)take((size_t)G_ * 4);
    float* hgraph  = (float*)take((size_t)G_ * D_ * 4);

    // ---- CSR build (once per launch) ----
    hipMemsetAsync(deg_i, 0, (size_t)N_ * 4, stream);
    hipMemsetAsync(fill, 0, (size_t)N_ * 4, stream);
    count_kernel<<<(E_ + 255) / 256, 256, 0, stream>>>(dst, deg_i);
    scan_kernel<<<1, 1024, 0, stream>>>(deg_i, row_off);
    fill_kernel<<<(E_ + 255) / 256, 256, 0, stream>>>(src, dst, row_off, fill,
                                                      perm, srcp, dstp);

    // encoders (e_cur written in CSR-permuted order)
    atom_enc<<<N_, 256, 0, stream>>>(x, atomW, atomB, nodebuf);
    bond_enc_perm<<<(E_ * ED_ + 255) / 256, 256, 0, stream>>>(eattr, bondW, bondB,
                                                              perm, e_cur);

    const float* h_prev = nodebuf;
    for (int l = 0; l < L_; ++l) {
        const float* Wl_l = Wl + (size_t)l * D_ * D_;
        const float* bl_l = bl + (size_t)l * D_;
        const float* Wr_l = Wr + (size_t)l * D_ * D_;
        const float* br_l = br + (size_t)l * D_;
        const float* We_l = We + (size_t)l * ED_ * D_;
        const float* att_l = att + (size_t)l * H_ * C_;
        const float* bias_l = bias + (size_t)l * D_;
        const float* ln1s_l = ln1s + (size_t)l * D_;
        const float* ln1b_l = ln1b + (size_t)l * D_;
        const float* eW_l = eW + (size_t)l * KEDGE * ED_;
        const float* eb_l = eb + (size_t)l * ED_;
        const float* ln2s_l = ln2s + (size_t)l * ED_;
        const float* ln2b_l = ln2b + (size_t)l * ED_;
        float* hn_l = outs + (size_t)l * N_ * D_;

        {
            DenseA a{h_prev, D_};
            dim3 grid((N_ + TBM - 1) / TBM, D_ / TBN);
            gemm64<DenseA><<<grid, 256, 0, stream>>>(a, Wl_l, bl_l, xl, N_, D_, D_);
            gemm64<DenseA><<<grid, 256, 0, stream>>>(a, Wr_l, br_l, xr, N_, D_, D_);
        }

        gat_fused<<<N_, 256, 0, stream>>>(xl, xr, e_cur, row_off, srcp,
                                          We_l, att_l, bias_l, ln1s_l, ln1b_l,
                                          elog, hn_l);

        edge_gemm_fused<<<E_ / TBM, 256, 0, stream>>>(hn_l, e_cur, srcp, dstp,
                                                      eW_l, eb_l, ln2s_l, ln2b_l);

        h_prev = hn_l;
    }

    // JK -> jk GEMM -> silu -> LN (hfin overlays xl)
    {
        JkA a{outs};
        dim3 grid((N_ + TBM - 1) / TBM, D_ / TBN);
        gemm64<JkA><<<grid, 256, 0, stream>>>(a, jkW, jkb, nodebuf, N_, L_ * D_, D_);
    }
    float* hfin = xl;
    node_silu_ln<<<N_, 256, 0, stream>>>(nodebuf, ln3s, ln3b, hfin);

    hipMemsetAsync(gden, 0, (size_t)G_ * 4, stream);
    hipMemsetAsync(hgraph, 0, (size_t)G_ * D_ * 4, stream);
    gate_kernel<<<N_, 128, 0, stream>>>(hfin, gW1, gb1, gW2, gb2, batch, g, gden);
    pool_kernel<<<(N_ * D_ + 255) / 256, 256, 0, stream>>>(hfin, g, gden, batch, hgraph);
    head_kernel<<<G_, 256, 0, stream>>>(hgraph, hW, hb, (float*)d_out);
}

// Round 4
// 4968.260 us; speedup vs baseline: 2.4270x; 1.6463x over previous
//
#include <hip/hip_runtime.h>
#include <hip/hip_bf16.h>

// Problem constants
#define N_ 20000
#define E_ 320000
#define G_ 128
#define H_ 4
#define C_ 64
#define D_ 256
#define ED_ 64
#define L_ 4

#define TBM 64
#define TBN 64
#define TBK 32

// ---------------- encoders ----------------
__global__ __launch_bounds__(256) void atom_enc(const float* __restrict__ x,
                                                const float* __restrict__ W,
                                                const float* __restrict__ b,
                                                float* __restrict__ h) {
    int n = blockIdx.x, t = threadIdx.x;
    float acc = b[t];
#pragma unroll
    for (int k = 0; k < 9; ++k) acc += x[n * 9 + k] * W[k * D_ + t];
    h[(size_t)n * D_ + t] = acc;
}

// bond encoder writing into CSR-permuted order: e[pos] = enc(edge_attr[perm[pos]])
__global__ __launch_bounds__(256) void bond_enc_perm(const float* __restrict__ ea,
                                                     const float* __restrict__ W,
                                                     const float* __restrict__ b,
                                                     const int* __restrict__ perm,
                                                     float* __restrict__ e) {
    int idx = blockIdx.x * 256 + threadIdx.x;
    if (idx >= E_ * ED_) return;
    int pos = idx >> 6, j = idx & 63;
    int orig = perm[pos];
    float acc = b[j];
#pragma unroll
    for (int k = 0; k < 3; ++k) acc += ea[orig * 3 + k] * W[k * ED_ + j];
    e[idx] = acc;
}

// ---------------- CSR build (dst-sorted) ----------------
__global__ __launch_bounds__(256) void count_kernel(const int* __restrict__ dst,
                                                    int* __restrict__ deg) {
    int e = blockIdx.x * 256 + threadIdx.x;
    if (e >= E_) return;
    atomicAdd(&deg[dst[e]], 1);
}

__global__ __launch_bounds__(1024) void scan_kernel(const int* __restrict__ deg,
                                                    int* __restrict__ row_off) {
    __shared__ int part[1024];
    int t = threadIdx.x;
    const int CH = (N_ + 1023) / 1024;  // 20
    int s = 0;
    for (int i = 0; i < CH; ++i) {
        int idx = t * CH + i;
        if (idx < N_) s += deg[idx];
    }
    part[t] = s;
    __syncthreads();
    for (int off = 1; off < 1024; off <<= 1) {
        int v = (t >= off) ? part[t - off] : 0;
        __syncthreads();
        part[t] += v;
        __syncthreads();
    }
    int base = (t == 0) ? 0 : part[t - 1];
    for (int i = 0; i < CH; ++i) {
        int idx = t * CH + i;
        if (idx < N_) { row_off[idx] = base; base += deg[idx]; }
    }
    if (t == 0) row_off[N_] = part[1023];
}

__global__ __launch_bounds__(256) void fill_kernel(const int* __restrict__ src,
                                                   const int* __restrict__ dst,
                                                   const int* __restrict__ row_off,
                                                   int* __restrict__ fill,
                                                   int* __restrict__ perm,
                                                   int* __restrict__ srcp,
                                                   int* __restrict__ dstp) {
    int e = blockIdx.x * 256 + threadIdx.x;
    if (e >= E_) return;
    int d = dst[e];
    int pos = row_off[d] + atomicAdd(&fill[d], 1);
    perm[pos] = e;
    srcp[pos] = src[e];
    dstp[pos] = d;
}

// ---------------- generic tiled f32 GEMM: C (=|+=) A @ B (+ bias) ----------------
struct DenseA {
    const float* A; int K;
    __device__ float operator()(int r, int k) const { return A[(size_t)r * K + k]; }
};

template <typename AFetch>
__global__ __launch_bounds__(256) void gemm64(AFetch af, const float* __restrict__ B,
                                              const float* __restrict__ bias,
                                              float* __restrict__ C,
                                              int M, int K, int Nn, int accum) {
    __shared__ float As[TBK][TBM + 1];
    __shared__ float Bs[TBK][TBN];
    int t = threadIdx.x;
    int bm = blockIdx.x * TBM;
    int bn = blockIdx.y * TBN;
    int tx = t & 15, ty = t >> 4;
    float acc[4][4] = {};
    for (int k0 = 0; k0 < K; k0 += TBK) {
#pragma unroll
        for (int i = 0; i < 8; ++i) {
            int lid = t + 256 * i;
            int r = lid >> 5, kk = lid & 31;
            int row = bm + r;
            As[kk][r] = (row < M) ? af(row, k0 + kk) : 0.f;
        }
#pragma unroll
        for (int i = 0; i < 8; ++i) {
            int lid = t + 256 * i;
            int kk = lid >> 6, c = lid & 63;
            if (c < Nn) Bs[kk][c] = B[(size_t)(k0 + kk) * Nn + (bn + c)];
        }
        __syncthreads();
#pragma unroll
        for (int kk = 0; kk < TBK; ++kk) {
            float a[4], b[4];
#pragma unroll
            for (int i = 0; i < 4; ++i) a[i] = As[kk][ty * 4 + i];
#pragma unroll
            for (int j = 0; j < 4; ++j) b[j] = Bs[kk][tx * 4 + j];
#pragma unroll
            for (int i = 0; i < 4; ++i)
#pragma unroll
                for (int j = 0; j < 4; ++j) acc[i][j] += a[i] * b[j];
        }
        __syncthreads();
    }
#pragma unroll
    for (int i = 0; i < 4; ++i) {
        int row = bm + ty * 4 + i;
        if (row >= M) continue;
#pragma unroll
        for (int j = 0; j < 4; ++j) {
            int col = bn + tx * 4 + j;
            if (col >= Nn) continue;
            float v = acc[i][j] + (bias ? bias[col] : 0.f);
            if (accum) C[(size_t)row * Nn + col] += v;
            else       C[(size_t)row * Nn + col] = v;
        }
    }
}

// ---------------- fused per-dst GATv2 layer (single pass) ----------------
// One block per dst node; We column hoisted to 64 VGPRs; logits+softmax+
// aggregation in one sweep over the CSR edges; bias+silu+LN epilogue.
__global__ __launch_bounds__(256) void gat_fused(const float* __restrict__ xl,
                                                 const float* __restrict__ xr,
                                                 const float* __restrict__ e,
                                                 const int* __restrict__ row_off,
                                                 const int* __restrict__ srcp,
                                                 const float* __restrict__ We,
                                                 const float* __restrict__ att,
                                                 const float* __restrict__ bias,
                                                 const float* __restrict__ gs,
                                                 const float* __restrict__ gb,
                                                 float* __restrict__ hn) {
    int d = blockIdx.x, t = threadIdx.x;
    int beg = row_off[d], end = row_off[d + 1];
    int deg = end - beg;
    int hh = t >> 6, c = t & 63;
    float av = att[hh * C_ + c];
    float wreg[64];
#pragma unroll
    for (int k = 0; k < 64; ++k) wreg[k] = We[k * D_ + t];
    float xr_d = xr[(size_t)d * D_ + t];
    float xl_d = xl[(size_t)d * D_ + t];
    float wsum = 0.f, den = 0.f, out = 0.f;
    __shared__ float efs[4][ED_];
    __shared__ int ss[4];
    for (int g0 = beg; g0 < end; g0 += 4) {
        int nq = min(4, end - g0);
        __syncthreads();
        {
            int q = t >> 6, j = t & 63;
            if (q < nq) efs[q][j] = e[(size_t)(g0 + q) * ED_ + j];
        }
        if (t < 4) ss[t] = (t < nq) ? srcp[g0 + t] : 0;
        __syncthreads();
        float xls[4];
#pragma unroll
        for (int q = 0; q < 4; ++q) xls[q] = (q < nq) ? xl[(size_t)ss[q] * D_ + t] : 0.f;
        float accW[4] = {0.f, 0.f, 0.f, 0.f};
#pragma unroll
        for (int q = 0; q < 4; ++q)
#pragma unroll
            for (int k0 = 0; k0 < 64; k0 += 4) {
                const float4 ev = *(const float4*)&efs[q][k0];
                accW[q] += ev.x * wreg[k0] + ev.y * wreg[k0 + 1] +
                           ev.z * wreg[k0 + 2] + ev.w * wreg[k0 + 3];
            }
        for (int q = 0; q < nq; ++q) {
            wsum += accW[q];
            float m = xls[q] + xr_d + accW[q];
            m = (m > 0.f) ? m : 0.2f * m;
            float v = m * av;
#pragma unroll
            for (int o = 32; o; o >>= 1) v += __shfl_xor(v, o);
            float ex = expf(v);
            den += ex;
            out += ex * xls[q];
        }
    }
    // self loop: loop_e@We = mean over incoming of ef@We (linearity)
    float loopW = (deg > 0) ? wsum / (float)deg : 0.f;
    {
        float m = xl_d + xr_d + loopW;
        m = (m > 0.f) ? m : 0.2f * m;
        float v = m * av;
#pragma unroll
        for (int o = 32; o; o >>= 1) v += __shfl_xor(v, o);
        float eself = expf(v);
        den += eself;
        out += eself * xl_d;
    }
    out *= 1.f / (den + 1e-16f);
    // epilogue: bias + silu + LN over 256 features
    float v = out + bias[t];
    v = v / (1.f + expf(-v));
    __shared__ float red[4];
    float s = v;
#pragma unroll
    for (int o = 32; o; o >>= 1) s += __shfl_xor(s, o);
    if ((t & 63) == 0) red[t >> 6] = s;
    __syncthreads();
    float mu = (red[0] + red[1] + red[2] + red[3]) * (1.f / 256.f);
    __syncthreads();
    float dv = v - mu;
    float q = dv * dv;
#pragma unroll
    for (int o = 32; o; o >>= 1) q += __shfl_xor(q, o);
    if ((t & 63) == 0) red[t >> 6] = q;
    __syncthreads();
    float var = (red[0] + red[1] + red[2] + red[3]) * (1.f / 256.f);
    hn[(size_t)d * D_ + t] = dv * rsqrtf(var + 1e-5f) * gs[t] + gb[t];
}

// ---------------- factored edge MLP + silu + LN (in-place into e) ----------------
// out = LN(silu(hsW[src] + hdW[dst] + e@eW3 + eb)); eW3 column in 64 VGPRs.
__global__ __launch_bounds__(256) void edge_mlp_fused(const float* __restrict__ hsW,
                                                      const float* __restrict__ hdW,
                                                      float* __restrict__ e,
                                                      const int* __restrict__ srcp,
                                                      const int* __restrict__ dstp,
                                                      const float* __restrict__ eW3,
                                                      const float* __restrict__ eb,
                                                      const float* __restrict__ gs,
                                                      const float* __restrict__ gb) {
    int t = threadIdx.x;
    int w = t >> 6, lane = t & 63;
    float wreg[64];
#pragma unroll
    for (int k = 0; k < 64; ++k) wreg[k] = eW3[k * ED_ + lane];
    float ebv = eb[lane], gsv = gs[lane], gbv = gb[lane];
    __shared__ float es[4][ED_];
    int base = blockIdx.x * 64;
    for (int it = 0; it < 16; ++it) {
        int edge = base + it * 4 + w;
        float ev = e[(size_t)edge * ED_ + lane];
        es[w][lane] = ev;  // wave-local slot; wave-coherent LDS, no barrier
        float acc = ebv + hsW[(size_t)srcp[edge] * ED_ + lane]
                        + hdW[(size_t)dstp[edge] * ED_ + lane];
#pragma unroll
        for (int k0 = 0; k0 < 64; k0 += 4) {
            const float4 e4 = *(const float4*)&es[w][k0];
            acc += e4.x * wreg[k0] + e4.y * wreg[k0 + 1] +
                   e4.z * wreg[k0 + 2] + e4.w * wreg[k0 + 3];
        }
        // silu + LN over 64 lanes (one wave per edge)
        float v = acc / (1.f + expf(-acc));
        float s = v;
#pragma unroll
        for (int o = 32; o; o >>= 1) s += __shfl_xor(s, o);
        float mu = s * (1.f / 64.f);
        float dv = v - mu;
        float q = dv * dv;
#pragma unroll
        for (int o = 32; o; o >>= 1) q += __shfl_xor(q, o);
        float rs = rsqrtf(q * (1.f / 64.f) + 1e-5f);
        e[(size_t)edge * ED_ + lane] = dv * rs * gsv + gbv;
    }
}

// ---------------- node silu + LN (final JK output) ----------------
__global__ __launch_bounds__(256) void node_silu_ln(const float* __restrict__ inp,
                                                    const float* __restrict__ gs,
                                                    const float* __restrict__ gb,
                                                    float* __restrict__ outp) {
    int n = blockIdx.x, t = threadIdx.x;
    float v = inp[(size_t)n * D_ + t];
    v = v / (1.f + expf(-v));
    __shared__ float red[4];
    float s = v;
#pragma unroll
    for (int o = 32; o; o >>= 1) s += __shfl_xor(s, o);
    if ((t & 63) == 0) red[t >> 6] = s;
    __syncthreads();
    float mu = (red[0] + red[1] + red[2] + red[3]) * (1.f / 256.f);
    __syncthreads();
    float dv = v - mu;
    float q = dv * dv;
#pragma unroll
    for (int o = 32; o; o >>= 1) q += __shfl_xor(q, o);
    if ((t & 63) == 0) red[t >> 6] = q;
    __syncthreads();
    float var = (red[0] + red[1] + red[2] + red[3]) * (1.f / 256.f);
    outp[(size_t)n * D_ + t] = dv * rsqrtf(var + 1e-5f) * gs[t] + gb[t];
}

// ---------------- gate MLP + softmax denom ----------------
__global__ __launch_bounds__(128) void gate_kernel(const float* __restrict__ h,
                                                   const float* __restrict__ gW1,
                                                   const float* __restrict__ gb1,
                                                   const float* __restrict__ gW2,
                                                   const float* __restrict__ gb2,
                                                   const int* __restrict__ batch,
                                                   float* __restrict__ g,
                                                   float* __restrict__ gden) {
    int n = blockIdx.x, t = threadIdx.x; // 128 threads
    const float* hn = h + (size_t)n * D_;
    float acc = gb1[t];
    for (int k = 0; k < D_; ++k) acc += hn[k] * gW1[k * 128 + t];
    acc = acc / (1.f + expf(-acc));
    float v = acc * gW2[t];
#pragma unroll
    for (int o = 32; o; o >>= 1) v += __shfl_xor(v, o);
    __shared__ float r2[2];
    if ((t & 63) == 0) r2[t >> 6] = v;
    __syncthreads();
    if (t == 0) {
        float gg = r2[0] + r2[1] + gb2[0];
        g[n] = gg;
        atomicAdd(&gden[batch[n]], expf(gg));
    }
}

__global__ __launch_bounds__(256) void pool_kernel(const float* __restrict__ h,
                                                   const float* __restrict__ g,
                                                   const float* __restrict__ gden,
                                                   const int* __restrict__ batch,
                                                   float* __restrict__ hgraph) {
    int idx = blockIdx.x * 256 + threadIdx.x;
    if (idx >= N_ * D_) return;
    int n = idx >> 8;
    int b = batch[n];
    float w = expf(g[n]) / (gden[b] + 1e-16f);
    atomicAdd(&hgraph[(size_t)b * D_ + (idx & 255)], w * h[idx]);
}

__global__ __launch_bounds__(256) void head_kernel(const float* __restrict__ hgraph,
                                                   const float* __restrict__ hW,
                                                   const float* __restrict__ hb,
                                                   float* __restrict__ out) {
    int gp = blockIdx.x, t = threadIdx.x;
    float v = hgraph[(size_t)gp * D_ + t] * hW[t];
#pragma unroll
    for (int o = 32; o; o >>= 1) v += __shfl_xor(v, o);
    __shared__ float r4[4];
    if ((t & 63) == 0) r4[t >> 6] = v;
    __syncthreads();
    if (t == 0) out[gp] = r4[0] + r4[1] + r4[2] + r4[3] + hb[0];
}

// ---------------- host launch ----------------
extern "C" void kernel_launch(void* const* d_in, const int* in_sizes, int n_in,
                              void* d_out, int out_size, void* d_ws, size_t ws_size,
                              hipStream_t stream) {
    const float* x     = (const float*)d_in[0];
    const int*   eidx  = (const int*)d_in[1];
    const float* eattr = (const float*)d_in[2];
    const int*   batch = (const int*)d_in[3];
    const float* atomW = (const float*)d_in[4];
    const float* atomB = (const float*)d_in[5];
    const float* bondW = (const float*)d_in[6];
    const float* bondB = (const float*)d_in[7];
    const float* Wl    = (const float*)d_in[8];
    const float* bl    = (const float*)d_in[9];
    const float* Wr    = (const float*)d_in[10];
    const float* br    = (const float*)d_in[11];
    const float* We    = (const float*)d_in[12];
    const float* att   = (const float*)d_in[13];
    const float* bias  = (const float*)d_in[14];
    const float* ln1s  = (const float*)d_in[15];
    const float* ln1b  = (const float*)d_in[16];
    const float* eW    = (const float*)d_in[17];
    const float* eb    = (const float*)d_in[18];
    const float* ln2s  = (const float*)d_in[19];
    const float* ln2b  = (const float*)d_in[20];
    const float* jkW   = (const float*)d_in[21];
    const float* jkb   = (const float*)d_in[22];
    const float* ln3s  = (const float*)d_in[23];
    const float* ln3b  = (const float*)d_in[24];
    const float* gW1   = (const float*)d_in[25];
    const float* gb1   = (const float*)d_in[26];
    const float* gW2   = (const float*)d_in[27];
    const float* gb2   = (const float*)d_in[28];
    const float* hW    = (const float*)d_in[29];
    const float* hb    = (const float*)d_in[30];

    const int* src = eidx;
    const int* dst = eidx + E_;

    // ---- workspace layout (~200 MB) ----
    char* wp = (char*)d_ws;
    auto take = [&](size_t bytes) {
        char* p = wp;
        wp += (bytes + 255) & ~(size_t)255;
        return (void*)p;
    };
    float* e_cur   = (float*)take((size_t)E_ * ED_ * 4);  // 81.92 MB, CSR-permuted
    float* hA      = (float*)take((size_t)N_ * D_ * 4);   // 20.48 MB
    float* hB      = (float*)take((size_t)N_ * D_ * 4);   // 20.48 MB
    float* xl      = (float*)take((size_t)N_ * D_ * 4);   // 20.48 MB (hfin at end)
    float* xr      = (float*)take((size_t)N_ * D_ * 4);   // 20.48 MB
    float* jkacc   = (float*)take((size_t)N_ * D_ * 4);   // 20.48 MB
    float* hsW     = (float*)take((size_t)N_ * ED_ * 4);  // 5.12 MB
    float* hdW     = (float*)take((size_t)N_ * ED_ * 4);  // 5.12 MB
    int*   deg_i   = (int*)take((size_t)N_ * 4);
    int*   fill    = (int*)take((size_t)N_ * 4);
    int*   row_off = (int*)take((size_t)(N_ + 1) * 4);
    int*   perm    = (int*)take((size_t)E_ * 4);
    int*   srcp    = (int*)take((size_t)E_ * 4);
    int*   dstp    = (int*)take((size_t)E_ * 4);
    float* g       = (float*)take((size_t)N_ * 4);
    float* gden    = (float*)take((size_t)G_ * 4);
    float* hgraph  = (float*)take((size_t)G_ * D_ * 4);

    // ---- CSR build ----
    hipMemsetAsync(deg_i, 0, (size_t)N_ * 4, stream);
    hipMemsetAsync(fill, 0, (size_t)N_ * 4, stream);
    count_kernel<<<(E_ + 255) / 256, 256, 0, stream>>>(dst, deg_i);
    scan_kernel<<<1, 1024, 0, stream>>>(deg_i, row_off);
    fill_kernel<<<(E_ + 255) / 256, 256, 0, stream>>>(src, dst, row_off, fill,
                                                      perm, srcp, dstp);

    // encoders (e_cur written in CSR-permuted order)
    atom_enc<<<N_, 256, 0, stream>>>(x, atomW, atomB, hA);
    bond_enc_perm<<<(E_ * ED_ + 255) / 256, 256, 0, stream>>>(eattr, bondW, bondB,
                                                              perm, e_cur);

    const float* h_prev = hA;
    for (int l = 0; l < L_; ++l) {
        const float* Wl_l = Wl + (size_t)l * D_ * D_;
        const float* bl_l = bl + (size_t)l * D_;
        const float* Wr_l = Wr + (size_t)l * D_ * D_;
        const float* br_l = br + (size_t)l * D_;
        const float* We_l = We + (size_t)l * ED_ * D_;
        const float* att_l = att + (size_t)l * H_ * C_;
        const float* bias_l = bias + (size_t)l * D_;
        const float* ln1s_l = ln1s + (size_t)l * D_;
        const float* ln1b_l = ln1b + (size_t)l * D_;
        const float* eW_l = eW + (size_t)l * (2 * D_ + ED_) * ED_;
        const float* eb_l = eb + (size_t)l * ED_;
        const float* ln2s_l = ln2s + (size_t)l * ED_;
        const float* ln2b_l = ln2b + (size_t)l * ED_;
        float* hn_l = (l & 1) ? hA : hB;

        {
            DenseA a{h_prev, D_};
            dim3 grid((N_ + TBM - 1) / TBM, D_ / TBN);
            gemm64<DenseA><<<grid, 256, 0, stream>>>(a, Wl_l, bl_l, xl, N_, D_, D_, 0);
            gemm64<DenseA><<<grid, 256, 0, stream>>>(a, Wr_l, br_l, xr, N_, D_, D_, 0);
        }

        gat_fused<<<N_, 256, 0, stream>>>(xl, xr, e_cur, row_off, srcp,
                                          We_l, att_l, bias_l, ln1s_l, ln1b_l, hn_l);

        // factored edge MLP: hsW = hn@eW[0:256], hdW = hn@eW[256:512]
        {
            DenseA a{hn_l, D_};
            dim3 grid((N_ + TBM - 1) / TBM, 1);
            gemm64<DenseA><<<grid, 256, 0, stream>>>(a, eW_l, nullptr, hsW, N_, D_, ED_, 0);
            gemm64<DenseA><<<grid, 256, 0, stream>>>(a, eW_l + (size_t)D_ * ED_, nullptr,
                                                     hdW, N_, D_, ED_, 0);
        }
        edge_mlp_fused<<<E_ / 64, 256, 0, stream>>>(hsW, hdW, e_cur, srcp, dstp,
                                                    eW_l + (size_t)2 * D_ * ED_,
                                                    eb_l, ln2s_l, ln2b_l);

        // incremental JK: jkacc (+)= hn_l @ jkW[l*256:(l+1)*256]
        {
            DenseA a{hn_l, D_};
            dim3 grid((N_ + TBM - 1) / TBM, D_ / TBN);
            gemm64<DenseA><<<grid, 256, 0, stream>>>(a, jkW + (size_t)l * D_ * D_,
                                                     (l == 0) ? jkb : nullptr,
                                                     jkacc, N_, D_, D_, (l == 0) ? 0 : 1);
        }

        h_prev = hn_l;
    }

    float* hfin = xl;
    node_silu_ln<<<N_, 256, 0, stream>>>(jkacc, ln3s, ln3b, hfin);

    hipMemsetAsync(gden, 0, (size_t)G_ * 4, stream);
    hipMemsetAsync(hgraph, 0, (size_t)G_ * D_ * 4, stream);
    gate_kernel<<<N_, 128, 0, stream>>>(hfin, gW1, gb1, gW2, gb2, batch, g, gden);
    pool_kernel<<<(N_ * D_ + 255) / 256, 256, 0, stream>>>(hfin, g, gden, batch, hgraph);
    head_kernel<<<G_, 256, 0, stream>>>(hgraph, hW, hb, (float*)d_out);
}

// Round 5
// 4709.025 us; speedup vs baseline: 2.5606x; 1.0551x over previous
//
#include <hip/hip_runtime.h>
#include <hip/hip_bf16.h>

// Problem constants
#define N_ 20000
#define E_ 320000
#define G_ 128
#define H_ 4
#define C_ 64
#define D_ 256
#define ED_ 64
#define L_ 4

#define TBM 64
#define TBN 64
#define TBK 32

// ---------------- encoders ----------------
__global__ __launch_bounds__(256) void atom_enc(const float* __restrict__ x,
                                                const float* __restrict__ W,
                                                const float* __restrict__ b,
                                                float* __restrict__ h) {
    int n = blockIdx.x, t = threadIdx.x;
    float acc = b[t];
#pragma unroll
    for (int k = 0; k < 9; ++k) acc += x[n * 9 + k] * W[k * D_ + t];
    h[(size_t)n * D_ + t] = acc;
}

// bond encoder writing into CSR-permuted order: e[pos] = enc(edge_attr[perm[pos]])
__global__ __launch_bounds__(256) void bond_enc_perm(const float* __restrict__ ea,
                                                     const float* __restrict__ W,
                                                     const float* __restrict__ b,
                                                     const int* __restrict__ perm,
                                                     float* __restrict__ e) {
    int idx = blockIdx.x * 256 + threadIdx.x;
    if (idx >= E_ * ED_) return;
    int pos = idx >> 6, j = idx & 63;
    int orig = perm[pos];
    float acc = b[j];
#pragma unroll
    for (int k = 0; k < 3; ++k) acc += ea[orig * 3 + k] * W[k * ED_ + j];
    e[idx] = acc;
}

// ---------------- CSR build (dst-sorted) ----------------
__global__ __launch_bounds__(256) void count_kernel(const int* __restrict__ dst,
                                                    int* __restrict__ deg) {
    int e = blockIdx.x * 256 + threadIdx.x;
    if (e >= E_) return;
    atomicAdd(&deg[dst[e]], 1);
}

__global__ __launch_bounds__(1024) void scan_kernel(const int* __restrict__ deg,
                                                    int* __restrict__ row_off) {
    __shared__ int part[1024];
    int t = threadIdx.x;
    const int CH = (N_ + 1023) / 1024;  // 20
    int s = 0;
    for (int i = 0; i < CH; ++i) {
        int idx = t * CH + i;
        if (idx < N_) s += deg[idx];
    }
    part[t] = s;
    __syncthreads();
    for (int off = 1; off < 1024; off <<= 1) {
        int v = (t >= off) ? part[t - off] : 0;
        __syncthreads();
        part[t] += v;
        __syncthreads();
    }
    int base = (t == 0) ? 0 : part[t - 1];
    for (int i = 0; i < CH; ++i) {
        int idx = t * CH + i;
        if (idx < N_) { row_off[idx] = base; base += deg[idx]; }
    }
    if (t == 0) row_off[N_] = part[1023];
}

__global__ __launch_bounds__(256) void fill_kernel(const int* __restrict__ src,
                                                   const int* __restrict__ dst,
                                                   const int* __restrict__ row_off,
                                                   int* __restrict__ fill,
                                                   int* __restrict__ perm,
                                                   int* __restrict__ srcp,
                                                   int* __restrict__ dstp) {
    int e = blockIdx.x * 256 + threadIdx.x;
    if (e >= E_) return;
    int d = dst[e];
    int pos = row_off[d] + atomicAdd(&fill[d], 1);
    perm[pos] = e;
    srcp[pos] = src[e];
    dstp[pos] = d;
}

// ---------------- generic tiled f32 GEMM: C (=|+=) A @ B (+ bias) ----------------
struct DenseA {
    const float* A; int K;
    __device__ float operator()(int r, int k) const { return A[(size_t)r * K + k]; }
};

template <typename AFetch>
__global__ __launch_bounds__(256) void gemm64(AFetch af, const float* __restrict__ B,
                                              const float* __restrict__ bias,
                                              float* __restrict__ C,
                                              int M, int K, int Nn, int accum) {
    __shared__ float As[TBK][TBM + 1];
    __shared__ float Bs[TBK][TBN];
    int t = threadIdx.x;
    int bm = blockIdx.x * TBM;
    int bn = blockIdx.y * TBN;
    int tx = t & 15, ty = t >> 4;
    float acc[4][4] = {};
    for (int k0 = 0; k0 < K; k0 += TBK) {
#pragma unroll
        for (int i = 0; i < 8; ++i) {
            int lid = t + 256 * i;
            int r = lid >> 5, kk = lid & 31;
            int row = bm + r;
            As[kk][r] = (row < M) ? af(row, k0 + kk) : 0.f;
        }
#pragma unroll
        for (int i = 0; i < 8; ++i) {
            int lid = t + 256 * i;
            int kk = lid >> 6, c = lid & 63;
            if (c < Nn) Bs[kk][c] = B[(size_t)(k0 + kk) * Nn + (bn + c)];
        }
        __syncthreads();
#pragma unroll
        for (int kk = 0; kk < TBK; ++kk) {
            float a[4], b[4];
#pragma unroll
            for (int i = 0; i < 4; ++i) a[i] = As[kk][ty * 4 + i];
#pragma unroll
            for (int j = 0; j < 4; ++j) b[j] = Bs[kk][tx * 4 + j];
#pragma unroll
            for (int i = 0; i < 4; ++i)
#pragma unroll
                for (int j = 0; j < 4; ++j) acc[i][j] += a[i] * b[j];
        }
        __syncthreads();
    }
#pragma unroll
    for (int i = 0; i < 4; ++i) {
        int row = bm + ty * 4 + i;
        if (row >= M) continue;
#pragma unroll
        for (int j = 0; j < 4; ++j) {
            int col = bn + tx * 4 + j;
            if (col >= Nn) continue;
            float v = acc[i][j] + (bias ? bias[col] : 0.f);
            if (accum) C[(size_t)row * Nn + col] += v;
            else       C[(size_t)row * Nn + col] = v;
        }
    }
}

// ---------------- fused per-dst GATv2 layer (barrier-free, wave-per-head) ----
// One block per dst node; wave w == head w. Each wave independently streams all
// CSR edges of d: loads the e-row itself, stages it in a PRIVATE per-wave LDS
// slot (wave-coherent, no __syncthreads), gathers its 64-feature slice of
// xl[src], and keeps head-local wsum/den/out. Single barrier before the LN
// epilogue. Math identical to the previous version.
__global__ __launch_bounds__(256) void gat_fused(const float* __restrict__ xl,
                                                 const float* __restrict__ xr,
                                                 const float* __restrict__ e,
                                                 const int* __restrict__ row_off,
                                                 const int* __restrict__ srcp,
                                                 const float* __restrict__ We,
                                                 const float* __restrict__ att,
                                                 const float* __restrict__ bias,
                                                 const float* __restrict__ gs,
                                                 const float* __restrict__ gb,
                                                 float* __restrict__ hn) {
    int d = blockIdx.x, t = threadIdx.x;
    int w = t >> 6, lane = t & 63;   // wave == head
    int beg = row_off[d], end = row_off[d + 1];
    int deg = end - beg;
    float av = att[w * C_ + lane];
    float wreg[64];
#pragma unroll
    for (int k = 0; k < 64; ++k) wreg[k] = We[k * D_ + t];
    float xr_d = xr[(size_t)d * D_ + t];
    float xl_d = xl[(size_t)d * D_ + t];
    float wsum = 0.f, den = 0.f, out = 0.f;
    __shared__ float es[4][2][ED_];
    int i = beg;
    for (; i + 2 <= end; i += 2) {
        int s0 = srcp[i], s1 = srcp[i + 1];
        float ev0 = e[(size_t)i * ED_ + lane];
        float ev1 = e[(size_t)(i + 1) * ED_ + lane];
        float xls0 = xl[(size_t)s0 * D_ + t];
        float xls1 = xl[(size_t)s1 * D_ + t];
        es[w][0][lane] = ev0;
        es[w][1][lane] = ev1;
        float a0 = 0.f, a1 = 0.f;
#pragma unroll
        for (int k0 = 0; k0 < 64; k0 += 4) {
            const float4 p = *(const float4*)&es[w][0][k0];
            const float4 q = *(const float4*)&es[w][1][k0];
            a0 += p.x * wreg[k0] + p.y * wreg[k0 + 1] + p.z * wreg[k0 + 2] + p.w * wreg[k0 + 3];
            a1 += q.x * wreg[k0] + q.y * wreg[k0 + 1] + q.z * wreg[k0 + 2] + q.w * wreg[k0 + 3];
        }
        wsum += a0 + a1;
        float m0 = xls0 + xr_d + a0; m0 = (m0 > 0.f) ? m0 : 0.2f * m0;
        float m1 = xls1 + xr_d + a1; m1 = (m1 > 0.f) ? m1 : 0.2f * m1;
        float v0 = m0 * av, v1 = m1 * av;
#pragma unroll
        for (int o = 32; o; o >>= 1) { v0 += __shfl_xor(v0, o); v1 += __shfl_xor(v1, o); }
        float ex0 = expf(v0), ex1 = expf(v1);
        den += ex0 + ex1;
        out += ex0 * xls0 + ex1 * xls1;
    }
    if (i < end) {  // tail edge
        int s0 = srcp[i];
        float ev0 = e[(size_t)i * ED_ + lane];
        float xls0 = xl[(size_t)s0 * D_ + t];
        es[w][0][lane] = ev0;
        float a0 = 0.f;
#pragma unroll
        for (int k0 = 0; k0 < 64; k0 += 4) {
            const float4 p = *(const float4*)&es[w][0][k0];
            a0 += p.x * wreg[k0] + p.y * wreg[k0 + 1] + p.z * wreg[k0 + 2] + p.w * wreg[k0 + 3];
        }
        wsum += a0;
        float m0 = xls0 + xr_d + a0; m0 = (m0 > 0.f) ? m0 : 0.2f * m0;
        float v0 = m0 * av;
#pragma unroll
        for (int o = 32; o; o >>= 1) v0 += __shfl_xor(v0, o);
        float ex0 = expf(v0);
        den += ex0;
        out += ex0 * xls0;
    }
    // self loop: loop_e@We = mean over incoming of ef@We (linearity)
    float loopW = (deg > 0) ? wsum / (float)deg : 0.f;
    {
        float m = xl_d + xr_d + loopW;
        m = (m > 0.f) ? m : 0.2f * m;
        float v = m * av;
#pragma unroll
        for (int o = 32; o; o >>= 1) v += __shfl_xor(v, o);
        float eself = expf(v);
        den += eself;
        out += eself * xl_d;
    }
    out *= 1.f / (den + 1e-16f);
    // epilogue: bias + silu + LN over 256 features (single block-wide barrier)
    float v = out + bias[t];
    v = v / (1.f + expf(-v));
    __shared__ float red[4];
    float s = v;
#pragma unroll
    for (int o = 32; o; o >>= 1) s += __shfl_xor(s, o);
    if (lane == 0) red[w] = s;
    __syncthreads();
    float mu = (red[0] + red[1] + red[2] + red[3]) * (1.f / 256.f);
    __syncthreads();
    float dv = v - mu;
    float q = dv * dv;
#pragma unroll
    for (int o = 32; o; o >>= 1) q += __shfl_xor(q, o);
    if (lane == 0) red[w] = q;
    __syncthreads();
    float var = (red[0] + red[1] + red[2] + red[3]) * (1.f / 256.f);
    hn[(size_t)d * D_ + t] = dv * rsqrtf(var + 1e-5f) * gs[t] + gb[t];
}

// ---------------- factored edge MLP + silu + LN (in-place into e) ----------------
// out = LN(silu(hsW[src] + hdW[dst] + e@eW3 + eb)); eW3 column in 64 VGPRs.
__global__ __launch_bounds__(256) void edge_mlp_fused(const float* __restrict__ hsW,
                                                      const float* __restrict__ hdW,
                                                      float* __restrict__ e,
                                                      const int* __restrict__ srcp,
                                                      const int* __restrict__ dstp,
                                                      const float* __restrict__ eW3,
                                                      const float* __restrict__ eb,
                                                      const float* __restrict__ gs,
                                                      const float* __restrict__ gb) {
    int t = threadIdx.x;
    int w = t >> 6, lane = t & 63;
    float wreg[64];
#pragma unroll
    for (int k = 0; k < 64; ++k) wreg[k] = eW3[k * ED_ + lane];
    float ebv = eb[lane], gsv = gs[lane], gbv = gb[lane];
    __shared__ float es[4][ED_];
    int base = blockIdx.x * 64;
    for (int it = 0; it < 16; ++it) {
        int edge = base + it * 4 + w;
        float ev = e[(size_t)edge * ED_ + lane];
        es[w][lane] = ev;  // wave-local slot; wave-coherent LDS, no barrier
        float acc = ebv + hsW[(size_t)srcp[edge] * ED_ + lane]
                        + hdW[(size_t)dstp[edge] * ED_ + lane];
#pragma unroll
        for (int k0 = 0; k0 < 64; k0 += 4) {
            const float4 e4 = *(const float4*)&es[w][k0];
            acc += e4.x * wreg[k0] + e4.y * wreg[k0 + 1] +
                   e4.z * wreg[k0 + 2] + e4.w * wreg[k0 + 3];
        }
        // silu + LN over 64 lanes (one wave per edge)
        float v = acc / (1.f + expf(-acc));
        float s = v;
#pragma unroll
        for (int o = 32; o; o >>= 1) s += __shfl_xor(s, o);
        float mu = s * (1.f / 64.f);
        float dv = v - mu;
        float q = dv * dv;
#pragma unroll
        for (int o = 32; o; o >>= 1) q += __shfl_xor(q, o);
        float rs = rsqrtf(q * (1.f / 64.f) + 1e-5f);
        e[(size_t)edge * ED_ + lane] = dv * rs * gsv + gbv;
    }
}

// ---------------- node silu + LN (final JK output) ----------------
__global__ __launch_bounds__(256) void node_silu_ln(const float* __restrict__ inp,
                                                    const float* __restrict__ gs,
                                                    const float* __restrict__ gb,
                                                    float* __restrict__ outp) {
    int n = blockIdx.x, t = threadIdx.x;
    float v = inp[(size_t)n * D_ + t];
    v = v / (1.f + expf(-v));
    __shared__ float red[4];
    float s = v;
#pragma unroll
    for (int o = 32; o; o >>= 1) s += __shfl_xor(s, o);
    if ((t & 63) == 0) red[t >> 6] = s;
    __syncthreads();
    float mu = (red[0] + red[1] + red[2] + red[3]) * (1.f / 256.f);
    __syncthreads();
    float dv = v - mu;
    float q = dv * dv;
#pragma unroll
    for (int o = 32; o; o >>= 1) q += __shfl_xor(q, o);
    if ((t & 63) == 0) red[t >> 6] = q;
    __syncthreads();
    float var = (red[0] + red[1] + red[2] + red[3]) * (1.f / 256.f);
    outp[(size_t)n * D_ + t] = dv * rsqrtf(var + 1e-5f) * gs[t] + gb[t];
}

// ---------------- gate MLP + softmax denom ----------------
__global__ __launch_bounds__(128) void gate_kernel(const float* __restrict__ h,
                                                   const float* __restrict__ gW1,
                                                   const float* __restrict__ gb1,
                                                   const float* __restrict__ gW2,
                                                   const float* __restrict__ gb2,
                                                   const int* __restrict__ batch,
                                                   float* __restrict__ g,
                                                   float* __restrict__ gden) {
    int n = blockIdx.x, t = threadIdx.x; // 128 threads
    const float* hn = h + (size_t)n * D_;
    float acc = gb1[t];
    for (int k = 0; k < D_; ++k) acc += hn[k] * gW1[k * 128 + t];
    acc = acc / (1.f + expf(-acc));
    float v = acc * gW2[t];
#pragma unroll
    for (int o = 32; o; o >>= 1) v += __shfl_xor(v, o);
    __shared__ float r2[2];
    if ((t & 63) == 0) r2[t >> 6] = v;
    __syncthreads();
    if (t == 0) {
        float gg = r2[0] + r2[1] + gb2[0];
        g[n] = gg;
        atomicAdd(&gden[batch[n]], expf(gg));
    }
}

__global__ __launch_bounds__(256) void pool_kernel(const float* __restrict__ h,
                                                   const float* __restrict__ g,
                                                   const float* __restrict__ gden,
                                                   const int* __restrict__ batch,
                                                   float* __restrict__ hgraph) {
    int idx = blockIdx.x * 256 + threadIdx.x;
    if (idx >= N_ * D_) return;
    int n = idx >> 8;
    int b = batch[n];
    float w = expf(g[n]) / (gden[b] + 1e-16f);
    atomicAdd(&hgraph[(size_t)b * D_ + (idx & 255)], w * h[idx]);
}

__global__ __launch_bounds__(256) void head_kernel(const float* __restrict__ hgraph,
                                                   const float* __restrict__ hW,
                                                   const float* __restrict__ hb,
                                                   float* __restrict__ out) {
    int gp = blockIdx.x, t = threadIdx.x;
    float v = hgraph[(size_t)gp * D_ + t] * hW[t];
#pragma unroll
    for (int o = 32; o; o >>= 1) v += __shfl_xor(v, o);
    __shared__ float r4[4];
    if ((t & 63) == 0) r4[t >> 6] = v;
    __syncthreads();
    if (t == 0) out[gp] = r4[0] + r4[1] + r4[2] + r4[3] + hb[0];
}

// ---------------- host launch ----------------
extern "C" void kernel_launch(void* const* d_in, const int* in_sizes, int n_in,
                              void* d_out, int out_size, void* d_ws, size_t ws_size,
                              hipStream_t stream) {
    const float* x     = (const float*)d_in[0];
    const int*   eidx  = (const int*)d_in[1];
    const float* eattr = (const float*)d_in[2];
    const int*   batch = (const int*)d_in[3];
    const float* atomW = (const float*)d_in[4];
    const float* atomB = (const float*)d_in[5];
    const float* bondW = (const float*)d_in[6];
    const float* bondB = (const float*)d_in[7];
    const float* Wl    = (const float*)d_in[8];
    const float* bl    = (const float*)d_in[9];
    const float* Wr    = (const float*)d_in[10];
    const float* br    = (const float*)d_in[11];
    const float* We    = (const float*)d_in[12];
    const float* att   = (const float*)d_in[13];
    const float* bias  = (const float*)d_in[14];
    const float* ln1s  = (const float*)d_in[15];
    const float* ln1b  = (const float*)d_in[16];
    const float* eW    = (const float*)d_in[17];
    const float* eb    = (const float*)d_in[18];
    const float* ln2s  = (const float*)d_in[19];
    const float* ln2b  = (const float*)d_in[20];
    const float* jkW   = (const float*)d_in[21];
    const float* jkb   = (const float*)d_in[22];
    const float* ln3s  = (const float*)d_in[23];
    const float* ln3b  = (const float*)d_in[24];
    const float* gW1   = (const float*)d_in[25];
    const float* gb1   = (const float*)d_in[26];
    const float* gW2   = (const float*)d_in[27];
    const float* gb2   = (const float*)d_in[28];
    const float* hW    = (const float*)d_in[29];
    const float* hb    = (const float*)d_in[30];

    const int* src = eidx;
    const int* dst = eidx + E_;

    // ---- workspace layout (~200 MB) ----
    char* wp = (char*)d_ws;
    auto take = [&](size_t bytes) {
        char* p = wp;
        wp += (bytes + 255) & ~(size_t)255;
        return (void*)p;
    };
    float* e_cur   = (float*)take((size_t)E_ * ED_ * 4);  // 81.92 MB, CSR-permuted
    float* hA      = (float*)take((size_t)N_ * D_ * 4);   // 20.48 MB
    float* hB      = (float*)take((size_t)N_ * D_ * 4);   // 20.48 MB
    float* xl      = (float*)take((size_t)N_ * D_ * 4);   // 20.48 MB (hfin at end)
    float* xr      = (float*)take((size_t)N_ * D_ * 4);   // 20.48 MB
    float* jkacc   = (float*)take((size_t)N_ * D_ * 4);   // 20.48 MB
    float* hsW     = (float*)take((size_t)N_ * ED_ * 4);  // 5.12 MB
    float* hdW     = (float*)take((size_t)N_ * ED_ * 4);  // 5.12 MB
    int*   deg_i   = (int*)take((size_t)N_ * 4);
    int*   fill    = (int*)take((size_t)N_ * 4);
    int*   row_off = (int*)take((size_t)(N_ + 1) * 4);
    int*   perm    = (int*)take((size_t)E_ * 4);
    int*   srcp    = (int*)take((size_t)E_ * 4);
    int*   dstp    = (int*)take((size_t)E_ * 4);
    float* g       = (float*)take((size_t)N_ * 4);
    float* gden    = (float*)take((size_t)G_ * 4);
    float* hgraph  = (float*)take((size_t)G_ * D_ * 4);

    // ---- CSR build ----
    hipMemsetAsync(deg_i, 0, (size_t)N_ * 4, stream);
    hipMemsetAsync(fill, 0, (size_t)N_ * 4, stream);
    count_kernel<<<(E_ + 255) / 256, 256, 0, stream>>>(dst, deg_i);
    scan_kernel<<<1, 1024, 0, stream>>>(deg_i, row_off);
    fill_kernel<<<(E_ + 255) / 256, 256, 0, stream>>>(src, dst, row_off, fill,
                                                      perm, srcp, dstp);

    // encoders (e_cur written in CSR-permuted order)
    atom_enc<<<N_, 256, 0, stream>>>(x, atomW, atomB, hA);
    bond_enc_perm<<<(E_ * ED_ + 255) / 256, 256, 0, stream>>>(eattr, bondW, bondB,
                                                              perm, e_cur);

    const float* h_prev = hA;
    for (int l = 0; l < L_; ++l) {
        const float* Wl_l = Wl + (size_t)l * D_ * D_;
        const float* bl_l = bl + (size_t)l * D_;
        const float* Wr_l = Wr + (size_t)l * D_ * D_;
        const float* br_l = br + (size_t)l * D_;
        const float* We_l = We + (size_t)l * ED_ * D_;
        const float* att_l = att + (size_t)l * H_ * C_;
        const float* bias_l = bias + (size_t)l * D_;
        const float* ln1s_l = ln1s + (size_t)l * D_;
        const float* ln1b_l = ln1b + (size_t)l * D_;
        const float* eW_l = eW + (size_t)l * (2 * D_ + ED_) * ED_;
        const float* eb_l = eb + (size_t)l * ED_;
        const float* ln2s_l = ln2s + (size_t)l * ED_;
        const float* ln2b_l = ln2b + (size_t)l * ED_;
        float* hn_l = (l & 1) ? hA : hB;

        {
            DenseA a{h_prev, D_};
            dim3 grid((N_ + TBM - 1) / TBM, D_ / TBN);
            gemm64<DenseA><<<grid, 256, 0, stream>>>(a, Wl_l, bl_l, xl, N_, D_, D_, 0);
            gemm64<DenseA><<<grid, 256, 0, stream>>>(a, Wr_l, br_l, xr, N_, D_, D_, 0);
        }

        gat_fused<<<N_, 256, 0, stream>>>(xl, xr, e_cur, row_off, srcp,
                                          We_l, att_l, bias_l, ln1s_l, ln1b_l, hn_l);

        // factored edge MLP: hsW = hn@eW[0:256], hdW = hn@eW[256:512]
        {
            DenseA a{hn_l, D_};
            dim3 grid((N_ + TBM - 1) / TBM, 1);
            gemm64<DenseA><<<grid, 256, 0, stream>>>(a, eW_l, nullptr, hsW, N_, D_, ED_, 0);
            gemm64<DenseA><<<grid, 256, 0, stream>>>(a, eW_l + (size_t)D_ * ED_, nullptr,
                                                     hdW, N_, D_, ED_, 0);
        }
        edge_mlp_fused<<<E_ / 64, 256, 0, stream>>>(hsW, hdW, e_cur, srcp, dstp,
                                                    eW_l + (size_t)2 * D_ * ED_,
                                                    eb_l, ln2s_l, ln2b_l);

        // incremental JK: jkacc (+)= hn_l @ jkW[l*256:(l+1)*256]
        {
            DenseA a{hn_l, D_};
            dim3 grid((N_ + TBM - 1) / TBM, D_ / TBN);
            gemm64<DenseA><<<grid, 256, 0, stream>>>(a, jkW + (size_t)l * D_ * D_,
                                                     (l == 0) ? jkb : nullptr,
                                                     jkacc, N_, D_, D_, (l == 0) ? 0 : 1);
        }

        h_prev = hn_l;
    }

    float* hfin = xl;
    node_silu_ln<<<N_, 256, 0, stream>>>(jkacc, ln3s, ln3b, hfin);

    hipMemsetAsync(gden, 0, (size_t)G_ * 4, stream);
    hipMemsetAsync(hgraph, 0, (size_t)G_ * D_ * 4, stream);
    gate_kernel<<<N_, 128, 0, stream>>>(hfin, gW1, gb1, gW2, gb2, batch, g, gden);
    pool_kernel<<<(N_ * D_ + 255) / 256, 256, 0, stream>>>(hfin, g, gden, batch, hgraph);
    head_kernel<<<G_, 256, 0, stream>>>(hgraph, hW, hb, (float*)d_out);
}

// Round 6
// 3726.078 us; speedup vs baseline: 3.2361x; 1.2638x over previous
//
#include <hip/hip_runtime.h>
#include <hip/hip_bf16.h>

// Problem constants
#define N_ 20000
#define E_ 320000
#define G_ 128
#define H_ 4
#define C_ 64
#define D_ 256
#define ED_ 64
#define L_ 4

#define TBM 64
#define TBN 64
#define TBK 32

// ---------------- encoders ----------------
__global__ __launch_bounds__(256) void atom_enc(const float* __restrict__ x,
                                                const float* __restrict__ W,
                                                const float* __restrict__ b,
                                                float* __restrict__ h) {
    int n = blockIdx.x, t = threadIdx.x;
    float acc = b[t];
#pragma unroll
    for (int k = 0; k < 9; ++k) acc += x[n * 9 + k] * W[k * D_ + t];
    h[(size_t)n * D_ + t] = acc;
}

// bond encoder writing into CSR-permuted order: e[pos] = enc(edge_attr[perm[pos]])
__global__ __launch_bounds__(256) void bond_enc_perm(const float* __restrict__ ea,
                                                     const float* __restrict__ W,
                                                     const float* __restrict__ b,
                                                     const int* __restrict__ perm,
                                                     float* __restrict__ e) {
    int idx = blockIdx.x * 256 + threadIdx.x;
    if (idx >= E_ * ED_) return;
    int pos = idx >> 6, j = idx & 63;
    int orig = perm[pos];
    float acc = b[j];
#pragma unroll
    for (int k = 0; k < 3; ++k) acc += ea[orig * 3 + k] * W[k * ED_ + j];
    e[idx] = acc;
}

// ---------------- CSR build (dst-sorted) ----------------
__global__ __launch_bounds__(256) void count_kernel(const int* __restrict__ dst,
                                                    int* __restrict__ deg) {
    int e = blockIdx.x * 256 + threadIdx.x;
    if (e >= E_) return;
    atomicAdd(&deg[dst[e]], 1);
}

__global__ __launch_bounds__(1024) void scan_kernel(const int* __restrict__ deg,
                                                    int* __restrict__ row_off) {
    __shared__ int part[1024];
    int t = threadIdx.x;
    const int CH = (N_ + 1023) / 1024;  // 20
    int s = 0;
    for (int i = 0; i < CH; ++i) {
        int idx = t * CH + i;
        if (idx < N_) s += deg[idx];
    }
    part[t] = s;
    __syncthreads();
    for (int off = 1; off < 1024; off <<= 1) {
        int v = (t >= off) ? part[t - off] : 0;
        __syncthreads();
        part[t] += v;
        __syncthreads();
    }
    int base = (t == 0) ? 0 : part[t - 1];
    for (int i = 0; i < CH; ++i) {
        int idx = t * CH + i;
        if (idx < N_) { row_off[idx] = base; base += deg[idx]; }
    }
    if (t == 0) row_off[N_] = part[1023];
}

__global__ __launch_bounds__(256) void fill_kernel(const int* __restrict__ src,
                                                   const int* __restrict__ dst,
                                                   const int* __restrict__ row_off,
                                                   int* __restrict__ fill,
                                                   int* __restrict__ perm,
                                                   int* __restrict__ srcp,
                                                   int* __restrict__ dstp) {
    int e = blockIdx.x * 256 + threadIdx.x;
    if (e >= E_) return;
    int d = dst[e];
    int pos = row_off[d] + atomicAdd(&fill[d], 1);
    perm[pos] = e;
    srcp[pos] = src[e];
    dstp[pos] = d;
}

// ---------------- generic tiled f32 GEMM: C (=|+=) A @ B (+ bias) ----------------
struct DenseA {
    const float* A; int K;
    __device__ float operator()(int r, int k) const { return A[(size_t)r * K + k]; }
};

template <typename AFetch>
__global__ __launch_bounds__(256) void gemm64(AFetch af, const float* __restrict__ B,
                                              const float* __restrict__ bias,
                                              float* __restrict__ C,
                                              int M, int K, int Nn, int accum) {
    __shared__ float As[TBK][TBM + 1];
    __shared__ float Bs[TBK][TBN];
    int t = threadIdx.x;
    int bm = blockIdx.x * TBM;
    int bn = blockIdx.y * TBN;
    int tx = t & 15, ty = t >> 4;
    float acc[4][4] = {};
    for (int k0 = 0; k0 < K; k0 += TBK) {
#pragma unroll
        for (int i = 0; i < 8; ++i) {
            int lid = t + 256 * i;
            int r = lid >> 5, kk = lid & 31;
            int row = bm + r;
            As[kk][r] = (row < M) ? af(row, k0 + kk) : 0.f;
        }
#pragma unroll
        for (int i = 0; i < 8; ++i) {
            int lid = t + 256 * i;
            int kk = lid >> 6, c = lid & 63;
            if (c < Nn) Bs[kk][c] = B[(size_t)(k0 + kk) * Nn + (bn + c)];
        }
        __syncthreads();
#pragma unroll
        for (int kk = 0; kk < TBK; ++kk) {
            float a[4], b[4];
#pragma unroll
            for (int i = 0; i < 4; ++i) a[i] = As[kk][ty * 4 + i];
#pragma unroll
            for (int j = 0; j < 4; ++j) b[j] = Bs[kk][tx * 4 + j];
#pragma unroll
            for (int i = 0; i < 4; ++i)
#pragma unroll
                for (int j = 0; j < 4; ++j) acc[i][j] += a[i] * b[j];
        }
        __syncthreads();
    }
#pragma unroll
    for (int i = 0; i < 4; ++i) {
        int row = bm + ty * 4 + i;
        if (row >= M) continue;
#pragma unroll
        for (int j = 0; j < 4; ++j) {
            int col = bn + tx * 4 + j;
            if (col >= Nn) continue;
            float v = acc[i][j] + (bias ? bias[col] : 0.f);
            if (accum) C[(size_t)row * Nn + col] += v;
            else       C[(size_t)row * Nn + col] = v;
        }
    }
}

// ---------------- phase A: edge-parallel GATv2 exp-logits ----------------
// Block = 64 consecutive CSR edges; wave w = head w. e reads are sequential,
// xr[dst] nearly sequential (CSR is dst-sorted), xl[src] random but hidden by
// edge-level TLP. Writes exp(logit) to exlog[E][H].
__global__ __launch_bounds__(256) void edge_logits2(const float* __restrict__ xl,
                                                    const float* __restrict__ xr,
                                                    const float* __restrict__ e,
                                                    const int* __restrict__ srcp,
                                                    const int* __restrict__ dstp,
                                                    const float* __restrict__ We,
                                                    const float* __restrict__ att,
                                                    float* __restrict__ exlog) {
    int t = threadIdx.x;
    int w = t >> 6, lane = t & 63;
    float wreg[64];
#pragma unroll
    for (int k = 0; k < 64; ++k) wreg[k] = We[k * D_ + t];
    float av = att[t];  // att is [H][C] flat == 256
    __shared__ float es[4][2][ED_];
    int base = blockIdx.x * 64;
    for (int i = 0; i < 64; i += 2) {
        int e0 = base + i, e1 = base + i + 1;
        int s0 = srcp[e0], s1 = srcp[e1];
        int d0 = dstp[e0], d1 = dstp[e1];
        float ev0 = e[(size_t)e0 * ED_ + lane];
        float ev1 = e[(size_t)e1 * ED_ + lane];
        float xls0 = xl[(size_t)s0 * D_ + t];
        float xls1 = xl[(size_t)s1 * D_ + t];
        float xrd0 = xr[(size_t)d0 * D_ + t];
        float xrd1 = xr[(size_t)d1 * D_ + t];
        es[w][0][lane] = ev0;
        es[w][1][lane] = ev1;
        float a0 = 0.f, a1 = 0.f;
#pragma unroll
        for (int k0 = 0; k0 < 64; k0 += 4) {
            const float4 p = *(const float4*)&es[w][0][k0];
            const float4 q = *(const float4*)&es[w][1][k0];
            a0 += p.x * wreg[k0] + p.y * wreg[k0 + 1] + p.z * wreg[k0 + 2] + p.w * wreg[k0 + 3];
            a1 += q.x * wreg[k0] + q.y * wreg[k0 + 1] + q.z * wreg[k0 + 2] + q.w * wreg[k0 + 3];
        }
        float m0 = xls0 + xrd0 + a0; m0 = (m0 > 0.f) ? m0 : 0.2f * m0;
        float m1 = xls1 + xrd1 + a1; m1 = (m1 > 0.f) ? m1 : 0.2f * m1;
        float v0 = m0 * av, v1 = m1 * av;
#pragma unroll
        for (int o = 32; o; o >>= 1) { v0 += __shfl_xor(v0, o); v1 += __shfl_xor(v1, o); }
        if (lane == 0) {
            exlog[(size_t)e0 * H_ + w] = expf(v0);
            exlog[(size_t)e1 * H_ + w] = expf(v1);
        }
    }
}

// ---------------- esum: per-dst segment sum of e rows (for self-loop) --------
__global__ __launch_bounds__(256) void esum_kernel(const float* __restrict__ e,
                                                   const int* __restrict__ row_off,
                                                   float* __restrict__ esum) {
    int d = blockIdx.x * 4 + (threadIdx.x >> 6);
    int lane = threadIdx.x & 63;
    if (d >= N_) return;
    int beg = row_off[d], end = row_off[d + 1];
    float s = 0.f;
    for (int i = beg; i < end; ++i) s += e[(size_t)i * ED_ + lane];
    esum[(size_t)d * ED_ + lane] = s;
}

// ---------------- phase B: per-dst softmax + aggregation + silu/LN ----------
// Light per-edge work: broadcast exlog scalar + one xl[src] gather + fma.
__global__ __launch_bounds__(256) void gat_agg(const float* __restrict__ xl,
                                               const float* __restrict__ xr,
                                               const float* __restrict__ loopW,
                                               const int* __restrict__ row_off,
                                               const int* __restrict__ srcp,
                                               const float* __restrict__ exlog,
                                               const float* __restrict__ att,
                                               const float* __restrict__ bias,
                                               const float* __restrict__ gs,
                                               const float* __restrict__ gb,
                                               float* __restrict__ hn) {
    int d = blockIdx.x, t = threadIdx.x;
    int w = t >> 6, lane = t & 63;
    int beg = row_off[d], end = row_off[d + 1];
    int deg = end - beg;
    float av = att[t];
    float xld = xl[(size_t)d * D_ + t];
    float xrd = xr[(size_t)d * D_ + t];
    float den = 0.f, out = 0.f;
    int i = beg;
    for (; i + 4 <= end; i += 4) {
        int s0 = srcp[i], s1 = srcp[i + 1], s2 = srcp[i + 2], s3 = srcp[i + 3];
        float ex0 = exlog[(size_t)i * H_ + w];
        float ex1 = exlog[(size_t)(i + 1) * H_ + w];
        float ex2 = exlog[(size_t)(i + 2) * H_ + w];
        float ex3 = exlog[(size_t)(i + 3) * H_ + w];
        float x0 = xl[(size_t)s0 * D_ + t];
        float x1 = xl[(size_t)s1 * D_ + t];
        float x2 = xl[(size_t)s2 * D_ + t];
        float x3 = xl[(size_t)s3 * D_ + t];
        den += (ex0 + ex1) + (ex2 + ex3);
        out += ex0 * x0 + ex1 * x1 + ex2 * x2 + ex3 * x3;
    }
    for (; i < end; ++i) {
        int s0 = srcp[i];
        float ex0 = exlog[(size_t)i * H_ + w];
        float x0 = xl[(size_t)s0 * D_ + t];
        den += ex0;
        out += ex0 * x0;
    }
    // self loop: loop_e@We = esum@We / deg (linearity)
    float lw = (deg > 0) ? loopW[(size_t)d * D_ + t] / (float)deg : 0.f;
    {
        float m = xld + xrd + lw;
        m = (m > 0.f) ? m : 0.2f * m;
        float v = m * av;
#pragma unroll
        for (int o = 32; o; o >>= 1) v += __shfl_xor(v, o);
        float eself = expf(v);
        den += eself;
        out += eself * xld;
    }
    out *= 1.f / (den + 1e-16f);
    // epilogue: bias + silu + LN over 256 features
    float v = out + bias[t];
    v = v / (1.f + expf(-v));
    __shared__ float red[4];
    float s = v;
#pragma unroll
    for (int o = 32; o; o >>= 1) s += __shfl_xor(s, o);
    if (lane == 0) red[w] = s;
    __syncthreads();
    float mu = (red[0] + red[1] + red[2] + red[3]) * (1.f / 256.f);
    __syncthreads();
    float dv = v - mu;
    float q = dv * dv;
#pragma unroll
    for (int o = 32; o; o >>= 1) q += __shfl_xor(q, o);
    if (lane == 0) red[w] = q;
    __syncthreads();
    float var = (red[0] + red[1] + red[2] + red[3]) * (1.f / 256.f);
    hn[(size_t)d * D_ + t] = dv * rsqrtf(var + 1e-5f) * gs[t] + gb[t];
}

// ---------------- factored edge MLP + silu + LN (in-place into e) ----------------
__global__ __launch_bounds__(256) void edge_mlp_fused(const float* __restrict__ hsW,
                                                      const float* __restrict__ hdW,
                                                      float* __restrict__ e,
                                                      const int* __restrict__ srcp,
                                                      const int* __restrict__ dstp,
                                                      const float* __restrict__ eW3,
                                                      const float* __restrict__ eb,
                                                      const float* __restrict__ gs,
                                                      const float* __restrict__ gb) {
    int t = threadIdx.x;
    int w = t >> 6, lane = t & 63;
    float wreg[64];
#pragma unroll
    for (int k = 0; k < 64; ++k) wreg[k] = eW3[k * ED_ + lane];
    float ebv = eb[lane], gsv = gs[lane], gbv = gb[lane];
    __shared__ float es[4][ED_];
    int base = blockIdx.x * 64;
    for (int it = 0; it < 16; ++it) {
        int edge = base + it * 4 + w;
        float ev = e[(size_t)edge * ED_ + lane];
        es[w][lane] = ev;  // wave-local slot; wave-coherent LDS, no barrier
        float acc = ebv + hsW[(size_t)srcp[edge] * ED_ + lane]
                        + hdW[(size_t)dstp[edge] * ED_ + lane];
#pragma unroll
        for (int k0 = 0; k0 < 64; k0 += 4) {
            const float4 e4 = *(const float4*)&es[w][k0];
            acc += e4.x * wreg[k0] + e4.y * wreg[k0 + 1] +
                   e4.z * wreg[k0 + 2] + e4.w * wreg[k0 + 3];
        }
        // silu + LN over 64 lanes (one wave per edge)
        float v = acc / (1.f + expf(-acc));
        float s = v;
#pragma unroll
        for (int o = 32; o; o >>= 1) s += __shfl_xor(s, o);
        float mu = s * (1.f / 64.f);
        float dv = v - mu;
        float q = dv * dv;
#pragma unroll
        for (int o = 32; o; o >>= 1) q += __shfl_xor(q, o);
        float rs = rsqrtf(q * (1.f / 64.f) + 1e-5f);
        e[(size_t)edge * ED_ + lane] = dv * rs * gsv + gbv;
    }
}

// ---------------- node silu + LN (final JK output) ----------------
__global__ __launch_bounds__(256) void node_silu_ln(const float* __restrict__ inp,
                                                    const float* __restrict__ gs,
                                                    const float* __restrict__ gb,
                                                    float* __restrict__ outp) {
    int n = blockIdx.x, t = threadIdx.x;
    float v = inp[(size_t)n * D_ + t];
    v = v / (1.f + expf(-v));
    __shared__ float red[4];
    float s = v;
#pragma unroll
    for (int o = 32; o; o >>= 1) s += __shfl_xor(s, o);
    if ((t & 63) == 0) red[t >> 6] = s;
    __syncthreads();
    float mu = (red[0] + red[1] + red[2] + red[3]) * (1.f / 256.f);
    __syncthreads();
    float dv = v - mu;
    float q = dv * dv;
#pragma unroll
    for (int o = 32; o; o >>= 1) q += __shfl_xor(q, o);
    if ((t & 63) == 0) red[t >> 6] = q;
    __syncthreads();
    float var = (red[0] + red[1] + red[2] + red[3]) * (1.f / 256.f);
    outp[(size_t)n * D_ + t] = dv * rsqrtf(var + 1e-5f) * gs[t] + gb[t];
}

// ---------------- gate MLP + softmax denom ----------------
__global__ __launch_bounds__(128) void gate_kernel(const float* __restrict__ h,
                                                   const float* __restrict__ gW1,
                                                   const float* __restrict__ gb1,
                                                   const float* __restrict__ gW2,
                                                   const float* __restrict__ gb2,
                                                   const int* __restrict__ batch,
                                                   float* __restrict__ g,
                                                   float* __restrict__ gden) {
    int n = blockIdx.x, t = threadIdx.x; // 128 threads
    const float* hn = h + (size_t)n * D_;
    float acc = gb1[t];
    for (int k = 0; k < D_; ++k) acc += hn[k] * gW1[k * 128 + t];
    acc = acc / (1.f + expf(-acc));
    float v = acc * gW2[t];
#pragma unroll
    for (int o = 32; o; o >>= 1) v += __shfl_xor(v, o);
    __shared__ float r2[2];
    if ((t & 63) == 0) r2[t >> 6] = v;
    __syncthreads();
    if (t == 0) {
        float gg = r2[0] + r2[1] + gb2[0];
        g[n] = gg;
        atomicAdd(&gden[batch[n]], expf(gg));
    }
}

__global__ __launch_bounds__(256) void pool_kernel(const float* __restrict__ h,
                                                   const float* __restrict__ g,
                                                   const float* __restrict__ gden,
                                                   const int* __restrict__ batch,
                                                   float* __restrict__ hgraph) {
    int idx = blockIdx.x * 256 + threadIdx.x;
    if (idx >= N_ * D_) return;
    int n = idx >> 8;
    int b = batch[n];
    float w = expf(g[n]) / (gden[b] + 1e-16f);
    atomicAdd(&hgraph[(size_t)b * D_ + (idx & 255)], w * h[idx]);
}

__global__ __launch_bounds__(256) void head_kernel(const float* __restrict__ hgraph,
                                                   const float* __restrict__ hW,
                                                   const float* __restrict__ hb,
                                                   float* __restrict__ out) {
    int gp = blockIdx.x, t = threadIdx.x;
    float v = hgraph[(size_t)gp * D_ + t] * hW[t];
#pragma unroll
    for (int o = 32; o; o >>= 1) v += __shfl_xor(v, o);
    __shared__ float r4[4];
    if ((t & 63) == 0) r4[t >> 6] = v;
    __syncthreads();
    if (t == 0) out[gp] = r4[0] + r4[1] + r4[2] + r4[3] + hb[0];
}

// ---------------- host launch ----------------
extern "C" void kernel_launch(void* const* d_in, const int* in_sizes, int n_in,
                              void* d_out, int out_size, void* d_ws, size_t ws_size,
                              hipStream_t stream) {
    const float* x     = (const float*)d_in[0];
    const int*   eidx  = (const int*)d_in[1];
    const float* eattr = (const float*)d_in[2];
    const int*   batch = (const int*)d_in[3];
    const float* atomW = (const float*)d_in[4];
    const float* atomB = (const float*)d_in[5];
    const float* bondW = (const float*)d_in[6];
    const float* bondB = (const float*)d_in[7];
    const float* Wl    = (const float*)d_in[8];
    const float* bl    = (const float*)d_in[9];
    const float* Wr    = (const float*)d_in[10];
    const float* br    = (const float*)d_in[11];
    const float* We    = (const float*)d_in[12];
    const float* att   = (const float*)d_in[13];
    const float* bias  = (const float*)d_in[14];
    const float* ln1s  = (const float*)d_in[15];
    const float* ln1b  = (const float*)d_in[16];
    const float* eW    = (const float*)d_in[17];
    const float* eb    = (const float*)d_in[18];
    const float* ln2s  = (const float*)d_in[19];
    const float* ln2b  = (const float*)d_in[20];
    const float* jkW   = (const float*)d_in[21];
    const float* jkb   = (const float*)d_in[22];
    const float* ln3s  = (const float*)d_in[23];
    const float* ln3b  = (const float*)d_in[24];
    const float* gW1   = (const float*)d_in[25];
    const float* gb1   = (const float*)d_in[26];
    const float* gW2   = (const float*)d_in[27];
    const float* gb2   = (const float*)d_in[28];
    const float* hW    = (const float*)d_in[29];
    const float* hb    = (const float*)d_in[30];

    const int* src = eidx;
    const int* dst = eidx + E_;

    // ---- workspace layout (~230 MB) ----
    char* wp = (char*)d_ws;
    auto take = [&](size_t bytes) {
        char* p = wp;
        wp += (bytes + 255) & ~(size_t)255;
        return (void*)p;
    };
    float* e_cur   = (float*)take((size_t)E_ * ED_ * 4);  // 81.92 MB, CSR-permuted
    float* hA      = (float*)take((size_t)N_ * D_ * 4);   // 20.48 MB
    float* hB      = (float*)take((size_t)N_ * D_ * 4);   // 20.48 MB
    float* xl      = (float*)take((size_t)N_ * D_ * 4);   // 20.48 MB (hfin at end)
    float* xr      = (float*)take((size_t)N_ * D_ * 4);   // 20.48 MB
    float* jkacc   = (float*)take((size_t)N_ * D_ * 4);   // 20.48 MB
    float* loopW   = (float*)take((size_t)N_ * D_ * 4);   // 20.48 MB
    float* hsW     = (float*)take((size_t)N_ * ED_ * 4);  // 5.12 MB
    float* hdW     = (float*)take((size_t)N_ * ED_ * 4);  // 5.12 MB
    float* exlog   = (float*)take((size_t)E_ * H_ * 4);   // 5.12 MB
    float* esum    = (float*)take((size_t)N_ * ED_ * 4);  // 5.12 MB
    int*   deg_i   = (int*)take((size_t)N_ * 4);
    int*   fill    = (int*)take((size_t)N_ * 4);
    int*   row_off = (int*)take((size_t)(N_ + 1) * 4);
    int*   perm    = (int*)take((size_t)E_ * 4);
    int*   srcp    = (int*)take((size_t)E_ * 4);
    int*   dstp    = (int*)take((size_t)E_ * 4);
    float* g       = (float*)take((size_t)N_ * 4);
    float* gden    = (float*)take((size_t)G_ * 4);
    float* hgraph  = (float*)take((size_t)G_ * D_ * 4);

    // ---- CSR build ----
    hipMemsetAsync(deg_i, 0, (size_t)N_ * 4, stream);
    hipMemsetAsync(fill, 0, (size_t)N_ * 4, stream);
    count_kernel<<<(E_ + 255) / 256, 256, 0, stream>>>(dst, deg_i);
    scan_kernel<<<1, 1024, 0, stream>>>(deg_i, row_off);
    fill_kernel<<<(E_ + 255) / 256, 256, 0, stream>>>(src, dst, row_off, fill,
                                                      perm, srcp, dstp);

    // encoders (e_cur written in CSR-permuted order)
    atom_enc<<<N_, 256, 0, stream>>>(x, atomW, atomB, hA);
    bond_enc_perm<<<(E_ * ED_ + 255) / 256, 256, 0, stream>>>(eattr, bondW, bondB,
                                                              perm, e_cur);

    const float* h_prev = hA;
    for (int l = 0; l < L_; ++l) {
        const float* Wl_l = Wl + (size_t)l * D_ * D_;
        const float* bl_l = bl + (size_t)l * D_;
        const float* Wr_l = Wr + (size_t)l * D_ * D_;
        const float* br_l = br + (size_t)l * D_;
        const float* We_l = We + (size_t)l * ED_ * D_;
        const float* att_l = att + (size_t)l * H_ * C_;
        const float* bias_l = bias + (size_t)l * D_;
        const float* ln1s_l = ln1s + (size_t)l * D_;
        const float* ln1b_l = ln1b + (size_t)l * D_;
        const float* eW_l = eW + (size_t)l * (2 * D_ + ED_) * ED_;
        const float* eb_l = eb + (size_t)l * ED_;
        const float* ln2s_l = ln2s + (size_t)l * ED_;
        const float* ln2b_l = ln2b + (size_t)l * ED_;
        float* hn_l = (l & 1) ? hA : hB;

        // xl/xr projections
        {
            DenseA a{h_prev, D_};
            dim3 grid((N_ + TBM - 1) / TBM, D_ / TBN);
            gemm64<DenseA><<<grid, 256, 0, stream>>>(a, Wl_l, bl_l, xl, N_, D_, D_, 0);
            gemm64<DenseA><<<grid, 256, 0, stream>>>(a, Wr_l, br_l, xr, N_, D_, D_, 0);
        }

        // self-loop term: esum (segment sum of e rows) then esum@We -> loopW
        esum_kernel<<<(N_ + 3) / 4, 256, 0, stream>>>(e_cur, row_off, esum);
        {
            DenseA a{esum, ED_};
            dim3 grid((N_ + TBM - 1) / TBM, D_ / TBN);
            gemm64<DenseA><<<grid, 256, 0, stream>>>(a, We_l, nullptr, loopW, N_, ED_, D_, 0);
        }

        // phase A: edge-parallel exp-logits
        edge_logits2<<<E_ / 64, 256, 0, stream>>>(xl, xr, e_cur, srcp, dstp,
                                                  We_l, att_l, exlog);

        // phase B: per-dst softmax + aggregation + silu/LN
        gat_agg<<<N_, 256, 0, stream>>>(xl, xr, loopW, row_off, srcp, exlog,
                                        att_l, bias_l, ln1s_l, ln1b_l, hn_l);

        // factored edge MLP: hsW = hn@eW[0:256], hdW = hn@eW[256:512]
        {
            DenseA a{hn_l, D_};
            dim3 grid((N_ + TBM - 1) / TBM, 1);
            gemm64<DenseA><<<grid, 256, 0, stream>>>(a, eW_l, nullptr, hsW, N_, D_, ED_, 0);
            gemm64<DenseA><<<grid, 256, 0, stream>>>(a, eW_l + (size_t)D_ * ED_, nullptr,
                                                     hdW, N_, D_, ED_, 0);
        }
        edge_mlp_fused<<<E_ / 64, 256, 0, stream>>>(hsW, hdW, e_cur, srcp, dstp,
                                                    eW_l + (size_t)2 * D_ * ED_,
                                                    eb_l, ln2s_l, ln2b_l);

        // incremental JK: jkacc (+)= hn_l @ jkW[l*256:(l+1)*256]
        {
            DenseA a{hn_l, D_};
            dim3 grid((N_ + TBM - 1) / TBM, D_ / TBN);
            gemm64<DenseA><<<grid, 256, 0, stream>>>(a, jkW + (size_t)l * D_ * D_,
                                                     (l == 0) ? jkb : nullptr,
                                                     jkacc, N_, D_, D_, (l == 0) ? 0 : 1);
        }

        h_prev = hn_l;
    }

    float* hfin = xl;
    node_silu_ln<<<N_, 256, 0, stream>>>(jkacc, ln3s, ln3b, hfin);

    hipMemsetAsync(gden, 0, (size_t)G_ * 4, stream);
    hipMemsetAsync(hgraph, 0, (size_t)G_ * D_ * 4, stream);
    gate_kernel<<<N_, 128, 0, stream>>>(hfin, gW1, gb1, gW2, gb2, batch, g, gden);
    pool_kernel<<<(N_ * D_ + 255) / 256, 256, 0, stream>>>(hfin, g, gden, batch, hgraph);
    head_kernel<<<G_, 256, 0, stream>>>(hgraph, hW, hb, (float*)d_out);
}

// Round 7
// 3054.455 us; speedup vs baseline: 3.9477x; 1.2199x over previous
//
#include <hip/hip_runtime.h>
#include <hip/hip_bf16.h>

// Problem constants
#define N_ 20000
#define E_ 320000
#define G_ 128
#define H_ 4
#define C_ 64
#define D_ 256
#define ED_ 64
#define L_ 4

typedef _Float16 f16x8 __attribute__((ext_vector_type(8)));
typedef float f32x4 __attribute__((ext_vector_type(4)));

// ---------------- encoders ----------------
__global__ __launch_bounds__(256) void atom_enc(const float* __restrict__ x,
                                                const float* __restrict__ W,
                                                const float* __restrict__ b,
                                                _Float16* __restrict__ h16) {
    int n = blockIdx.x, t = threadIdx.x;
    float acc = b[t];
#pragma unroll
    for (int k = 0; k < 9; ++k) acc += x[n * 9 + k] * W[k * D_ + t];
    h16[(size_t)n * D_ + t] = (_Float16)acc;
}

// bond encoder writing into CSR-permuted order: e[pos] = enc(edge_attr[perm[pos]])
__global__ __launch_bounds__(256) void bond_enc_perm(const float* __restrict__ ea,
                                                     const float* __restrict__ W,
                                                     const float* __restrict__ b,
                                                     const int* __restrict__ perm,
                                                     float* __restrict__ e) {
    int idx = blockIdx.x * 256 + threadIdx.x;
    if (idx >= E_ * ED_) return;
    int pos = idx >> 6, j = idx & 63;
    int orig = perm[pos];
    float acc = b[j];
#pragma unroll
    for (int k = 0; k < 3; ++k) acc += ea[orig * 3 + k] * W[k * ED_ + j];
    e[idx] = acc;
}

// ---------------- CSR build (dst-sorted) ----------------
__global__ __launch_bounds__(256) void count_kernel(const int* __restrict__ dst,
                                                    int* __restrict__ deg) {
    int e = blockIdx.x * 256 + threadIdx.x;
    if (e >= E_) return;
    atomicAdd(&deg[dst[e]], 1);
}

__global__ __launch_bounds__(1024) void scan_kernel(const int* __restrict__ deg,
                                                    int* __restrict__ row_off) {
    __shared__ int part[1024];
    int t = threadIdx.x;
    const int CH = (N_ + 1023) / 1024;  // 20
    int s = 0;
    for (int i = 0; i < CH; ++i) {
        int idx = t * CH + i;
        if (idx < N_) s += deg[idx];
    }
    part[t] = s;
    __syncthreads();
    for (int off = 1; off < 1024; off <<= 1) {
        int v = (t >= off) ? part[t - off] : 0;
        __syncthreads();
        part[t] += v;
        __syncthreads();
    }
    int base = (t == 0) ? 0 : part[t - 1];
    for (int i = 0; i < CH; ++i) {
        int idx = t * CH + i;
        if (idx < N_) { row_off[idx] = base; base += deg[idx]; }
    }
    if (t == 0) row_off[N_] = part[1023];
}

__global__ __launch_bounds__(256) void fill_kernel(const int* __restrict__ src,
                                                   const int* __restrict__ dst,
                                                   const int* __restrict__ row_off,
                                                   int* __restrict__ fill,
                                                   int* __restrict__ perm,
                                                   int* __restrict__ srcp,
                                                   int* __restrict__ dstp) {
    int e = blockIdx.x * 256 + threadIdx.x;
    if (e >= E_) return;
    int d = dst[e];
    int pos = row_off[d] + atomicAdd(&fill[d], 1);
    perm[pos] = e;
    srcp[pos] = src[e];
    dstp[pos] = d;
}

// ---------------- weight pre-pack: W[K][N] f32 -> WT[N][K] f16 ----------------
__global__ __launch_bounds__(256) void pack_wT(const float* __restrict__ W,
                                               _Float16* __restrict__ WT,
                                               int K, int Nn) {
    int idx = blockIdx.x * 256 + threadIdx.x;
    if (idx >= K * Nn) return;
    int n = idx / K, k = idx - n * K;
    WT[idx] = (_Float16)W[(size_t)k * Nn + n];
}

// ---------------- MFMA f16 GEMM: C (=|+=) A16 @ BT16^T (+ bias) ----------------
// A16: [M][K] f16 row-major. BT16: [N][K] f16 row-major (i.e. B transposed).
// Direct-from-global fragments (no LDS): weights are L1/L2-hot, A rows unique
// per wave. 4 waves x 16 rows, 4 col-tiles each; f32 accumulate.
// C layout per m89: col = lane&15, row = (lane>>4)*4 + reg.
__global__ __launch_bounds__(256) void mfma_gemm(const _Float16* __restrict__ A16,
                                                 const _Float16* __restrict__ BT16,
                                                 const float* __restrict__ bias,
                                                 float* __restrict__ C,
                                                 int M, int K, int Nn, int accum) {
    int t = threadIdx.x;
    int w = t >> 6, l = t & 63;
    int bm = blockIdx.x * 64, bn = blockIdx.y * 64;
    int row0 = bm + w * 16 + (l & 15);
    int arow = row0 < M ? row0 : M - 1;
    int koff = (l >> 4) * 8;
    const _Float16* Ap = A16 + (size_t)arow * K + koff;
    f32x4 acc0 = {}, acc1 = {}, acc2 = {}, acc3 = {};
    for (int ks = 0; ks < K; ks += 32) {
        f16x8 a = *(const f16x8*)(Ap + ks);
        const _Float16* Bp = BT16 + (size_t)(bn + (l & 15)) * K + ks + koff;
        f16x8 b0 = *(const f16x8*)(Bp);
        f16x8 b1 = *(const f16x8*)(Bp + (size_t)16 * K);
        f16x8 b2 = *(const f16x8*)(Bp + (size_t)32 * K);
        f16x8 b3 = *(const f16x8*)(Bp + (size_t)48 * K);
        acc0 = __builtin_amdgcn_mfma_f32_16x16x32_f16(a, b0, acc0, 0, 0, 0);
        acc1 = __builtin_amdgcn_mfma_f32_16x16x32_f16(a, b1, acc1, 0, 0, 0);
        acc2 = __builtin_amdgcn_mfma_f32_16x16x32_f16(a, b2, acc2, 0, 0, 0);
        acc3 = __builtin_amdgcn_mfma_f32_16x16x32_f16(a, b3, acc3, 0, 0, 0);
    }
    f32x4 accs[4] = {acc0, acc1, acc2, acc3};
#pragma unroll
    for (int ct = 0; ct < 4; ++ct) {
        int col = bn + ct * 16 + (l & 15);
#pragma unroll
        for (int r = 0; r < 4; ++r) {
            int row = bm + w * 16 + (l >> 4) * 4 + r;
            if (row < M) {
                float v = accs[ct][r] + (bias ? bias[col] : 0.f);
                if (accum) C[(size_t)row * Nn + col] += v;
                else       C[(size_t)row * Nn + col] = v;
            }
        }
    }
}

// ---------------- phase A: edge-parallel GATv2 exp-logits ----------------
__global__ __launch_bounds__(256) void edge_logits2(const float* __restrict__ xl,
                                                    const float* __restrict__ xr,
                                                    const float* __restrict__ e,
                                                    const int* __restrict__ srcp,
                                                    const int* __restrict__ dstp,
                                                    const float* __restrict__ We,
                                                    const float* __restrict__ att,
                                                    float* __restrict__ exlog) {
    int t = threadIdx.x;
    int w = t >> 6, lane = t & 63;
    float wreg[64];
#pragma unroll
    for (int k = 0; k < 64; ++k) wreg[k] = We[k * D_ + t];
    float av = att[t];  // att is [H][C] flat == 256
    __shared__ float es[4][2][ED_];
    int base = blockIdx.x * 64;
    for (int i = 0; i < 64; i += 2) {
        int e0 = base + i, e1 = base + i + 1;
        int s0 = srcp[e0], s1 = srcp[e1];
        int d0 = dstp[e0], d1 = dstp[e1];
        float ev0 = e[(size_t)e0 * ED_ + lane];
        float ev1 = e[(size_t)e1 * ED_ + lane];
        float xls0 = xl[(size_t)s0 * D_ + t];
        float xls1 = xl[(size_t)s1 * D_ + t];
        float xrd0 = xr[(size_t)d0 * D_ + t];
        float xrd1 = xr[(size_t)d1 * D_ + t];
        es[w][0][lane] = ev0;
        es[w][1][lane] = ev1;
        float a0 = 0.f, a1 = 0.f;
#pragma unroll
        for (int k0 = 0; k0 < 64; k0 += 4) {
            const float4 p = *(const float4*)&es[w][0][k0];
            const float4 q = *(const float4*)&es[w][1][k0];
            a0 += p.x * wreg[k0] + p.y * wreg[k0 + 1] + p.z * wreg[k0 + 2] + p.w * wreg[k0 + 3];
            a1 += q.x * wreg[k0] + q.y * wreg[k0 + 1] + q.z * wreg[k0 + 2] + q.w * wreg[k0 + 3];
        }
        float m0 = xls0 + xrd0 + a0; m0 = (m0 > 0.f) ? m0 : 0.2f * m0;
        float m1 = xls1 + xrd1 + a1; m1 = (m1 > 0.f) ? m1 : 0.2f * m1;
        float v0 = m0 * av, v1 = m1 * av;
#pragma unroll
        for (int o = 32; o; o >>= 1) { v0 += __shfl_xor(v0, o); v1 += __shfl_xor(v1, o); }
        if (lane == 0) {
            exlog[(size_t)e0 * H_ + w] = expf(v0);
            exlog[(size_t)e1 * H_ + w] = expf(v1);
        }
    }
}

// ---------------- esum16: per-dst segment sum of e rows (f16 out) ------------
__global__ __launch_bounds__(256) void esum_kernel(const float* __restrict__ e,
                                                   const int* __restrict__ row_off,
                                                   _Float16* __restrict__ esum16) {
    int d = blockIdx.x * 4 + (threadIdx.x >> 6);
    int lane = threadIdx.x & 63;
    if (d >= N_) return;
    int beg = row_off[d], end = row_off[d + 1];
    float s = 0.f;
    for (int i = beg; i < end; ++i) s += e[(size_t)i * ED_ + lane];
    esum16[(size_t)d * ED_ + lane] = (_Float16)s;
}

// ---------------- phase B: per-dst softmax + aggregation + silu/LN ----------
__global__ __launch_bounds__(256) void gat_agg(const float* __restrict__ xl,
                                               const float* __restrict__ xr,
                                               const float* __restrict__ loopW,
                                               const int* __restrict__ row_off,
                                               const int* __restrict__ srcp,
                                               const float* __restrict__ exlog,
                                               const float* __restrict__ att,
                                               const float* __restrict__ bias,
                                               const float* __restrict__ gs,
                                               const float* __restrict__ gb,
                                               _Float16* __restrict__ hn16) {
    int d = blockIdx.x, t = threadIdx.x;
    int w = t >> 6, lane = t & 63;
    int beg = row_off[d], end = row_off[d + 1];
    int deg = end - beg;
    float av = att[t];
    float xld = xl[(size_t)d * D_ + t];
    float xrd = xr[(size_t)d * D_ + t];
    float den = 0.f, out = 0.f;
    int i = beg;
    for (; i + 4 <= end; i += 4) {
        int s0 = srcp[i], s1 = srcp[i + 1], s2 = srcp[i + 2], s3 = srcp[i + 3];
        float ex0 = exlog[(size_t)i * H_ + w];
        float ex1 = exlog[(size_t)(i + 1) * H_ + w];
        float ex2 = exlog[(size_t)(i + 2) * H_ + w];
        float ex3 = exlog[(size_t)(i + 3) * H_ + w];
        float x0 = xl[(size_t)s0 * D_ + t];
        float x1 = xl[(size_t)s1 * D_ + t];
        float x2 = xl[(size_t)s2 * D_ + t];
        float x3 = xl[(size_t)s3 * D_ + t];
        den += (ex0 + ex1) + (ex2 + ex3);
        out += ex0 * x0 + ex1 * x1 + ex2 * x2 + ex3 * x3;
    }
    for (; i < end; ++i) {
        int s0 = srcp[i];
        float ex0 = exlog[(size_t)i * H_ + w];
        float x0 = xl[(size_t)s0 * D_ + t];
        den += ex0;
        out += ex0 * x0;
    }
    // self loop: loop_e@We = esum@We / deg (linearity)
    float lw = (deg > 0) ? loopW[(size_t)d * D_ + t] / (float)deg : 0.f;
    {
        float m = xld + xrd + lw;
        m = (m > 0.f) ? m : 0.2f * m;
        float v = m * av;
#pragma unroll
        for (int o = 32; o; o >>= 1) v += __shfl_xor(v, o);
        float eself = expf(v);
        den += eself;
        out += eself * xld;
    }
    out *= 1.f / (den + 1e-16f);
    // epilogue: bias + silu + LN over 256 features
    float v = out + bias[t];
    v = v / (1.f + expf(-v));
    __shared__ float red[4];
    float s = v;
#pragma unroll
    for (int o = 32; o; o >>= 1) s += __shfl_xor(s, o);
    if (lane == 0) red[w] = s;
    __syncthreads();
    float mu = (red[0] + red[1] + red[2] + red[3]) * (1.f / 256.f);
    __syncthreads();
    float dv = v - mu;
    float q = dv * dv;
#pragma unroll
    for (int o = 32; o; o >>= 1) q += __shfl_xor(q, o);
    if (lane == 0) red[w] = q;
    __syncthreads();
    float var = (red[0] + red[1] + red[2] + red[3]) * (1.f / 256.f);
    hn16[(size_t)d * D_ + t] = (_Float16)(dv * rsqrtf(var + 1e-5f) * gs[t] + gb[t]);
}

// ---------------- factored edge MLP + silu + LN (in-place into e) ----------------
__global__ __launch_bounds__(256) void edge_mlp_fused(const float* __restrict__ hsW,
                                                      const float* __restrict__ hdW,
                                                      float* __restrict__ e,
                                                      const int* __restrict__ srcp,
                                                      const int* __restrict__ dstp,
                                                      const float* __restrict__ eW3,
                                                      const float* __restrict__ eb,
                                                      const float* __restrict__ gs,
                                                      const float* __restrict__ gb) {
    int t = threadIdx.x;
    int w = t >> 6, lane = t & 63;
    float wreg[64];
#pragma unroll
    for (int k = 0; k < 64; ++k) wreg[k] = eW3[k * ED_ + lane];
    float ebv = eb[lane], gsv = gs[lane], gbv = gb[lane];
    __shared__ float es[4][ED_];
    int base = blockIdx.x * 64;
    for (int it = 0; it < 16; ++it) {
        int edge = base + it * 4 + w;
        float ev = e[(size_t)edge * ED_ + lane];
        es[w][lane] = ev;  // wave-local slot; wave-coherent LDS, no barrier
        float acc = ebv + hsW[(size_t)srcp[edge] * ED_ + lane]
                        + hdW[(size_t)dstp[edge] * ED_ + lane];
#pragma unroll
        for (int k0 = 0; k0 < 64; k0 += 4) {
            const float4 e4 = *(const float4*)&es[w][k0];
            acc += e4.x * wreg[k0] + e4.y * wreg[k0 + 1] +
                   e4.z * wreg[k0 + 2] + e4.w * wreg[k0 + 3];
        }
        // silu + LN over 64 lanes (one wave per edge)
        float v = acc / (1.f + expf(-acc));
        float s = v;
#pragma unroll
        for (int o = 32; o; o >>= 1) s += __shfl_xor(s, o);
        float mu = s * (1.f / 64.f);
        float dv = v - mu;
        float q = dv * dv;
#pragma unroll
        for (int o = 32; o; o >>= 1) q += __shfl_xor(q, o);
        float rs = rsqrtf(q * (1.f / 64.f) + 1e-5f);
        e[(size_t)edge * ED_ + lane] = dv * rs * gsv + gbv;
    }
}

// ---------------- node silu + LN (final JK output) ----------------
__global__ __launch_bounds__(256) void node_silu_ln(const float* __restrict__ inp,
                                                    const float* __restrict__ gs,
                                                    const float* __restrict__ gb,
                                                    float* __restrict__ outp) {
    int n = blockIdx.x, t = threadIdx.x;
    float v = inp[(size_t)n * D_ + t];
    v = v / (1.f + expf(-v));
    __shared__ float red[4];
    float s = v;
#pragma unroll
    for (int o = 32; o; o >>= 1) s += __shfl_xor(s, o);
    if ((t & 63) == 0) red[t >> 6] = s;
    __syncthreads();
    float mu = (red[0] + red[1] + red[2] + red[3]) * (1.f / 256.f);
    __syncthreads();
    float dv = v - mu;
    float q = dv * dv;
#pragma unroll
    for (int o = 32; o; o >>= 1) q += __shfl_xor(q, o);
    if ((t & 63) == 0) red[t >> 6] = q;
    __syncthreads();
    float var = (red[0] + red[1] + red[2] + red[3]) * (1.f / 256.f);
    outp[(size_t)n * D_ + t] = dv * rsqrtf(var + 1e-5f) * gs[t] + gb[t];
}

// ---------------- gate MLP + softmax denom ----------------
__global__ __launch_bounds__(128) void gate_kernel(const float* __restrict__ h,
                                                   const float* __restrict__ gW1,
                                                   const float* __restrict__ gb1,
                                                   const float* __restrict__ gW2,
                                                   const float* __restrict__ gb2,
                                                   const int* __restrict__ batch,
                                                   float* __restrict__ g,
                                                   float* __restrict__ gden) {
    int n = blockIdx.x, t = threadIdx.x; // 128 threads
    const float* hn = h + (size_t)n * D_;
    float acc = gb1[t];
    for (int k = 0; k < D_; ++k) acc += hn[k] * gW1[k * 128 + t];
    acc = acc / (1.f + expf(-acc));
    float v = acc * gW2[t];
#pragma unroll
    for (int o = 32; o; o >>= 1) v += __shfl_xor(v, o);
    __shared__ float r2[2];
    if ((t & 63) == 0) r2[t >> 6] = v;
    __syncthreads();
    if (t == 0) {
        float gg = r2[0] + r2[1] + gb2[0];
        g[n] = gg;
        atomicAdd(&gden[batch[n]], expf(gg));
    }
}

__global__ __launch_bounds__(256) void pool_kernel(const float* __restrict__ h,
                                                   const float* __restrict__ g,
                                                   const float* __restrict__ gden,
                                                   const int* __restrict__ batch,
                                                   float* __restrict__ hgraph) {
    int idx = blockIdx.x * 256 + threadIdx.x;
    if (idx >= N_ * D_) return;
    int n = idx >> 8;
    int b = batch[n];
    float w = expf(g[n]) / (gden[b] + 1e-16f);
    atomicAdd(&hgraph[(size_t)b * D_ + (idx & 255)], w * h[idx]);
}

__global__ __launch_bounds__(256) void head_kernel(const float* __restrict__ hgraph,
                                                   const float* __restrict__ hW,
                                                   const float* __restrict__ hb,
                                                   float* __restrict__ out) {
    int gp = blockIdx.x, t = threadIdx.x;
    float v = hgraph[(size_t)gp * D_ + t] * hW[t];
#pragma unroll
    for (int o = 32; o; o >>= 1) v += __shfl_xor(v, o);
    __shared__ float r4[4];
    if ((t & 63) == 0) r4[t >> 6] = v;
    __syncthreads();
    if (t == 0) out[gp] = r4[0] + r4[1] + r4[2] + r4[3] + hb[0];
}

// ---------------- host launch ----------------
extern "C" void kernel_launch(void* const* d_in, const int* in_sizes, int n_in,
                              void* d_out, int out_size, void* d_ws, size_t ws_size,
                              hipStream_t stream) {
    const float* x     = (const float*)d_in[0];
    const int*   eidx  = (const int*)d_in[1];
    const float* eattr = (const float*)d_in[2];
    const int*   batch = (const int*)d_in[3];
    const float* atomW = (const float*)d_in[4];
    const float* atomB = (const float*)d_in[5];
    const float* bondW = (const float*)d_in[6];
    const float* bondB = (const float*)d_in[7];
    const float* Wl    = (const float*)d_in[8];
    const float* bl    = (const float*)d_in[9];
    const float* Wr    = (const float*)d_in[10];
    const float* br    = (const float*)d_in[11];
    const float* We    = (const float*)d_in[12];
    const float* att   = (const float*)d_in[13];
    const float* bias  = (const float*)d_in[14];
    const float* ln1s  = (const float*)d_in[15];
    const float* ln1b  = (const float*)d_in[16];
    const float* eW    = (const float*)d_in[17];
    const float* eb    = (const float*)d_in[18];
    const float* ln2s  = (const float*)d_in[19];
    const float* ln2b  = (const float*)d_in[20];
    const float* jkW   = (const float*)d_in[21];
    const float* jkb   = (const float*)d_in[22];
    const float* ln3s  = (const float*)d_in[23];
    const float* ln3b  = (const float*)d_in[24];
    const float* gW1   = (const float*)d_in[25];
    const float* gb1   = (const float*)d_in[26];
    const float* gW2   = (const float*)d_in[27];
    const float* gb2   = (const float*)d_in[28];
    const float* hW    = (const float*)d_in[29];
    const float* hb    = (const float*)d_in[30];

    const int* src = eidx;
    const int* dst = eidx + E_;

    // ---- workspace layout (~210 MB) ----
    char* wp = (char*)d_ws;
    auto take = [&](size_t bytes) {
        char* p = wp;
        wp += (bytes + 255) & ~(size_t)255;
        return (void*)p;
    };
    float*     e_cur   = (float*)take((size_t)E_ * ED_ * 4);   // 81.92 MB, CSR-permuted
    float*     xl      = (float*)take((size_t)N_ * D_ * 4);    // 20.48 MB (hfin at end)
    float*     xr      = (float*)take((size_t)N_ * D_ * 4);    // 20.48 MB
    float*     jkacc   = (float*)take((size_t)N_ * D_ * 4);    // 20.48 MB
    float*     loopW   = (float*)take((size_t)N_ * D_ * 4);    // 20.48 MB
    _Float16*  h16A    = (_Float16*)take((size_t)N_ * D_ * 2); // 10.24 MB
    _Float16*  h16B    = (_Float16*)take((size_t)N_ * D_ * 2); // 10.24 MB
    float*     hsW     = (float*)take((size_t)N_ * ED_ * 4);   // 5.12 MB
    float*     hdW     = (float*)take((size_t)N_ * ED_ * 4);   // 5.12 MB
    float*     exlog   = (float*)take((size_t)E_ * H_ * 4);    // 5.12 MB
    _Float16*  esum16  = (_Float16*)take((size_t)N_ * ED_ * 2);// 2.56 MB
    _Float16*  wlT16   = (_Float16*)take((size_t)L_ * D_ * D_ * 2);
    _Float16*  wrT16   = (_Float16*)take((size_t)L_ * D_ * D_ * 2);
    _Float16*  weT16   = (_Float16*)take((size_t)L_ * ED_ * D_ * 2);
    _Float16*  ewsT16  = (_Float16*)take((size_t)L_ * D_ * ED_ * 2);
    _Float16*  ewdT16  = (_Float16*)take((size_t)L_ * D_ * ED_ * 2);
    _Float16*  jkwT16  = (_Float16*)take((size_t)L_ * D_ * D_ * 2);
    int*   deg_i   = (int*)take((size_t)N_ * 4);
    int*   fill    = (int*)take((size_t)N_ * 4);
    int*   row_off = (int*)take((size_t)(N_ + 1) * 4);
    int*   perm    = (int*)take((size_t)E_ * 4);
    int*   srcp    = (int*)take((size_t)E_ * 4);
    int*   dstp    = (int*)take((size_t)E_ * 4);
    float* g       = (float*)take((size_t)N_ * 4);
    float* gden    = (float*)take((size_t)G_ * 4);
    float* hgraph  = (float*)take((size_t)G_ * D_ * 4);

    // ---- weight pre-pack (f32 -> transposed f16) ----
    auto pack = [&](const float* W, _Float16* WT, int K, int Nn) {
        pack_wT<<<(K * Nn + 255) / 256, 256, 0, stream>>>(W, WT, K, Nn);
    };
    for (int l = 0; l < L_; ++l) {
        pack(Wl + (size_t)l * D_ * D_, wlT16 + (size_t)l * D_ * D_, D_, D_);
        pack(Wr + (size_t)l * D_ * D_, wrT16 + (size_t)l * D_ * D_, D_, D_);
        pack(We + (size_t)l * ED_ * D_, weT16 + (size_t)l * ED_ * D_, ED_, D_);
        const float* eW_l = eW + (size_t)l * (2 * D_ + ED_) * ED_;
        pack(eW_l,                      ewsT16 + (size_t)l * D_ * ED_, D_, ED_);
        pack(eW_l + (size_t)D_ * ED_,   ewdT16 + (size_t)l * D_ * ED_, D_, ED_);
        pack(jkW + (size_t)l * D_ * D_, jkwT16 + (size_t)l * D_ * D_, D_, D_);
    }

    // ---- CSR build ----
    hipMemsetAsync(deg_i, 0, (size_t)N_ * 4, stream);
    hipMemsetAsync(fill, 0, (size_t)N_ * 4, stream);
    count_kernel<<<(E_ + 255) / 256, 256, 0, stream>>>(dst, deg_i);
    scan_kernel<<<1, 1024, 0, stream>>>(deg_i, row_off);
    fill_kernel<<<(E_ + 255) / 256, 256, 0, stream>>>(src, dst, row_off, fill,
                                                      perm, srcp, dstp);

    // encoders
    atom_enc<<<N_, 256, 0, stream>>>(x, atomW, atomB, h16A);
    bond_enc_perm<<<(E_ * ED_ + 255) / 256, 256, 0, stream>>>(eattr, bondW, bondB,
                                                              perm, e_cur);

    const int MB = (N_ + 63) / 64;  // 313
    const _Float16* h16_prev = h16A;
    for (int l = 0; l < L_; ++l) {
        const float* bl_l = bl + (size_t)l * D_;
        const float* br_l = br + (size_t)l * D_;
        const float* We_l = We + (size_t)l * ED_ * D_;
        const float* att_l = att + (size_t)l * H_ * C_;
        const float* bias_l = bias + (size_t)l * D_;
        const float* ln1s_l = ln1s + (size_t)l * D_;
        const float* ln1b_l = ln1b + (size_t)l * D_;
        const float* eW_l = eW + (size_t)l * (2 * D_ + ED_) * ED_;
        const float* eb_l = eb + (size_t)l * ED_;
        const float* ln2s_l = ln2s + (size_t)l * ED_;
        const float* ln2b_l = ln2b + (size_t)l * ED_;
        _Float16* hn16_l = (l & 1) ? h16A : h16B;

        // xl/xr projections (MFMA)
        {
            dim3 grid(MB, D_ / 64);
            mfma_gemm<<<grid, 256, 0, stream>>>(h16_prev, wlT16 + (size_t)l * D_ * D_,
                                                bl_l, xl, N_, D_, D_, 0);
            mfma_gemm<<<grid, 256, 0, stream>>>(h16_prev, wrT16 + (size_t)l * D_ * D_,
                                                br_l, xr, N_, D_, D_, 0);
        }

        // self-loop term: esum16 then esum16@We -> loopW (MFMA, K=64)
        esum_kernel<<<(N_ + 3) / 4, 256, 0, stream>>>(e_cur, row_off, esum16);
        {
            dim3 grid(MB, D_ / 64);
            mfma_gemm<<<grid, 256, 0, stream>>>(esum16, weT16 + (size_t)l * ED_ * D_,
                                                nullptr, loopW, N_, ED_, D_, 0);
        }

        // phase A: edge-parallel exp-logits
        edge_logits2<<<E_ / 64, 256, 0, stream>>>(xl, xr, e_cur, srcp, dstp,
                                                  We_l, att_l, exlog);

        // phase B: per-dst softmax + aggregation + silu/LN -> hn16
        gat_agg<<<N_, 256, 0, stream>>>(xl, xr, loopW, row_off, srcp, exlog,
                                        att_l, bias_l, ln1s_l, ln1b_l, hn16_l);

        // factored edge MLP: hsW = hn@eW[0:256], hdW = hn@eW[256:512] (MFMA, N=64)
        {
            dim3 grid(MB, 1);
            mfma_gemm<<<grid, 256, 0, stream>>>(hn16_l, ewsT16 + (size_t)l * D_ * ED_,
                                                nullptr, hsW, N_, D_, ED_, 0);
            mfma_gemm<<<grid, 256, 0, stream>>>(hn16_l, ewdT16 + (size_t)l * D_ * ED_,
                                                nullptr, hdW, N_, D_, ED_, 0);
        }
        edge_mlp_fused<<<E_ / 64, 256, 0, stream>>>(hsW, hdW, e_cur, srcp, dstp,
                                                    eW_l + (size_t)2 * D_ * ED_,
                                                    eb_l, ln2s_l, ln2b_l);

        // incremental JK: jkacc (+)= hn @ jkW_l (MFMA)
        {
            dim3 grid(MB, D_ / 64);
            mfma_gemm<<<grid, 256, 0, stream>>>(hn16_l, jkwT16 + (size_t)l * D_ * D_,
                                                (l == 0) ? jkb : nullptr,
                                                jkacc, N_, D_, D_, (l == 0) ? 0 : 1);
        }

        h16_prev = hn16_l;
    }

    float* hfin = xl;
    node_silu_ln<<<N_, 256, 0, stream>>>(jkacc, ln3s, ln3b, hfin);

    hipMemsetAsync(gden, 0, (size_t)G_ * 4, stream);
    hipMemsetAsync(hgraph, 0, (size_t)G_ * D_ * 4, stream);
    gate_kernel<<<N_, 128, 0, stream>>>(hfin, gW1, gb1, gW2, gb2, batch, g, gden);
    pool_kernel<<<(N_ * D_ + 255) / 256, 256, 0, stream>>>(hfin, g, gden, batch, hgraph);
    head_kernel<<<G_, 256, 0, stream>>>(hgraph, hW, hb, (float*)d_out);
}

// Round 9
// 1910.651 us; speedup vs baseline: 6.3110x; 1.5986x over previous
//
#include <hip/hip_runtime.h>
#include <hip/hip_bf16.h>

// Problem constants
#define N_ 20000
#define E_ 320000
#define G_ 128
#define H_ 4
#define C_ 64
#define D_ 256
#define ED_ 64
#define L_ 4
#define LROW 72  // padded LDS row stride (f16 units)

typedef _Float16 f16x8 __attribute__((ext_vector_type(8)));
typedef float f32x4 __attribute__((ext_vector_type(4)));

// ---------------- encoders ----------------
__global__ __launch_bounds__(256) void atom_enc(const float* __restrict__ x,
                                                const float* __restrict__ W,
                                                const float* __restrict__ b,
                                                _Float16* __restrict__ h16) {
    int n = blockIdx.x, t = threadIdx.x;
    float acc = b[t];
#pragma unroll
    for (int k = 0; k < 9; ++k) acc += x[n * 9 + k] * W[k * D_ + t];
    h16[(size_t)n * D_ + t] = (_Float16)acc;
}

__global__ __launch_bounds__(256) void bond_enc_perm(const float* __restrict__ ea,
                                                     const float* __restrict__ W,
                                                     const float* __restrict__ b,
                                                     const int* __restrict__ perm,
                                                     _Float16* __restrict__ e16) {
    int idx = blockIdx.x * 256 + threadIdx.x;
    if (idx >= E_ * ED_) return;
    int pos = idx >> 6, j = idx & 63;
    int orig = perm[pos];
    float acc = b[j];
#pragma unroll
    for (int k = 0; k < 3; ++k) acc += ea[orig * 3 + k] * W[k * ED_ + j];
    e16[idx] = (_Float16)acc;
}

// ---------------- CSR build (dst-sorted) ----------------
__global__ __launch_bounds__(256) void count_kernel(const int* __restrict__ dst,
                                                    int* __restrict__ deg) {
    int e = blockIdx.x * 256 + threadIdx.x;
    if (e >= E_) return;
    atomicAdd(&deg[dst[e]], 1);
}

__global__ __launch_bounds__(1024) void scan_kernel(const int* __restrict__ deg,
                                                    int* __restrict__ row_off) {
    __shared__ int part[1024];
    int t = threadIdx.x;
    const int CH = (N_ + 1023) / 1024;  // 20
    int s = 0;
    for (int i = 0; i < CH; ++i) {
        int idx = t * CH + i;
        if (idx < N_) s += deg[idx];
    }
    part[t] = s;
    __syncthreads();
    for (int off = 1; off < 1024; off <<= 1) {
        int v = (t >= off) ? part[t - off] : 0;
        __syncthreads();
        part[t] += v;
        __syncthreads();
    }
    int base = (t == 0) ? 0 : part[t - 1];
    for (int i = 0; i < CH; ++i) {
        int idx = t * CH + i;
        if (idx < N_) { row_off[idx] = base; base += deg[idx]; }
    }
    if (t == 0) row_off[N_] = part[1023];
}

__global__ __launch_bounds__(256) void fill_kernel(const int* __restrict__ src,
                                                   const int* __restrict__ dst,
                                                   const int* __restrict__ row_off,
                                                   int* __restrict__ fill,
                                                   int* __restrict__ perm,
                                                   int* __restrict__ srcp,
                                                   int* __restrict__ dstp) {
    int e = blockIdx.x * 256 + threadIdx.x;
    if (e >= E_) return;
    int d = dst[e];
    int pos = row_off[d] + atomicAdd(&fill[d], 1);
    perm[pos] = e;
    srcp[pos] = src[e];
    dstp[pos] = d;
}

// ---------------- weight pre-pack: W[K][N] f32 -> WT[N][K] f16 ----------------
__global__ __launch_bounds__(256) void pack_wT(const float* __restrict__ W,
                                               _Float16* __restrict__ WT,
                                               int K, int Nn) {
    int idx = blockIdx.x * 256 + threadIdx.x;
    if (idx >= K * Nn) return;
    int n = idx / K, k = idx - n * K;
    WT[idx] = (_Float16)W[(size_t)k * Nn + n];
}

// ---------------- MFMA f16 GEMM (f32 out, bias, accum) ----------------
__global__ __launch_bounds__(256) void mfma_gemm(const _Float16* __restrict__ A16,
                                                 const _Float16* __restrict__ BT16,
                                                 const float* __restrict__ bias,
                                                 float* __restrict__ C,
                                                 int M, int K, int Nn, int accum) {
    int t = threadIdx.x;
    int w = t >> 6, l = t & 63;
    int bm = blockIdx.x * 64, bn = blockIdx.y * 64;
    int row0 = bm + w * 16 + (l & 15);
    int arow = row0 < M ? row0 : M - 1;
    int koff = (l >> 4) * 8;
    const _Float16* Ap = A16 + (size_t)arow * K + koff;
    f32x4 acc0 = {}, acc1 = {}, acc2 = {}, acc3 = {};
    for (int ks = 0; ks < K; ks += 32) {
        f16x8 a = *(const f16x8*)(Ap + ks);
        const _Float16* Bp = BT16 + (size_t)(bn + (l & 15)) * K + ks + koff;
        f16x8 b0 = *(const f16x8*)(Bp);
        f16x8 b1 = *(const f16x8*)(Bp + (size_t)16 * K);
        f16x8 b2 = *(const f16x8*)(Bp + (size_t)32 * K);
        f16x8 b3 = *(const f16x8*)(Bp + (size_t)48 * K);
        acc0 = __builtin_amdgcn_mfma_f32_16x16x32_f16(a, b0, acc0, 0, 0, 0);
        acc1 = __builtin_amdgcn_mfma_f32_16x16x32_f16(a, b1, acc1, 0, 0, 0);
        acc2 = __builtin_amdgcn_mfma_f32_16x16x32_f16(a, b2, acc2, 0, 0, 0);
        acc3 = __builtin_amdgcn_mfma_f32_16x16x32_f16(a, b3, acc3, 0, 0, 0);
    }
    f32x4 accs[4] = {acc0, acc1, acc2, acc3};
#pragma unroll
    for (int ct = 0; ct < 4; ++ct) {
        int col = bn + ct * 16 + (l & 15);
#pragma unroll
        for (int r = 0; r < 4; ++r) {
            int row = bm + w * 16 + (l >> 4) * 4 + r;
            if (row < M) {
                float v = accs[ct][r] + (bias ? bias[col] : 0.f);
                if (accum) C[(size_t)row * Nn + col] += v;
                else       C[(size_t)row * Nn + col] = v;
            }
        }
    }
}

// ---------------- MFMA f16 GEMM, f16 out, no bias ----------------
// Safe in-place (C16 == A16): wave w reads exactly A rows [bm+16w, bm+16w+16)
// and writes the same rows; loads drain into MFMAs before stores issue.
__global__ __launch_bounds__(256) void mfma_gemm16(const _Float16* __restrict__ A16,
                                                   const _Float16* __restrict__ BT16,
                                                   _Float16* __restrict__ C16,
                                                   int M, int K, int Nn) {
    int t = threadIdx.x;
    int w = t >> 6, l = t & 63;
    int bm = blockIdx.x * 64, bn = blockIdx.y * 64;
    int row0 = bm + w * 16 + (l & 15);
    int arow = row0 < M ? row0 : M - 1;
    int koff = (l >> 4) * 8;
    const _Float16* Ap = A16 + (size_t)arow * K + koff;
    f32x4 acc0 = {}, acc1 = {}, acc2 = {}, acc3 = {};
    for (int ks = 0; ks < K; ks += 32) {
        f16x8 a = *(const f16x8*)(Ap + ks);
        const _Float16* Bp = BT16 + (size_t)(bn + (l & 15)) * K + ks + koff;
        f16x8 b0 = *(const f16x8*)(Bp);
        f16x8 b1 = *(const f16x8*)(Bp + (size_t)16 * K);
        f16x8 b2 = *(const f16x8*)(Bp + (size_t)32 * K);
        f16x8 b3 = *(const f16x8*)(Bp + (size_t)48 * K);
        acc0 = __builtin_amdgcn_mfma_f32_16x16x32_f16(a, b0, acc0, 0, 0, 0);
        acc1 = __builtin_amdgcn_mfma_f32_16x16x32_f16(a, b1, acc1, 0, 0, 0);
        acc2 = __builtin_amdgcn_mfma_f32_16x16x32_f16(a, b2, acc2, 0, 0, 0);
        acc3 = __builtin_amdgcn_mfma_f32_16x16x32_f16(a, b3, acc3, 0, 0, 0);
    }
    f32x4 accs[4] = {acc0, acc1, acc2, acc3};
#pragma unroll
    for (int ct = 0; ct < 4; ++ct) {
        int col = bn + ct * 16 + (l & 15);
#pragma unroll
        for (int r = 0; r < 4; ++r) {
            int row = bm + w * 16 + (l >> 4) * 4 + r;
            if (row < M) C16[(size_t)row * Nn + col] = (_Float16)accs[ct][r];
        }
    }
}

// ---------------- fused MFMA edge logits ----------------
// Block = 64 CSR edges. Stage FULL 64x64 f16 e-tile in padded LDS (two uint4
// per thread = 16 f16; round-8 bug staged only half). Per wave (= head w):
// 32 MFMA for efW tile; epilogue gathers xl/xr per C-fragment element,
// leaky+att-dot, 16-lane group reduce -> exp-logit.
__global__ __launch_bounds__(256) void edge_logits_mfma(const _Float16* __restrict__ e16,
                                                        const _Float16* __restrict__ weT16,
                                                        const float* __restrict__ xl,
                                                        const float* __restrict__ xr,
                                                        const int* __restrict__ srcp,
                                                        const int* __restrict__ dstp,
                                                        const float* __restrict__ att,
                                                        float* __restrict__ exlog) {
    __shared__ _Float16 es[64 * LROW];
    __shared__ int ssrc[64], sdst[64];
    int t = threadIdx.x;
    int w = t >> 6, l = t & 63;
    int base = blockIdx.x * 64;
    {   // stage: thread t copies 16 f16 (two uint4) of row t>>2, segment t&3
        int row = t >> 2, seg = t & 3;
        const _Float16* gp = e16 + (size_t)(base + row) * ED_ + seg * 16;
        uint4 v0 = *(const uint4*)(gp);
        uint4 v1 = *(const uint4*)(gp + 8);
        _Float16* lp = es + row * LROW + seg * 16;
        *(uint4*)(lp) = v0;
        *(uint4*)(lp + 8) = v1;
    }
    if (t < 64) { ssrc[t] = srcp[base + t]; sdst[t] = dstp[base + t]; }
    __syncthreads();
    int koff = (l >> 4) * 8;
    int cgrp = l & 15;
    // B fragments: head w's 64 cols of We (from WT[256][64])
    f16x8 bf[4][2];
#pragma unroll
    for (int nt = 0; nt < 4; ++nt) {
        const _Float16* bp = weT16 + (size_t)(w * 64 + nt * 16 + cgrp) * 64 + koff;
        bf[nt][0] = *(const f16x8*)(bp);
        bf[nt][1] = *(const f16x8*)(bp + 32);
    }
    f32x4 acc[4][4] = {};
#pragma unroll
    for (int mt = 0; mt < 4; ++mt) {
        f16x8 a0 = *(const f16x8*)(es + (mt * 16 + cgrp) * LROW + koff);
        f16x8 a1 = *(const f16x8*)(es + (mt * 16 + cgrp) * LROW + 32 + koff);
#pragma unroll
        for (int nt = 0; nt < 4; ++nt) {
            acc[mt][nt] = __builtin_amdgcn_mfma_f32_16x16x32_f16(a0, bf[nt][0], acc[mt][nt], 0, 0, 0);
            acc[mt][nt] = __builtin_amdgcn_mfma_f32_16x16x32_f16(a1, bf[nt][1], acc[mt][nt], 0, 0, 0);
        }
    }
    float av[4];
#pragma unroll
    for (int nt = 0; nt < 4; ++nt) av[nt] = att[w * 64 + nt * 16 + cgrp];
#pragma unroll
    for (int mt = 0; mt < 4; ++mt) {
#pragma unroll
        for (int r = 0; r < 4; ++r) {
            int eidx = mt * 16 + (l >> 4) * 4 + r;
            int s = ssrc[eidx], d = sdst[eidx];
            float v = 0.f;
#pragma unroll
            for (int nt = 0; nt < 4; ++nt) {
                int col = w * 64 + nt * 16 + cgrp;
                float m = xl[(size_t)s * D_ + col] + xr[(size_t)d * D_ + col] + acc[mt][nt][r];
                m = (m > 0.f) ? m : 0.2f * m;
                v += m * av[nt];
            }
            v += __shfl_xor(v, 1); v += __shfl_xor(v, 2);
            v += __shfl_xor(v, 4); v += __shfl_xor(v, 8);
            if (cgrp == 0) exlog[(size_t)(base + eidx) * H_ + w] = expf(v);
        }
    }
}

// ---------------- esum16: per-dst segment sum of e rows ----------------
__global__ __launch_bounds__(256) void esum_kernel(const _Float16* __restrict__ e16,
                                                   const int* __restrict__ row_off,
                                                   _Float16* __restrict__ esum16) {
    int d = blockIdx.x * 4 + (threadIdx.x >> 6);
    int lane = threadIdx.x & 63;
    if (d >= N_) return;
    int beg = row_off[d], end = row_off[d + 1];
    float s = 0.f;
    for (int i = beg; i < end; ++i) s += (float)e16[(size_t)i * ED_ + lane];
    esum16[(size_t)d * ED_ + lane] = (_Float16)s;
}

// ---------------- phase B: per-dst softmax + aggregation + silu/LN ----------
__global__ __launch_bounds__(256) void gat_agg(const float* __restrict__ xl,
                                               const float* __restrict__ xr,
                                               const float* __restrict__ loopW,
                                               const int* __restrict__ row_off,
                                               const int* __restrict__ srcp,
                                               const float* __restrict__ exlog,
                                               const float* __restrict__ att,
                                               const float* __restrict__ bias,
                                               const float* __restrict__ gs,
                                               const float* __restrict__ gb,
                                               _Float16* __restrict__ hn16) {
    int d = blockIdx.x, t = threadIdx.x;
    int w = t >> 6, lane = t & 63;
    int beg = row_off[d], end = row_off[d + 1];
    int deg = end - beg;
    float av = att[t];
    float xld = xl[(size_t)d * D_ + t];
    float xrd = xr[(size_t)d * D_ + t];
    float den = 0.f, out = 0.f;
    int i = beg;
    for (; i + 4 <= end; i += 4) {
        int s0 = srcp[i], s1 = srcp[i + 1], s2 = srcp[i + 2], s3 = srcp[i + 3];
        float ex0 = exlog[(size_t)i * H_ + w];
        float ex1 = exlog[(size_t)(i + 1) * H_ + w];
        float ex2 = exlog[(size_t)(i + 2) * H_ + w];
        float ex3 = exlog[(size_t)(i + 3) * H_ + w];
        float x0 = xl[(size_t)s0 * D_ + t];
        float x1 = xl[(size_t)s1 * D_ + t];
        float x2 = xl[(size_t)s2 * D_ + t];
        float x3 = xl[(size_t)s3 * D_ + t];
        den += (ex0 + ex1) + (ex2 + ex3);
        out += ex0 * x0 + ex1 * x1 + ex2 * x2 + ex3 * x3;
    }
    for (; i < end; ++i) {
        int s0 = srcp[i];
        float ex0 = exlog[(size_t)i * H_ + w];
        float x0 = xl[(size_t)s0 * D_ + t];
        den += ex0;
        out += ex0 * x0;
    }
    float lw = (deg > 0) ? loopW[(size_t)d * D_ + t] / (float)deg : 0.f;
    {
        float m = xld + xrd + lw;
        m = (m > 0.f) ? m : 0.2f * m;
        float v = m * av;
#pragma unroll
        for (int o = 32; o; o >>= 1) v += __shfl_xor(v, o);
        float eself = expf(v);
        den += eself;
        out += eself * xld;
    }
    out *= 1.f / (den + 1e-16f);
    float v = out + bias[t];
    v = v / (1.f + expf(-v));
    __shared__ float red[4];
    float s = v;
#pragma unroll
    for (int o = 32; o; o >>= 1) s += __shfl_xor(s, o);
    if (lane == 0) red[w] = s;
    __syncthreads();
    float mu = (red[0] + red[1] + red[2] + red[3]) * (1.f / 256.f);
    __syncthreads();
    float dv = v - mu;
    float q = dv * dv;
#pragma unroll
    for (int o = 32; o; o >>= 1) q += __shfl_xor(q, o);
    if (lane == 0) red[w] = q;
    __syncthreads();
    float var = (red[0] + red[1] + red[2] + red[3]) * (1.f / 256.f);
    hn16[(size_t)d * D_ + t] = (_Float16)(dv * rsqrtf(var + 1e-5f) * gs[t] + gb[t]);
}

// ---------------- edge MLP lite: e16 (holds e@eW3) + gathers + silu + LN -----
__global__ __launch_bounds__(256) void edge_mlp_lite(const _Float16* __restrict__ hsW16,
                                                     const _Float16* __restrict__ hdW16,
                                                     _Float16* __restrict__ e16,
                                                     const int* __restrict__ srcp,
                                                     const int* __restrict__ dstp,
                                                     const float* __restrict__ eb,
                                                     const float* __restrict__ gs,
                                                     const float* __restrict__ gb) {
    int t = threadIdx.x;
    int w = t >> 6, lane = t & 63;
    float ebv = eb[lane], gsv = gs[lane], gbv = gb[lane];
    int base = blockIdx.x * 64;
    for (int it = 0; it < 16; ++it) {
        int edge = base + it * 4 + w;
        float acc = ebv + (float)e16[(size_t)edge * ED_ + lane]
                        + (float)hsW16[(size_t)srcp[edge] * ED_ + lane]
                        + (float)hdW16[(size_t)dstp[edge] * ED_ + lane];
        float v = acc / (1.f + expf(-acc));
        float s = v;
#pragma unroll
        for (int o = 32; o; o >>= 1) s += __shfl_xor(s, o);
        float mu = s * (1.f / 64.f);
        float dv = v - mu;
        float q = dv * dv;
#pragma unroll
        for (int o = 32; o; o >>= 1) q += __shfl_xor(q, o);
        float rs = rsqrtf(q * (1.f / 64.f) + 1e-5f);
        e16[(size_t)edge * ED_ + lane] = (_Float16)(dv * rs * gsv + gbv);
    }
}

// ---------------- node silu + LN (final JK output) ----------------
__global__ __launch_bounds__(256) void node_silu_ln(const float* __restrict__ inp,
                                                    const float* __restrict__ gs,
                                                    const float* __restrict__ gb,
                                                    float* __restrict__ outp) {
    int n = blockIdx.x, t = threadIdx.x;
    float v = inp[(size_t)n * D_ + t];
    v = v / (1.f + expf(-v));
    __shared__ float red[4];
    float s = v;
#pragma unroll
    for (int o = 32; o; o >>= 1) s += __shfl_xor(s, o);
    if ((t & 63) == 0) red[t >> 6] = s;
    __syncthreads();
    float mu = (red[0] + red[1] + red[2] + red[3]) * (1.f / 256.f);
    __syncthreads();
    float dv = v - mu;
    float q = dv * dv;
#pragma unroll
    for (int o = 32; o; o >>= 1) q += __shfl_xor(q, o);
    if ((t & 63) == 0) red[t >> 6] = q;
    __syncthreads();
    float var = (red[0] + red[1] + red[2] + red[3]) * (1.f / 256.f);
    outp[(size_t)n * D_ + t] = dv * rsqrtf(var + 1e-5f) * gs[t] + gb[t];
}

// ---------------- gate MLP + softmax denom ----------------
__global__ __launch_bounds__(128) void gate_kernel(const float* __restrict__ h,
                                                   const float* __restrict__ gW1,
                                                   const float* __restrict__ gb1,
                                                   const float* __restrict__ gW2,
                                                   const float* __restrict__ gb2,
                                                   const int* __restrict__ batch,
                                                   float* __restrict__ g,
                                                   float* __restrict__ gden) {
    int n = blockIdx.x, t = threadIdx.x; // 128 threads
    const float* hn = h + (size_t)n * D_;
    float acc = gb1[t];
    for (int k = 0; k < D_; ++k) acc += hn[k] * gW1[k * 128 + t];
    acc = acc / (1.f + expf(-acc));
    float v = acc * gW2[t];
#pragma unroll
    for (int o = 32; o; o >>= 1) v += __shfl_xor(v, o);
    __shared__ float r2[2];
    if ((t & 63) == 0) r2[t >> 6] = v;
    __syncthreads();
    if (t == 0) {
        float gg = r2[0] + r2[1] + gb2[0];
        g[n] = gg;
        atomicAdd(&gden[batch[n]], expf(gg));
    }
}

__global__ __launch_bounds__(256) void pool_kernel(const float* __restrict__ h,
                                                   const float* __restrict__ g,
                                                   const float* __restrict__ gden,
                                                   const int* __restrict__ batch,
                                                   float* __restrict__ hgraph) {
    int idx = blockIdx.x * 256 + threadIdx.x;
    if (idx >= N_ * D_) return;
    int n = idx >> 8;
    int b = batch[n];
    float w = expf(g[n]) / (gden[b] + 1e-16f);
    atomicAdd(&hgraph[(size_t)b * D_ + (idx & 255)], w * h[idx]);
}

__global__ __launch_bounds__(256) void head_kernel(const float* __restrict__ hgraph,
                                                   const float* __restrict__ hW,
                                                   const float* __restrict__ hb,
                                                   float* __restrict__ out) {
    int gp = blockIdx.x, t = threadIdx.x;
    float v = hgraph[(size_t)gp * D_ + t] * hW[t];
#pragma unroll
    for (int o = 32; o; o >>= 1) v += __shfl_xor(v, o);
    __shared__ float r4[4];
    if ((t & 63) == 0) r4[t >> 6] = v;
    __syncthreads();
    if (t == 0) out[gp] = r4[0] + r4[1] + r4[2] + r4[3] + hb[0];
}

// ---------------- host launch ----------------
extern "C" void kernel_launch(void* const* d_in, const int* in_sizes, int n_in,
                              void* d_out, int out_size, void* d_ws, size_t ws_size,
                              hipStream_t stream) {
    const float* x     = (const float*)d_in[0];
    const int*   eidx  = (const int*)d_in[1];
    const float* eattr = (const float*)d_in[2];
    const int*   batch = (const int*)d_in[3];
    const float* atomW = (const float*)d_in[4];
    const float* atomB = (const float*)d_in[5];
    const float* bondW = (const float*)d_in[6];
    const float* bondB = (const float*)d_in[7];
    const float* Wl    = (const float*)d_in[8];
    const float* bl    = (const float*)d_in[9];
    const float* Wr    = (const float*)d_in[10];
    const float* br    = (const float*)d_in[11];
    const float* We    = (const float*)d_in[12];
    const float* att   = (const float*)d_in[13];
    const float* bias  = (const float*)d_in[14];
    const float* ln1s  = (const float*)d_in[15];
    const float* ln1b  = (const float*)d_in[16];
    const float* eW    = (const float*)d_in[17];
    const float* eb    = (const float*)d_in[18];
    const float* ln2s  = (const float*)d_in[19];
    const float* ln2b  = (const float*)d_in[20];
    const float* jkW   = (const float*)d_in[21];
    const float* jkb   = (const float*)d_in[22];
    const float* ln3s  = (const float*)d_in[23];
    const float* ln3b  = (const float*)d_in[24];
    const float* gW1   = (const float*)d_in[25];
    const float* gb1   = (const float*)d_in[26];
    const float* gW2   = (const float*)d_in[27];
    const float* gb2   = (const float*)d_in[28];
    const float* hW    = (const float*)d_in[29];
    const float* hb    = (const float*)d_in[30];

    const int* src = eidx;
    const int* dst = eidx + E_;

    // ---- workspace layout (~165 MB) ----
    char* wp = (char*)d_ws;
    auto take = [&](size_t bytes) {
        char* p = wp;
        wp += (bytes + 255) & ~(size_t)255;
        return (void*)p;
    };
    _Float16*  e16     = (_Float16*)take((size_t)E_ * ED_ * 2); // 40.96 MB, CSR-permuted
    float*     xl      = (float*)take((size_t)N_ * D_ * 4);     // 20.48 MB (hfin at end)
    float*     xr      = (float*)take((size_t)N_ * D_ * 4);     // 20.48 MB
    float*     jkacc   = (float*)take((size_t)N_ * D_ * 4);     // 20.48 MB
    float*     loopW   = (float*)take((size_t)N_ * D_ * 4);     // 20.48 MB
    _Float16*  h16A    = (_Float16*)take((size_t)N_ * D_ * 2);  // 10.24 MB
    _Float16*  h16B    = (_Float16*)take((size_t)N_ * D_ * 2);  // 10.24 MB
    _Float16*  hsW16   = (_Float16*)take((size_t)N_ * ED_ * 2); // 2.56 MB
    _Float16*  hdW16   = (_Float16*)take((size_t)N_ * ED_ * 2); // 2.56 MB
    float*     exlog   = (float*)take((size_t)E_ * H_ * 4);     // 5.12 MB
    _Float16*  esum16  = (_Float16*)take((size_t)N_ * ED_ * 2); // 2.56 MB
    _Float16*  wlT16   = (_Float16*)take((size_t)L_ * D_ * D_ * 2);
    _Float16*  wrT16   = (_Float16*)take((size_t)L_ * D_ * D_ * 2);
    _Float16*  weT16   = (_Float16*)take((size_t)L_ * ED_ * D_ * 2);
    _Float16*  ewsT16  = (_Float16*)take((size_t)L_ * D_ * ED_ * 2);
    _Float16*  ewdT16  = (_Float16*)take((size_t)L_ * D_ * ED_ * 2);
    _Float16*  ew3T16  = (_Float16*)take((size_t)L_ * ED_ * ED_ * 2);
    _Float16*  jkwT16  = (_Float16*)take((size_t)L_ * D_ * D_ * 2);
    int*   deg_i   = (int*)take((size_t)N_ * 4);
    int*   fill    = (int*)take((size_t)N_ * 4);
    int*   row_off = (int*)take((size_t)(N_ + 1) * 4);
    int*   perm    = (int*)take((size_t)E_ * 4);
    int*   srcp    = (int*)take((size_t)E_ * 4);
    int*   dstp    = (int*)take((size_t)E_ * 4);
    float* g       = (float*)take((size_t)N_ * 4);
    float* gden    = (float*)take((size_t)G_ * 4);
    float* hgraph  = (float*)take((size_t)G_ * D_ * 4);

    // ---- weight pre-pack (f32 -> transposed f16) ----
    auto pack = [&](const float* W, _Float16* WT, int K, int Nn) {
        pack_wT<<<(K * Nn + 255) / 256, 256, 0, stream>>>(W, WT, K, Nn);
    };
    for (int l = 0; l < L_; ++l) {
        pack(Wl + (size_t)l * D_ * D_, wlT16 + (size_t)l * D_ * D_, D_, D_);
        pack(Wr + (size_t)l * D_ * D_, wrT16 + (size_t)l * D_ * D_, D_, D_);
        pack(We + (size_t)l * ED_ * D_, weT16 + (size_t)l * ED_ * D_, ED_, D_);
        const float* eW_l = eW + (size_t)l * (2 * D_ + ED_) * ED_;
        pack(eW_l,                        ewsT16 + (size_t)l * D_ * ED_, D_, ED_);
        pack(eW_l + (size_t)D_ * ED_,     ewdT16 + (size_t)l * D_ * ED_, D_, ED_);
        pack(eW_l + (size_t)2 * D_ * ED_, ew3T16 + (size_t)l * ED_ * ED_, ED_, ED_);
        pack(jkW + (size_t)l * D_ * D_,   jkwT16 + (size_t)l * D_ * D_, D_, D_);
    }

    // ---- CSR build ----
    hipMemsetAsync(deg_i, 0, (size_t)N_ * 4, stream);
    hipMemsetAsync(fill, 0, (size_t)N_ * 4, stream);
    count_kernel<<<(E_ + 255) / 256, 256, 0, stream>>>(dst, deg_i);
    scan_kernel<<<1, 1024, 0, stream>>>(deg_i, row_off);
    fill_kernel<<<(E_ + 255) / 256, 256, 0, stream>>>(src, dst, row_off, fill,
                                                      perm, srcp, dstp);

    // encoders
    atom_enc<<<N_, 256, 0, stream>>>(x, atomW, atomB, h16A);
    bond_enc_perm<<<(E_ * ED_ + 255) / 256, 256, 0, stream>>>(eattr, bondW, bondB,
                                                              perm, e16);

    const int MB = (N_ + 63) / 64;  // 313
    const _Float16* h16_prev = h16A;
    for (int l = 0; l < L_; ++l) {
        const float* bl_l = bl + (size_t)l * D_;
        const float* br_l = br + (size_t)l * D_;
        const float* att_l = att + (size_t)l * H_ * C_;
        const float* bias_l = bias + (size_t)l * D_;
        const float* ln1s_l = ln1s + (size_t)l * D_;
        const float* ln1b_l = ln1b + (size_t)l * D_;
        const float* eb_l = eb + (size_t)l * ED_;
        const float* ln2s_l = ln2s + (size_t)l * ED_;
        const float* ln2b_l = ln2b + (size_t)l * ED_;
        const _Float16* weT_l = weT16 + (size_t)l * ED_ * D_;
        _Float16* hn16_l = (l & 1) ? h16A : h16B;

        // xl/xr projections (MFMA)
        {
            dim3 grid(MB, D_ / 64);
            mfma_gemm<<<grid, 256, 0, stream>>>(h16_prev, wlT16 + (size_t)l * D_ * D_,
                                                bl_l, xl, N_, D_, D_, 0);
            mfma_gemm<<<grid, 256, 0, stream>>>(h16_prev, wrT16 + (size_t)l * D_ * D_,
                                                br_l, xr, N_, D_, D_, 0);
        }

        // self-loop term: esum16 then esum16@We -> loopW (MFMA, K=64)
        esum_kernel<<<(N_ + 3) / 4, 256, 0, stream>>>(e16, row_off, esum16);
        {
            dim3 grid(MB, D_ / 64);
            mfma_gemm<<<grid, 256, 0, stream>>>(esum16, weT_l, nullptr, loopW,
                                                N_, ED_, D_, 0);
        }

        // phase A: fused MFMA edge logits
        edge_logits_mfma<<<E_ / 64, 256, 0, stream>>>(e16, weT_l, xl, xr,
                                                      srcp, dstp, att_l, exlog);

        // phase B: per-dst softmax + aggregation + silu/LN -> hn16
        gat_agg<<<N_, 256, 0, stream>>>(xl, xr, loopW, row_off, srcp, exlog,
                                        att_l, bias_l, ln1s_l, ln1b_l, hn16_l);

        // factored edge MLP: hsW16 = hn@eWs, hdW16 = hn@eWd, e16 <- e16@eW3 (in-place)
        {
            dim3 grid(MB, 1);
            mfma_gemm16<<<grid, 256, 0, stream>>>(hn16_l, ewsT16 + (size_t)l * D_ * ED_,
                                                  hsW16, N_, D_, ED_);
            mfma_gemm16<<<grid, 256, 0, stream>>>(hn16_l, ewdT16 + (size_t)l * D_ * ED_,
                                                  hdW16, N_, D_, ED_);
        }
        mfma_gemm16<<<dim3(E_ / 64, 1), 256, 0, stream>>>(e16, ew3T16 + (size_t)l * ED_ * ED_,
                                                          e16, E_, ED_, ED_);
        edge_mlp_lite<<<E_ / 64, 256, 0, stream>>>(hsW16, hdW16, e16, srcp, dstp,
                                                   eb_l, ln2s_l, ln2b_l);

        // incremental JK: jkacc (+)= hn @ jkW_l (MFMA)
        {
            dim3 grid(MB, D_ / 64);
            mfma_gemm<<<grid, 256, 0, stream>>>(hn16_l, jkwT16 + (size_t)l * D_ * D_,
                                                (l == 0) ? jkb : nullptr,
                                                jkacc, N_, D_, D_, (l == 0) ? 0 : 1);
        }

        h16_prev = hn16_l;
    }

    float* hfin = xl;
    node_silu_ln<<<N_, 256, 0, stream>>>(jkacc, ln3s, ln3b, hfin);

    hipMemsetAsync(gden, 0, (size_t)G_ * 4, stream);
    hipMemsetAsync(hgraph, 0, (size_t)G_ * D_ * 4, stream);
    gate_kernel<<<N_, 128, 0, stream>>>(hfin, gW1, gb1, gW2, gb2, batch, g, gden);
    pool_kernel<<<(N_ * D_ + 255) / 256, 256, 0, stream>>>(hfin, g, gden, batch, hgraph);
    head_kernel<<<G_, 256, 0, stream>>>(hgraph, hW, hb, (float*)d_out);
}

// Round 10
// 1786.820 us; speedup vs baseline: 6.7484x; 1.0693x over previous
//
#include <hip/hip_runtime.h>
#include <hip/hip_bf16.h>

// Problem constants
#define N_ 20000
#define E_ 320000
#define G_ 128
#define H_ 4
#define C_ 64
#define D_ 256
#define ED_ 64
#define L_ 4
#define LROW 72  // padded LDS row stride (f16 units)

typedef _Float16 f16x8 __attribute__((ext_vector_type(8)));
typedef _Float16 f16x4 __attribute__((ext_vector_type(4)));
typedef float f32x4 __attribute__((ext_vector_type(4)));

// ---------------- encoders ----------------
__global__ __launch_bounds__(256) void atom_enc(const float* __restrict__ x,
                                                const float* __restrict__ W,
                                                const float* __restrict__ b,
                                                _Float16* __restrict__ h16) {
    int n = blockIdx.x, t = threadIdx.x;
    float acc = b[t];
#pragma unroll
    for (int k = 0; k < 9; ++k) acc += x[n * 9 + k] * W[k * D_ + t];
    h16[(size_t)n * D_ + t] = (_Float16)acc;
}

__global__ __launch_bounds__(256) void bond_enc_perm(const float* __restrict__ ea,
                                                     const float* __restrict__ W,
                                                     const float* __restrict__ b,
                                                     const int* __restrict__ perm,
                                                     _Float16* __restrict__ e16) {
    int idx = blockIdx.x * 256 + threadIdx.x;
    if (idx >= E_ * ED_) return;
    int pos = idx >> 6, j = idx & 63;
    int orig = perm[pos];
    float acc = b[j];
#pragma unroll
    for (int k = 0; k < 3; ++k) acc += ea[orig * 3 + k] * W[k * ED_ + j];
    e16[idx] = (_Float16)acc;
}

// ---------------- CSR build (dst-sorted) ----------------
__global__ __launch_bounds__(256) void count_kernel(const int* __restrict__ dst,
                                                    int* __restrict__ deg) {
    int e = blockIdx.x * 256 + threadIdx.x;
    if (e >= E_) return;
    atomicAdd(&deg[dst[e]], 1);
}

__global__ __launch_bounds__(1024) void scan_kernel(const int* __restrict__ deg,
                                                    int* __restrict__ row_off) {
    __shared__ int part[1024];
    int t = threadIdx.x;
    const int CH = (N_ + 1023) / 1024;  // 20
    int s = 0;
    for (int i = 0; i < CH; ++i) {
        int idx = t * CH + i;
        if (idx < N_) s += deg[idx];
    }
    part[t] = s;
    __syncthreads();
    for (int off = 1; off < 1024; off <<= 1) {
        int v = (t >= off) ? part[t - off] : 0;
        __syncthreads();
        part[t] += v;
        __syncthreads();
    }
    int base = (t == 0) ? 0 : part[t - 1];
    for (int i = 0; i < CH; ++i) {
        int idx = t * CH + i;
        if (idx < N_) { row_off[idx] = base; base += deg[idx]; }
    }
    if (t == 0) row_off[N_] = part[1023];
}

__global__ __launch_bounds__(256) void fill_kernel(const int* __restrict__ src,
                                                   const int* __restrict__ dst,
                                                   const int* __restrict__ row_off,
                                                   int* __restrict__ fill,
                                                   int* __restrict__ perm,
                                                   int* __restrict__ srcp,
                                                   int* __restrict__ dstp) {
    int e = blockIdx.x * 256 + threadIdx.x;
    if (e >= E_) return;
    int d = dst[e];
    int pos = row_off[d] + atomicAdd(&fill[d], 1);
    perm[pos] = e;
    srcp[pos] = src[e];
    dstp[pos] = d;
}

// ---------------- weight pre-pack: W[K][N] f32 -> WT[N][K] f16 ----------------
__global__ __launch_bounds__(256) void pack_wT(const float* __restrict__ W,
                                               _Float16* __restrict__ WT,
                                               int K, int Nn) {
    int idx = blockIdx.x * 256 + threadIdx.x;
    if (idx >= K * Nn) return;
    int n = idx / K, k = idx - n * K;
    WT[idx] = (_Float16)W[(size_t)k * Nn + n];
}

// ---------------- MFMA f16 GEMM (f32 out, bias, accum) ----------------
__global__ __launch_bounds__(256) void mfma_gemm(const _Float16* __restrict__ A16,
                                                 const _Float16* __restrict__ BT16,
                                                 const float* __restrict__ bias,
                                                 float* __restrict__ C,
                                                 int M, int K, int Nn, int accum) {
    int t = threadIdx.x;
    int w = t >> 6, l = t & 63;
    int bm = blockIdx.x * 64, bn = blockIdx.y * 64;
    int row0 = bm + w * 16 + (l & 15);
    int arow = row0 < M ? row0 : M - 1;
    int koff = (l >> 4) * 8;
    const _Float16* Ap = A16 + (size_t)arow * K + koff;
    f32x4 acc0 = {}, acc1 = {}, acc2 = {}, acc3 = {};
    for (int ks = 0; ks < K; ks += 32) {
        f16x8 a = *(const f16x8*)(Ap + ks);
        const _Float16* Bp = BT16 + (size_t)(bn + (l & 15)) * K + ks + koff;
        f16x8 b0 = *(const f16x8*)(Bp);
        f16x8 b1 = *(const f16x8*)(Bp + (size_t)16 * K);
        f16x8 b2 = *(const f16x8*)(Bp + (size_t)32 * K);
        f16x8 b3 = *(const f16x8*)(Bp + (size_t)48 * K);
        acc0 = __builtin_amdgcn_mfma_f32_16x16x32_f16(a, b0, acc0, 0, 0, 0);
        acc1 = __builtin_amdgcn_mfma_f32_16x16x32_f16(a, b1, acc1, 0, 0, 0);
        acc2 = __builtin_amdgcn_mfma_f32_16x16x32_f16(a, b2, acc2, 0, 0, 0);
        acc3 = __builtin_amdgcn_mfma_f32_16x16x32_f16(a, b3, acc3, 0, 0, 0);
    }
    f32x4 accs[4] = {acc0, acc1, acc2, acc3};
#pragma unroll
    for (int ct = 0; ct < 4; ++ct) {
        int col = bn + ct * 16 + (l & 15);
#pragma unroll
        for (int r = 0; r < 4; ++r) {
            int row = bm + w * 16 + (l >> 4) * 4 + r;
            if (row < M) {
                float v = accs[ct][r] + (bias ? bias[col] : 0.f);
                if (accum) C[(size_t)row * Nn + col] += v;
                else       C[(size_t)row * Nn + col] = v;
            }
        }
    }
}

// ---------------- MFMA f16 GEMM, f16 out, optional bias ----------------
// Safe in-place (C16 == A16): wave w reads exactly A rows [bm+16w, bm+16w+16)
// and writes the same rows; loads drain into MFMAs before stores issue.
__global__ __launch_bounds__(256) void mfma_gemm16(const _Float16* __restrict__ A16,
                                                   const _Float16* __restrict__ BT16,
                                                   const float* __restrict__ bias,
                                                   _Float16* __restrict__ C16,
                                                   int M, int K, int Nn) {
    int t = threadIdx.x;
    int w = t >> 6, l = t & 63;
    int bm = blockIdx.x * 64, bn = blockIdx.y * 64;
    int row0 = bm + w * 16 + (l & 15);
    int arow = row0 < M ? row0 : M - 1;
    int koff = (l >> 4) * 8;
    const _Float16* Ap = A16 + (size_t)arow * K + koff;
    f32x4 acc0 = {}, acc1 = {}, acc2 = {}, acc3 = {};
    for (int ks = 0; ks < K; ks += 32) {
        f16x8 a = *(const f16x8*)(Ap + ks);
        const _Float16* Bp = BT16 + (size_t)(bn + (l & 15)) * K + ks + koff;
        f16x8 b0 = *(const f16x8*)(Bp);
        f16x8 b1 = *(const f16x8*)(Bp + (size_t)16 * K);
        f16x8 b2 = *(const f16x8*)(Bp + (size_t)32 * K);
        f16x8 b3 = *(const f16x8*)(Bp + (size_t)48 * K);
        acc0 = __builtin_amdgcn_mfma_f32_16x16x32_f16(a, b0, acc0, 0, 0, 0);
        acc1 = __builtin_amdgcn_mfma_f32_16x16x32_f16(a, b1, acc1, 0, 0, 0);
        acc2 = __builtin_amdgcn_mfma_f32_16x16x32_f16(a, b2, acc2, 0, 0, 0);
        acc3 = __builtin_amdgcn_mfma_f32_16x16x32_f16(a, b3, acc3, 0, 0, 0);
    }
    f32x4 accs[4] = {acc0, acc1, acc2, acc3};
#pragma unroll
    for (int ct = 0; ct < 4; ++ct) {
        int col = bn + ct * 16 + (l & 15);
        float bv = bias ? bias[col] : 0.f;
#pragma unroll
        for (int r = 0; r < 4; ++r) {
            int row = bm + w * 16 + (l >> 4) * 4 + r;
            if (row < M) C16[(size_t)row * Nn + col] = (_Float16)(accs[ct][r] + bv);
        }
    }
}

// ---------------- fused MFMA edge logits (f16 xl/xr) ----------------
__global__ __launch_bounds__(256) void edge_logits_mfma(const _Float16* __restrict__ e16,
                                                        const _Float16* __restrict__ weT16,
                                                        const _Float16* __restrict__ xl16,
                                                        const _Float16* __restrict__ xr16,
                                                        const int* __restrict__ srcp,
                                                        const int* __restrict__ dstp,
                                                        const float* __restrict__ att,
                                                        float* __restrict__ exlog) {
    __shared__ _Float16 es[64 * LROW];
    __shared__ int ssrc[64], sdst[64];
    int t = threadIdx.x;
    int w = t >> 6, l = t & 63;
    int base = blockIdx.x * 64;
    {   // stage full 64x64 tile: thread t copies 16 f16 (two uint4)
        int row = t >> 2, seg = t & 3;
        const _Float16* gp = e16 + (size_t)(base + row) * ED_ + seg * 16;
        uint4 v0 = *(const uint4*)(gp);
        uint4 v1 = *(const uint4*)(gp + 8);
        _Float16* lp = es + row * LROW + seg * 16;
        *(uint4*)(lp) = v0;
        *(uint4*)(lp + 8) = v1;
    }
    if (t < 64) { ssrc[t] = srcp[base + t]; sdst[t] = dstp[base + t]; }
    __syncthreads();
    int koff = (l >> 4) * 8;
    int cgrp = l & 15;
    f16x8 bf[4][2];
#pragma unroll
    for (int nt = 0; nt < 4; ++nt) {
        const _Float16* bp = weT16 + (size_t)(w * 64 + nt * 16 + cgrp) * 64 + koff;
        bf[nt][0] = *(const f16x8*)(bp);
        bf[nt][1] = *(const f16x8*)(bp + 32);
    }
    f32x4 acc[4][4] = {};
#pragma unroll
    for (int mt = 0; mt < 4; ++mt) {
        f16x8 a0 = *(const f16x8*)(es + (mt * 16 + cgrp) * LROW + koff);
        f16x8 a1 = *(const f16x8*)(es + (mt * 16 + cgrp) * LROW + 32 + koff);
#pragma unroll
        for (int nt = 0; nt < 4; ++nt) {
            acc[mt][nt] = __builtin_amdgcn_mfma_f32_16x16x32_f16(a0, bf[nt][0], acc[mt][nt], 0, 0, 0);
            acc[mt][nt] = __builtin_amdgcn_mfma_f32_16x16x32_f16(a1, bf[nt][1], acc[mt][nt], 0, 0, 0);
        }
    }
    float av[4];
#pragma unroll
    for (int nt = 0; nt < 4; ++nt) av[nt] = att[w * 64 + nt * 16 + cgrp];
#pragma unroll
    for (int mt = 0; mt < 4; ++mt) {
#pragma unroll
        for (int r = 0; r < 4; ++r) {
            int eidx = mt * 16 + (l >> 4) * 4 + r;
            int s = ssrc[eidx], d = sdst[eidx];
            float v = 0.f;
#pragma unroll
            for (int nt = 0; nt < 4; ++nt) {
                int col = w * 64 + nt * 16 + cgrp;
                float m = (float)xl16[(size_t)s * D_ + col] + (float)xr16[(size_t)d * D_ + col]
                          + acc[mt][nt][r];
                m = (m > 0.f) ? m : 0.2f * m;
                v += m * av[nt];
            }
            v += __shfl_xor(v, 1); v += __shfl_xor(v, 2);
            v += __shfl_xor(v, 4); v += __shfl_xor(v, 8);
            if (cgrp == 0) exlog[(size_t)(base + eidx) * H_ + w] = expf(v);
        }
    }
}

// ---------------- esum16: per-dst segment sum of e rows ----------------
__global__ __launch_bounds__(256) void esum_kernel(const _Float16* __restrict__ e16,
                                                   const int* __restrict__ row_off,
                                                   _Float16* __restrict__ esum16) {
    int d = blockIdx.x * 4 + (threadIdx.x >> 6);
    int lane = threadIdx.x & 63;
    if (d >= N_) return;
    int beg = row_off[d], end = row_off[d + 1];
    float s = 0.f;
    for (int i = beg; i < end; ++i) s += (float)e16[(size_t)i * ED_ + lane];
    esum16[(size_t)d * ED_ + lane] = (_Float16)s;
}

// ---------------- phase B: wave-per-dst softmax + aggregation + silu/LN ------
// Barrier-free: wave w handles node blockIdx.x*4+w; lane holds 4 features
// (head = lane>>4). Per edge: 1 f16x4 gather per lane, 4-edge unroll.
__global__ __launch_bounds__(256) void gat_agg4(const _Float16* __restrict__ xl16,
                                                const _Float16* __restrict__ xr16,
                                                const float* __restrict__ loopW,
                                                const int* __restrict__ row_off,
                                                const int* __restrict__ srcp,
                                                const float* __restrict__ exlog,
                                                const float* __restrict__ att,
                                                const float* __restrict__ bias,
                                                const float* __restrict__ gs,
                                                const float* __restrict__ gb,
                                                _Float16* __restrict__ hn16) {
    int t = threadIdx.x;
    int w = t >> 6, lane = t & 63;
    int d = blockIdx.x * 4 + w;
    if (d >= N_) return;
    int beg = row_off[d], end = row_off[d + 1];
    int deg = end - beg;
    int hh = lane >> 4;
    float4 av = *(const float4*)&att[lane * 4];
    f16x4 xld_h = *(const f16x4*)&xl16[(size_t)d * D_ + lane * 4];
    f16x4 xrd_h = *(const f16x4*)&xr16[(size_t)d * D_ + lane * 4];
    float xld[4], xrd[4];
#pragma unroll
    for (int j = 0; j < 4; ++j) { xld[j] = (float)xld_h[j]; xrd[j] = (float)xrd_h[j]; }
    float den = 0.f;
    float out[4] = {0.f, 0.f, 0.f, 0.f};
    int i = beg;
    for (; i + 4 <= end; i += 4) {
        int s0 = srcp[i], s1 = srcp[i + 1], s2 = srcp[i + 2], s3 = srcp[i + 3];
        float ex0 = exlog[(size_t)i * H_ + hh];
        float ex1 = exlog[(size_t)(i + 1) * H_ + hh];
        float ex2 = exlog[(size_t)(i + 2) * H_ + hh];
        float ex3 = exlog[(size_t)(i + 3) * H_ + hh];
        f16x4 x0 = *(const f16x4*)&xl16[(size_t)s0 * D_ + lane * 4];
        f16x4 x1 = *(const f16x4*)&xl16[(size_t)s1 * D_ + lane * 4];
        f16x4 x2 = *(const f16x4*)&xl16[(size_t)s2 * D_ + lane * 4];
        f16x4 x3 = *(const f16x4*)&xl16[(size_t)s3 * D_ + lane * 4];
        den += (ex0 + ex1) + (ex2 + ex3);
#pragma unroll
        for (int j = 0; j < 4; ++j)
            out[j] += ex0 * (float)x0[j] + ex1 * (float)x1[j] +
                      ex2 * (float)x2[j] + ex3 * (float)x3[j];
    }
    for (; i < end; ++i) {
        int s0 = srcp[i];
        float ex0 = exlog[(size_t)i * H_ + hh];
        f16x4 x0 = *(const f16x4*)&xl16[(size_t)s0 * D_ + lane * 4];
        den += ex0;
#pragma unroll
        for (int j = 0; j < 4; ++j) out[j] += ex0 * (float)x0[j];
    }
    // self loop
    float4 lw4 = *(const float4*)&loopW[(size_t)d * D_ + lane * 4];
    float idg = (deg > 0) ? 1.f / (float)deg : 0.f;
    {
        float v = 0.f;
        float lw[4] = {lw4.x * idg, lw4.y * idg, lw4.z * idg, lw4.w * idg};
        float avv[4] = {av.x, av.y, av.z, av.w};
#pragma unroll
        for (int j = 0; j < 4; ++j) {
            float m = xld[j] + xrd[j] + lw[j];
            m = (m > 0.f) ? m : 0.2f * m;
            v += m * avv[j];
        }
        v += __shfl_xor(v, 1); v += __shfl_xor(v, 2);
        v += __shfl_xor(v, 4); v += __shfl_xor(v, 8);  // 16-lane head group
        float eself = expf(v);
        den += eself;
#pragma unroll
        for (int j = 0; j < 4; ++j) out[j] += eself * xld[j];
    }
    float inv = 1.f / (den + 1e-16f);
    float4 b4 = *(const float4*)&bias[lane * 4];
    float bv[4] = {b4.x, b4.y, b4.z, b4.w};
    float v4[4], s = 0.f;
#pragma unroll
    for (int j = 0; j < 4; ++j) {
        float v = out[j] * inv + bv[j];
        v = v / (1.f + expf(-v));
        v4[j] = v;
        s += v;
    }
#pragma unroll
    for (int o = 32; o; o >>= 1) s += __shfl_xor(s, o);
    float mu = s * (1.f / 256.f);
    float q = 0.f;
#pragma unroll
    for (int j = 0; j < 4; ++j) { float dv = v4[j] - mu; q += dv * dv; }
#pragma unroll
    for (int o = 32; o; o >>= 1) q += __shfl_xor(q, o);
    float rs = rsqrtf(q * (1.f / 256.f) + 1e-5f);
    float4 g4 = *(const float4*)&gs[lane * 4];
    float4 gb4 = *(const float4*)&gb[lane * 4];
    float gsv[4] = {g4.x, g4.y, g4.z, g4.w};
    float gbv[4] = {gb4.x, gb4.y, gb4.z, gb4.w};
    f16x4 o4;
#pragma unroll
    for (int j = 0; j < 4; ++j) o4[j] = (_Float16)((v4[j] - mu) * rs * gsv[j] + gbv[j]);
    *(f16x4*)&hn16[(size_t)d * D_ + lane * 4] = o4;
}

// ---------------- edge MLP lite ----------------
__global__ __launch_bounds__(256) void edge_mlp_lite(const _Float16* __restrict__ hsW16,
                                                     const _Float16* __restrict__ hdW16,
                                                     _Float16* __restrict__ e16,
                                                     const int* __restrict__ srcp,
                                                     const int* __restrict__ dstp,
                                                     const float* __restrict__ eb,
                                                     const float* __restrict__ gs,
                                                     const float* __restrict__ gb) {
    int t = threadIdx.x;
    int w = t >> 6, lane = t & 63;
    float ebv = eb[lane], gsv = gs[lane], gbv = gb[lane];
    int base = blockIdx.x * 64;
    for (int it = 0; it < 16; ++it) {
        int edge = base + it * 4 + w;
        float acc = ebv + (float)e16[(size_t)edge * ED_ + lane]
                        + (float)hsW16[(size_t)srcp[edge] * ED_ + lane]
                        + (float)hdW16[(size_t)dstp[edge] * ED_ + lane];
        float v = acc / (1.f + expf(-acc));
        float s = v;
#pragma unroll
        for (int o = 32; o; o >>= 1) s += __shfl_xor(s, o);
        float mu = s * (1.f / 64.f);
        float dv = v - mu;
        float q = dv * dv;
#pragma unroll
        for (int o = 32; o; o >>= 1) q += __shfl_xor(q, o);
        float rs = rsqrtf(q * (1.f / 64.f) + 1e-5f);
        e16[(size_t)edge * ED_ + lane] = (_Float16)(dv * rs * gsv + gbv);
    }
}

// ---------------- node silu + LN (final JK output; f32 + f16 outs) ----------
__global__ __launch_bounds__(256) void node_silu_ln(const float* __restrict__ inp,
                                                    const float* __restrict__ gs,
                                                    const float* __restrict__ gb,
                                                    float* __restrict__ outp,
                                                    _Float16* __restrict__ outp16) {
    int n = blockIdx.x, t = threadIdx.x;
    float v = inp[(size_t)n * D_ + t];
    v = v / (1.f + expf(-v));
    __shared__ float red[4];
    float s = v;
#pragma unroll
    for (int o = 32; o; o >>= 1) s += __shfl_xor(s, o);
    if ((t & 63) == 0) red[t >> 6] = s;
    __syncthreads();
    float mu = (red[0] + red[1] + red[2] + red[3]) * (1.f / 256.f);
    __syncthreads();
    float dv = v - mu;
    float q = dv * dv;
#pragma unroll
    for (int o = 32; o; o >>= 1) q += __shfl_xor(q, o);
    if ((t & 63) == 0) red[t >> 6] = q;
    __syncthreads();
    float var = (red[0] + red[1] + red[2] + red[3]) * (1.f / 256.f);
    float r = dv * rsqrtf(var + 1e-5f) * gs[t] + gb[t];
    outp[(size_t)n * D_ + t] = r;
    outp16[(size_t)n * D_ + t] = (_Float16)r;
}

// ---------------- gate lite: silu(hid)·gW2 reduce + softmax denom ------------
__global__ __launch_bounds__(256) void gate_lite(const float* __restrict__ hid,
                                                 const float* __restrict__ gW2,
                                                 const float* __restrict__ gb2,
                                                 const int* __restrict__ batch,
                                                 float* __restrict__ g,
                                                 float* __restrict__ gden) {
    int t = threadIdx.x;
    int w = t >> 6, lane = t & 63;
    int n = blockIdx.x * 4 + w;
    if (n >= N_) return;
    float2 h2 = *(const float2*)&hid[(size_t)n * 128 + lane * 2];
    float w0 = gW2[lane * 2], w1 = gW2[lane * 2 + 1];
    float s0 = h2.x / (1.f + expf(-h2.x));
    float s1 = h2.y / (1.f + expf(-h2.y));
    float v = s0 * w0 + s1 * w1;
#pragma unroll
    for (int o = 32; o; o >>= 1) v += __shfl_xor(v, o);
    if (lane == 0) {
        float gg = v + gb2[0];
        g[n] = gg;
        atomicAdd(&gden[batch[n]], expf(gg));
    }
}

__global__ __launch_bounds__(256) void pool_kernel(const float* __restrict__ h,
                                                   const float* __restrict__ g,
                                                   const float* __restrict__ gden,
                                                   const int* __restrict__ batch,
                                                   float* __restrict__ hgraph) {
    int idx = blockIdx.x * 256 + threadIdx.x;
    if (idx >= N_ * D_) return;
    int n = idx >> 8;
    int b = batch[n];
    float w = expf(g[n]) / (gden[b] + 1e-16f);
    atomicAdd(&hgraph[(size_t)b * D_ + (idx & 255)], w * h[idx]);
}

__global__ __launch_bounds__(256) void head_kernel(const float* __restrict__ hgraph,
                                                   const float* __restrict__ hW,
                                                   const float* __restrict__ hb,
                                                   float* __restrict__ out) {
    int gp = blockIdx.x, t = threadIdx.x;
    float v = hgraph[(size_t)gp * D_ + t] * hW[t];
#pragma unroll
    for (int o = 32; o; o >>= 1) v += __shfl_xor(v, o);
    __shared__ float r4[4];
    if ((t & 63) == 0) r4[t >> 6] = v;
    __syncthreads();
    if (t == 0) out[gp] = r4[0] + r4[1] + r4[2] + r4[3] + hb[0];
}

// ---------------- host launch ----------------
extern "C" void kernel_launch(void* const* d_in, const int* in_sizes, int n_in,
                              void* d_out, int out_size, void* d_ws, size_t ws_size,
                              hipStream_t stream) {
    const float* x     = (const float*)d_in[0];
    const int*   eidx  = (const int*)d_in[1];
    const float* eattr = (const float*)d_in[2];
    const int*   batch = (const int*)d_in[3];
    const float* atomW = (const float*)d_in[4];
    const float* atomB = (const float*)d_in[5];
    const float* bondW = (const float*)d_in[6];
    const float* bondB = (const float*)d_in[7];
    const float* Wl    = (const float*)d_in[8];
    const float* bl    = (const float*)d_in[9];
    const float* Wr    = (const float*)d_in[10];
    const float* br    = (const float*)d_in[11];
    const float* We    = (const float*)d_in[12];
    const float* att   = (const float*)d_in[13];
    const float* bias  = (const float*)d_in[14];
    const float* ln1s  = (const float*)d_in[15];
    const float* ln1b  = (const float*)d_in[16];
    const float* eW    = (const float*)d_in[17];
    const float* eb    = (const float*)d_in[18];
    const float* ln2s  = (const float*)d_in[19];
    const float* ln2b  = (const float*)d_in[20];
    const float* jkW   = (const float*)d_in[21];
    const float* jkb   = (const float*)d_in[22];
    const float* ln3s  = (const float*)d_in[23];
    const float* ln3b  = (const float*)d_in[24];
    const float* gW1   = (const float*)d_in[25];
    const float* gb1   = (const float*)d_in[26];
    const float* gW2   = (const float*)d_in[27];
    const float* gb2   = (const float*)d_in[28];
    const float* hW    = (const float*)d_in[29];
    const float* hb    = (const float*)d_in[30];

    const int* src = eidx;
    const int* dst = eidx + E_;

    // ---- workspace layout (~185 MB) ----
    char* wp = (char*)d_ws;
    auto take = [&](size_t bytes) {
        char* p = wp;
        wp += (bytes + 255) & ~(size_t)255;
        return (void*)p;
    };
    _Float16*  e16     = (_Float16*)take((size_t)E_ * ED_ * 2); // 40.96 MB, CSR-permuted
    _Float16*  xl16    = (_Float16*)take((size_t)N_ * D_ * 2);  // 10.24 MB
    _Float16*  xr16    = (_Float16*)take((size_t)N_ * D_ * 2);  // 10.24 MB
    float*     jkacc   = (float*)take((size_t)N_ * D_ * 4);     // 20.48 MB
    float*     loopW   = (float*)take((size_t)N_ * D_ * 4);     // 20.48 MB
    float*     hfin    = (float*)take((size_t)N_ * D_ * 4);     // 20.48 MB
    _Float16*  hfin16  = (_Float16*)take((size_t)N_ * D_ * 2);  // 10.24 MB
    float*     hid     = (float*)take((size_t)N_ * 128 * 4);    // 10.24 MB
    _Float16*  h16A    = (_Float16*)take((size_t)N_ * D_ * 2);  // 10.24 MB
    _Float16*  h16B    = (_Float16*)take((size_t)N_ * D_ * 2);  // 10.24 MB
    _Float16*  hsW16   = (_Float16*)take((size_t)N_ * ED_ * 2); // 2.56 MB
    _Float16*  hdW16   = (_Float16*)take((size_t)N_ * ED_ * 2); // 2.56 MB
    float*     exlog   = (float*)take((size_t)E_ * H_ * 4);     // 5.12 MB
    _Float16*  esum16  = (_Float16*)take((size_t)N_ * ED_ * 2); // 2.56 MB
    _Float16*  wlT16   = (_Float16*)take((size_t)L_ * D_ * D_ * 2);
    _Float16*  wrT16   = (_Float16*)take((size_t)L_ * D_ * D_ * 2);
    _Float16*  weT16   = (_Float16*)take((size_t)L_ * ED_ * D_ * 2);
    _Float16*  ewsT16  = (_Float16*)take((size_t)L_ * D_ * ED_ * 2);
    _Float16*  ewdT16  = (_Float16*)take((size_t)L_ * D_ * ED_ * 2);
    _Float16*  ew3T16  = (_Float16*)take((size_t)L_ * ED_ * ED_ * 2);
    _Float16*  jkwT16  = (_Float16*)take((size_t)L_ * D_ * D_ * 2);
    _Float16*  g1T16   = (_Float16*)take((size_t)D_ * 128 * 2);
    int*   deg_i   = (int*)take((size_t)N_ * 4);
    int*   fill    = (int*)take((size_t)N_ * 4);
    int*   row_off = (int*)take((size_t)(N_ + 1) * 4);
    int*   perm    = (int*)take((size_t)E_ * 4);
    int*   srcp    = (int*)take((size_t)E_ * 4);
    int*   dstp    = (int*)take((size_t)E_ * 4);
    float* g       = (float*)take((size_t)N_ * 4);
    float* gden    = (float*)take((size_t)G_ * 4);
    float* hgraph  = (float*)take((size_t)G_ * D_ * 4);

    // ---- weight pre-pack (f32 -> transposed f16) ----
    auto pack = [&](const float* W, _Float16* WT, int K, int Nn) {
        pack_wT<<<(K * Nn + 255) / 256, 256, 0, stream>>>(W, WT, K, Nn);
    };
    for (int l = 0; l < L_; ++l) {
        pack(Wl + (size_t)l * D_ * D_, wlT16 + (size_t)l * D_ * D_, D_, D_);
        pack(Wr + (size_t)l * D_ * D_, wrT16 + (size_t)l * D_ * D_, D_, D_);
        pack(We + (size_t)l * ED_ * D_, weT16 + (size_t)l * ED_ * D_, ED_, D_);
        const float* eW_l = eW + (size_t)l * (2 * D_ + ED_) * ED_;
        pack(eW_l,                        ewsT16 + (size_t)l * D_ * ED_, D_, ED_);
        pack(eW_l + (size_t)D_ * ED_,     ewdT16 + (size_t)l * D_ * ED_, D_, ED_);
        pack(eW_l + (size_t)2 * D_ * ED_, ew3T16 + (size_t)l * ED_ * ED_, ED_, ED_);
        pack(jkW + (size_t)l * D_ * D_,   jkwT16 + (size_t)l * D_ * D_, D_, D_);
    }
    pack(gW1, g1T16, D_, 128);

    // ---- CSR build ----
    hipMemsetAsync(deg_i, 0, (size_t)N_ * 4, stream);
    hipMemsetAsync(fill, 0, (size_t)N_ * 4, stream);
    count_kernel<<<(E_ + 255) / 256, 256, 0, stream>>>(dst, deg_i);
    scan_kernel<<<1, 1024, 0, stream>>>(deg_i, row_off);
    fill_kernel<<<(E_ + 255) / 256, 256, 0, stream>>>(src, dst, row_off, fill,
                                                      perm, srcp, dstp);

    // encoders
    atom_enc<<<N_, 256, 0, stream>>>(x, atomW, atomB, h16A);
    bond_enc_perm<<<(E_ * ED_ + 255) / 256, 256, 0, stream>>>(eattr, bondW, bondB,
                                                              perm, e16);

    const int MB = (N_ + 63) / 64;  // 313
    const _Float16* h16_prev = h16A;
    for (int l = 0; l < L_; ++l) {
        const float* bl_l = bl + (size_t)l * D_;
        const float* br_l = br + (size_t)l * D_;
        const float* att_l = att + (size_t)l * H_ * C_;
        const float* bias_l = bias + (size_t)l * D_;
        const float* ln1s_l = ln1s + (size_t)l * D_;
        const float* ln1b_l = ln1b + (size_t)l * D_;
        const float* eb_l = eb + (size_t)l * ED_;
        const float* ln2s_l = ln2s + (size_t)l * ED_;
        const float* ln2b_l = ln2b + (size_t)l * ED_;
        const _Float16* weT_l = weT16 + (size_t)l * ED_ * D_;
        _Float16* hn16_l = (l & 1) ? h16A : h16B;

        // xl/xr projections (MFMA, f16 out with bias)
        {
            dim3 grid(MB, D_ / 64);
            mfma_gemm16<<<grid, 256, 0, stream>>>(h16_prev, wlT16 + (size_t)l * D_ * D_,
                                                  bl_l, xl16, N_, D_, D_);
            mfma_gemm16<<<grid, 256, 0, stream>>>(h16_prev, wrT16 + (size_t)l * D_ * D_,
                                                  br_l, xr16, N_, D_, D_);
        }

        // self-loop term: esum16 then esum16@We -> loopW (MFMA, K=64)
        esum_kernel<<<(N_ + 3) / 4, 256, 0, stream>>>(e16, row_off, esum16);
        {
            dim3 grid(MB, D_ / 64);
            mfma_gemm<<<grid, 256, 0, stream>>>(esum16, weT_l, nullptr, loopW,
                                                N_, ED_, D_, 0);
        }

        // phase A: fused MFMA edge logits
        edge_logits_mfma<<<E_ / 64, 256, 0, stream>>>(e16, weT_l, xl16, xr16,
                                                      srcp, dstp, att_l, exlog);

        // phase B: wave-per-dst softmax + aggregation + silu/LN -> hn16
        gat_agg4<<<(N_ + 3) / 4, 256, 0, stream>>>(xl16, xr16, loopW, row_off, srcp,
                                                   exlog, att_l, bias_l,
                                                   ln1s_l, ln1b_l, hn16_l);

        // factored edge MLP: hsW16 = hn@eWs, hdW16 = hn@eWd, e16 <- e16@eW3 (in-place)
        {
            dim3 grid(MB, 1);
            mfma_gemm16<<<grid, 256, 0, stream>>>(hn16_l, ewsT16 + (size_t)l * D_ * ED_,
                                                  nullptr, hsW16, N_, D_, ED_);
            mfma_gemm16<<<grid, 256, 0, stream>>>(hn16_l, ewdT16 + (size_t)l * D_ * ED_,
                                                  nullptr, hdW16, N_, D_, ED_);
        }
        mfma_gemm16<<<dim3(E_ / 64, 1), 256, 0, stream>>>(e16, ew3T16 + (size_t)l * ED_ * ED_,
                                                          nullptr, e16, E_, ED_, ED_);
        edge_mlp_lite<<<E_ / 64, 256, 0, stream>>>(hsW16, hdW16, e16, srcp, dstp,
                                                   eb_l, ln2s_l, ln2b_l);

        // incremental JK: jkacc (+)= hn @ jkW_l (MFMA, f32 accum)
        {
            dim3 grid(MB, D_ / 64);
            mfma_gemm<<<grid, 256, 0, stream>>>(hn16_l, jkwT16 + (size_t)l * D_ * D_,
                                                (l == 0) ? jkb : nullptr,
                                                jkacc, N_, D_, D_, (l == 0) ? 0 : 1);
        }

        h16_prev = hn16_l;
    }

    node_silu_ln<<<N_, 256, 0, stream>>>(jkacc, ln3s, ln3b, hfin, hfin16);

    hipMemsetAsync(gden, 0, (size_t)G_ * 4, stream);
    hipMemsetAsync(hgraph, 0, (size_t)G_ * D_ * 4, stream);
    // gate MLP: hid = hfin16 @ gW1 + gb1 (MFMA), then lite reduce
    mfma_gemm<<<dim3(MB, 2), 256, 0, stream>>>(hfin16, g1T16, gb1, hid, N_, D_, 128, 0);
    gate_lite<<<(N_ + 3) / 4, 256, 0, stream>>>(hid, gW2, gb2, batch, g, gden);
    pool_kernel<<<(N_ * D_ + 255) / 256, 256, 0, stream>>>(hfin, g, gden, batch, hgraph);
    head_kernel<<<G_, 256, 0, stream>>>(hgraph, hW, hb, (float*)d_out);
}

// Round 11
// 1438.806 us; speedup vs baseline: 8.3806x; 1.2419x over previous
//
#include <hip/hip_runtime.h>
#include <hip/hip_bf16.h>

// Problem constants
#define N_ 20000
#define E_ 320000
#define G_ 128
#define H_ 4
#define C_ 64
#define D_ 256
#define ED_ 64
#define L_ 4
#define LROW 72  // padded LDS row stride (f16 units)

typedef _Float16 f16x8 __attribute__((ext_vector_type(8)));
typedef _Float16 f16x4 __attribute__((ext_vector_type(4)));
typedef float f32x4 __attribute__((ext_vector_type(4)));

// ---------------- encoders ----------------
__global__ __launch_bounds__(256) void atom_enc(const float* __restrict__ x,
                                                const float* __restrict__ W,
                                                const float* __restrict__ b,
                                                _Float16* __restrict__ h16) {
    int n = blockIdx.x, t = threadIdx.x;
    float acc = b[t];
#pragma unroll
    for (int k = 0; k < 9; ++k) acc += x[n * 9 + k] * W[k * D_ + t];
    h16[(size_t)n * D_ + t] = (_Float16)acc;
}

__global__ __launch_bounds__(256) void bond_enc_perm(const float* __restrict__ ea,
                                                     const float* __restrict__ W,
                                                     const float* __restrict__ b,
                                                     const int* __restrict__ perm,
                                                     _Float16* __restrict__ e16) {
    int idx = blockIdx.x * 256 + threadIdx.x;
    if (idx >= E_ * ED_) return;
    int pos = idx >> 6, j = idx & 63;
    int orig = perm[pos];
    float acc = b[j];
#pragma unroll
    for (int k = 0; k < 3; ++k) acc += ea[orig * 3 + k] * W[k * ED_ + j];
    e16[idx] = (_Float16)acc;
}

// ---------------- CSR build (dst-sorted) ----------------
__global__ __launch_bounds__(256) void count_kernel(const int* __restrict__ dst,
                                                    int* __restrict__ deg) {
    int e = blockIdx.x * 256 + threadIdx.x;
    if (e >= E_) return;
    atomicAdd(&deg[dst[e]], 1);
}

__global__ __launch_bounds__(1024) void scan_kernel(const int* __restrict__ deg,
                                                    int* __restrict__ row_off) {
    __shared__ int part[1024];
    int t = threadIdx.x;
    const int CH = (N_ + 1023) / 1024;  // 20
    int s = 0;
    for (int i = 0; i < CH; ++i) {
        int idx = t * CH + i;
        if (idx < N_) s += deg[idx];
    }
    part[t] = s;
    __syncthreads();
    for (int off = 1; off < 1024; off <<= 1) {
        int v = (t >= off) ? part[t - off] : 0;
        __syncthreads();
        part[t] += v;
        __syncthreads();
    }
    int base = (t == 0) ? 0 : part[t - 1];
    for (int i = 0; i < CH; ++i) {
        int idx = t * CH + i;
        if (idx < N_) { row_off[idx] = base; base += deg[idx]; }
    }
    if (t == 0) row_off[N_] = part[1023];
}

__global__ __launch_bounds__(256) void fill_kernel(const int* __restrict__ src,
                                                   const int* __restrict__ dst,
                                                   const int* __restrict__ row_off,
                                                   int* __restrict__ fill,
                                                   int* __restrict__ perm,
                                                   int* __restrict__ srcp,
                                                   int* __restrict__ dstp) {
    int e = blockIdx.x * 256 + threadIdx.x;
    if (e >= E_) return;
    int d = dst[e];
    int pos = row_off[d] + atomicAdd(&fill[d], 1);
    perm[pos] = e;
    srcp[pos] = src[e];
    dstp[pos] = d;
}

// graph boundaries via binary search (batch is sorted ascending)
__global__ __launch_bounds__(256) void goff_kernel(const int* __restrict__ batch,
                                                   int* __restrict__ goff) {
    int t = threadIdx.x;
    if (t > G_) return;
    int lo = 0, hi = N_;
    while (lo < hi) { int mid = (lo + hi) >> 1; if (batch[mid] < t) lo = mid + 1; else hi = mid; }
    goff[t] = lo;
}

// ---------------- weight pre-pack: W[K][N] f32 -> WT[N][K] f16 ----------------
__global__ __launch_bounds__(256) void pack_wT(const float* __restrict__ W,
                                               _Float16* __restrict__ WT,
                                               int K, int Nn) {
    int idx = blockIdx.x * 256 + threadIdx.x;
    if (idx >= K * Nn) return;
    int n = idx / K, k = idx - n * K;
    WT[idx] = (_Float16)W[(size_t)k * Nn + n];
}

// ---------------- MFMA f16 GEMM (f32 out, bias, accum) ----------------
__global__ __launch_bounds__(256) void mfma_gemm(const _Float16* __restrict__ A16,
                                                 const _Float16* __restrict__ BT16,
                                                 const float* __restrict__ bias,
                                                 float* __restrict__ C,
                                                 int M, int K, int Nn, int accum) {
    int t = threadIdx.x;
    int w = t >> 6, l = t & 63;
    int bm = blockIdx.x * 64, bn = blockIdx.y * 64;
    int row0 = bm + w * 16 + (l & 15);
    int arow = row0 < M ? row0 : M - 1;
    int koff = (l >> 4) * 8;
    const _Float16* Ap = A16 + (size_t)arow * K + koff;
    f32x4 acc0 = {}, acc1 = {}, acc2 = {}, acc3 = {};
    for (int ks = 0; ks < K; ks += 32) {
        f16x8 a = *(const f16x8*)(Ap + ks);
        const _Float16* Bp = BT16 + (size_t)(bn + (l & 15)) * K + ks + koff;
        f16x8 b0 = *(const f16x8*)(Bp);
        f16x8 b1 = *(const f16x8*)(Bp + (size_t)16 * K);
        f16x8 b2 = *(const f16x8*)(Bp + (size_t)32 * K);
        f16x8 b3 = *(const f16x8*)(Bp + (size_t)48 * K);
        acc0 = __builtin_amdgcn_mfma_f32_16x16x32_f16(a, b0, acc0, 0, 0, 0);
        acc1 = __builtin_amdgcn_mfma_f32_16x16x32_f16(a, b1, acc1, 0, 0, 0);
        acc2 = __builtin_amdgcn_mfma_f32_16x16x32_f16(a, b2, acc2, 0, 0, 0);
        acc3 = __builtin_amdgcn_mfma_f32_16x16x32_f16(a, b3, acc3, 0, 0, 0);
    }
    f32x4 accs[4] = {acc0, acc1, acc2, acc3};
#pragma unroll
    for (int ct = 0; ct < 4; ++ct) {
        int col = bn + ct * 16 + (l & 15);
#pragma unroll
        for (int r = 0; r < 4; ++r) {
            int row = bm + w * 16 + (l >> 4) * 4 + r;
            if (row < M) {
                float v = accs[ct][r] + (bias ? bias[col] : 0.f);
                if (accum) C[(size_t)row * Nn + col] += v;
                else       C[(size_t)row * Nn + col] = v;
            }
        }
    }
}

// ---------------- MFMA f16 GEMM, f16 out, optional bias ----------------
__global__ __launch_bounds__(256) void mfma_gemm16(const _Float16* __restrict__ A16,
                                                   const _Float16* __restrict__ BT16,
                                                   const float* __restrict__ bias,
                                                   _Float16* __restrict__ C16,
                                                   int M, int K, int Nn) {
    int t = threadIdx.x;
    int w = t >> 6, l = t & 63;
    int bm = blockIdx.x * 64, bn = blockIdx.y * 64;
    int row0 = bm + w * 16 + (l & 15);
    int arow = row0 < M ? row0 : M - 1;
    int koff = (l >> 4) * 8;
    const _Float16* Ap = A16 + (size_t)arow * K + koff;
    f32x4 acc0 = {}, acc1 = {}, acc2 = {}, acc3 = {};
    for (int ks = 0; ks < K; ks += 32) {
        f16x8 a = *(const f16x8*)(Ap + ks);
        const _Float16* Bp = BT16 + (size_t)(bn + (l & 15)) * K + ks + koff;
        f16x8 b0 = *(const f16x8*)(Bp);
        f16x8 b1 = *(const f16x8*)(Bp + (size_t)16 * K);
        f16x8 b2 = *(const f16x8*)(Bp + (size_t)32 * K);
        f16x8 b3 = *(const f16x8*)(Bp + (size_t)48 * K);
        acc0 = __builtin_amdgcn_mfma_f32_16x16x32_f16(a, b0, acc0, 0, 0, 0);
        acc1 = __builtin_amdgcn_mfma_f32_16x16x32_f16(a, b1, acc1, 0, 0, 0);
        acc2 = __builtin_amdgcn_mfma_f32_16x16x32_f16(a, b2, acc2, 0, 0, 0);
        acc3 = __builtin_amdgcn_mfma_f32_16x16x32_f16(a, b3, acc3, 0, 0, 0);
    }
    f32x4 accs[4] = {acc0, acc1, acc2, acc3};
#pragma unroll
    for (int ct = 0; ct < 4; ++ct) {
        int col = bn + ct * 16 + (l & 15);
        float bv = bias ? bias[col] : 0.f;
#pragma unroll
        for (int r = 0; r < 4; ++r) {
            int row = bm + w * 16 + (l >> 4) * 4 + r;
            if (row < M) C16[(size_t)row * Nn + col] = (_Float16)(accs[ct][r] + bv);
        }
    }
}

// ---------------- fused MFMA edge logits (xlr packed) ----------------
__global__ __launch_bounds__(256) void edge_logits_mfma(const _Float16* __restrict__ e16,
                                                        const _Float16* __restrict__ weT16,
                                                        const _Float16* __restrict__ xlr16,
                                                        const int* __restrict__ srcp,
                                                        const int* __restrict__ dstp,
                                                        const float* __restrict__ att,
                                                        float* __restrict__ exlog) {
    __shared__ _Float16 es[64 * LROW];
    __shared__ int ssrc[64], sdst[64];
    int t = threadIdx.x;
    int w = t >> 6, l = t & 63;
    int base = blockIdx.x * 64;
    {   // stage full 64x64 tile: thread t copies 16 f16 (two uint4)
        int row = t >> 2, seg = t & 3;
        const _Float16* gp = e16 + (size_t)(base + row) * ED_ + seg * 16;
        uint4 v0 = *(const uint4*)(gp);
        uint4 v1 = *(const uint4*)(gp + 8);
        _Float16* lp = es + row * LROW + seg * 16;
        *(uint4*)(lp) = v0;
        *(uint4*)(lp + 8) = v1;
    }
    if (t < 64) { ssrc[t] = srcp[base + t]; sdst[t] = dstp[base + t]; }
    __syncthreads();
    int koff = (l >> 4) * 8;
    int cgrp = l & 15;
    f16x8 bf[4][2];
#pragma unroll
    for (int nt = 0; nt < 4; ++nt) {
        const _Float16* bp = weT16 + (size_t)(w * 64 + nt * 16 + cgrp) * 64 + koff;
        bf[nt][0] = *(const f16x8*)(bp);
        bf[nt][1] = *(const f16x8*)(bp + 32);
    }
    f32x4 acc[4][4] = {};
#pragma unroll
    for (int mt = 0; mt < 4; ++mt) {
        f16x8 a0 = *(const f16x8*)(es + (mt * 16 + cgrp) * LROW + koff);
        f16x8 a1 = *(const f16x8*)(es + (mt * 16 + cgrp) * LROW + 32 + koff);
#pragma unroll
        for (int nt = 0; nt < 4; ++nt) {
            acc[mt][nt] = __builtin_amdgcn_mfma_f32_16x16x32_f16(a0, bf[nt][0], acc[mt][nt], 0, 0, 0);
            acc[mt][nt] = __builtin_amdgcn_mfma_f32_16x16x32_f16(a1, bf[nt][1], acc[mt][nt], 0, 0, 0);
        }
    }
    float av[4];
#pragma unroll
    for (int nt = 0; nt < 4; ++nt) av[nt] = att[w * 64 + nt * 16 + cgrp];
#pragma unroll
    for (int mt = 0; mt < 4; ++mt) {
#pragma unroll
        for (int r = 0; r < 4; ++r) {
            int eidx = mt * 16 + (l >> 4) * 4 + r;
            int s = ssrc[eidx], d = sdst[eidx];
            float v = 0.f;
#pragma unroll
            for (int nt = 0; nt < 4; ++nt) {
                int col = w * 64 + nt * 16 + cgrp;
                float m = (float)xlr16[(size_t)s * 512 + col]
                        + (float)xlr16[(size_t)d * 512 + 256 + col]
                        + acc[mt][nt][r];
                m = (m > 0.f) ? m : 0.2f * m;
                v += m * av[nt];
            }
            v += __shfl_xor(v, 1); v += __shfl_xor(v, 2);
            v += __shfl_xor(v, 4); v += __shfl_xor(v, 8);
            if (cgrp == 0) exlog[(size_t)(base + eidx) * H_ + w] = expf(v);
        }
    }
}

// ---------------- esum16: per-dst segment sum of e rows ----------------
__global__ __launch_bounds__(256) void esum_kernel(const _Float16* __restrict__ e16,
                                                   const int* __restrict__ row_off,
                                                   _Float16* __restrict__ esum16) {
    int d = blockIdx.x * 4 + (threadIdx.x >> 6);
    int lane = threadIdx.x & 63;
    if (d >= N_) return;
    int beg = row_off[d], end = row_off[d + 1];
    float s = 0.f;
    for (int i = beg; i < end; ++i) s += (float)e16[(size_t)i * ED_ + lane];
    esum16[(size_t)d * ED_ + lane] = (_Float16)s;
}

// ---------------- phase B: wave-per-dst softmax + aggregation + silu/LN ------
__global__ __launch_bounds__(256) void gat_agg4(const _Float16* __restrict__ xlr16,
                                                const _Float16* __restrict__ loopW16,
                                                const int* __restrict__ row_off,
                                                const int* __restrict__ srcp,
                                                const float* __restrict__ exlog,
                                                const float* __restrict__ att,
                                                const float* __restrict__ bias,
                                                const float* __restrict__ gs,
                                                const float* __restrict__ gb,
                                                _Float16* __restrict__ hn16) {
    int t = threadIdx.x;
    int w = t >> 6, lane = t & 63;
    int d = blockIdx.x * 4 + w;
    if (d >= N_) return;
    int beg = row_off[d], end = row_off[d + 1];
    int deg = end - beg;
    int hh = lane >> 4;
    float4 av = *(const float4*)&att[lane * 4];
    f16x4 xld_h = *(const f16x4*)&xlr16[(size_t)d * 512 + lane * 4];
    f16x4 xrd_h = *(const f16x4*)&xlr16[(size_t)d * 512 + 256 + lane * 4];
    float xld[4], xrd[4];
#pragma unroll
    for (int j = 0; j < 4; ++j) { xld[j] = (float)xld_h[j]; xrd[j] = (float)xrd_h[j]; }
    float den = 0.f;
    float out[4] = {0.f, 0.f, 0.f, 0.f};
    int i = beg;
    for (; i + 4 <= end; i += 4) {
        int s0 = srcp[i], s1 = srcp[i + 1], s2 = srcp[i + 2], s3 = srcp[i + 3];
        float ex0 = exlog[(size_t)i * H_ + hh];
        float ex1 = exlog[(size_t)(i + 1) * H_ + hh];
        float ex2 = exlog[(size_t)(i + 2) * H_ + hh];
        float ex3 = exlog[(size_t)(i + 3) * H_ + hh];
        f16x4 x0 = *(const f16x4*)&xlr16[(size_t)s0 * 512 + lane * 4];
        f16x4 x1 = *(const f16x4*)&xlr16[(size_t)s1 * 512 + lane * 4];
        f16x4 x2 = *(const f16x4*)&xlr16[(size_t)s2 * 512 + lane * 4];
        f16x4 x3 = *(const f16x4*)&xlr16[(size_t)s3 * 512 + lane * 4];
        den += (ex0 + ex1) + (ex2 + ex3);
#pragma unroll
        for (int j = 0; j < 4; ++j)
            out[j] += ex0 * (float)x0[j] + ex1 * (float)x1[j] +
                      ex2 * (float)x2[j] + ex3 * (float)x3[j];
    }
    for (; i < end; ++i) {
        int s0 = srcp[i];
        float ex0 = exlog[(size_t)i * H_ + hh];
        f16x4 x0 = *(const f16x4*)&xlr16[(size_t)s0 * 512 + lane * 4];
        den += ex0;
#pragma unroll
        for (int j = 0; j < 4; ++j) out[j] += ex0 * (float)x0[j];
    }
    // self loop
    f16x4 lw4 = *(const f16x4*)&loopW16[(size_t)d * D_ + lane * 4];
    float idg = (deg > 0) ? 1.f / (float)deg : 0.f;
    {
        float v = 0.f;
        float avv[4] = {av.x, av.y, av.z, av.w};
#pragma unroll
        for (int j = 0; j < 4; ++j) {
            float m = xld[j] + xrd[j] + (float)lw4[j] * idg;
            m = (m > 0.f) ? m : 0.2f * m;
            v += m * avv[j];
        }
        v += __shfl_xor(v, 1); v += __shfl_xor(v, 2);
        v += __shfl_xor(v, 4); v += __shfl_xor(v, 8);  // 16-lane head group
        float eself = expf(v);
        den += eself;
#pragma unroll
        for (int j = 0; j < 4; ++j) out[j] += eself * xld[j];
    }
    float inv = 1.f / (den + 1e-16f);
    float4 b4 = *(const float4*)&bias[lane * 4];
    float bv[4] = {b4.x, b4.y, b4.z, b4.w};
    float v4[4], s = 0.f;
#pragma unroll
    for (int j = 0; j < 4; ++j) {
        float v = out[j] * inv + bv[j];
        v = v / (1.f + expf(-v));
        v4[j] = v;
        s += v;
    }
#pragma unroll
    for (int o = 32; o; o >>= 1) s += __shfl_xor(s, o);
    float mu = s * (1.f / 256.f);
    float q = 0.f;
#pragma unroll
    for (int j = 0; j < 4; ++j) { float dv = v4[j] - mu; q += dv * dv; }
#pragma unroll
    for (int o = 32; o; o >>= 1) q += __shfl_xor(q, o);
    float rs = rsqrtf(q * (1.f / 256.f) + 1e-5f);
    float4 g4 = *(const float4*)&gs[lane * 4];
    float4 gb4 = *(const float4*)&gb[lane * 4];
    f16x4 o4;
    float gsv[4] = {g4.x, g4.y, g4.z, g4.w};
    float gbv[4] = {gb4.x, gb4.y, gb4.z, gb4.w};
#pragma unroll
    for (int j = 0; j < 4; ++j) o4[j] = (_Float16)((v4[j] - mu) * rs * gsv[j] + gbv[j]);
    *(f16x4*)&hn16[(size_t)d * D_ + lane * 4] = o4;
}

// ---------------- fused edge MLP: e16 <- LN(silu(e16@eW3 + hsd gathers + eb)) --
// In-place MFMA: wave reads only its own 16 rows, writes after compute.
// Row-LN: for fixed row (fixed l>>4, r), the 64 cols live in the 16 lanes
// sharing l>>4 (cols nt*16+(l&15)) -> shfl_xor 1,2,4,8 reduces the row.
__global__ __launch_bounds__(256) void edge_mlp_mfma(_Float16* __restrict__ e16,
                                                     const _Float16* __restrict__ ew3T16,
                                                     const _Float16* __restrict__ hsd16,
                                                     const int* __restrict__ srcp,
                                                     const int* __restrict__ dstp,
                                                     const float* __restrict__ eb,
                                                     const float* __restrict__ gs,
                                                     const float* __restrict__ gb) {
    int t = threadIdx.x;
    int w = t >> 6, l = t & 63;
    int bm = blockIdx.x * 64;
    int arow = bm + w * 16 + (l & 15);
    int koff = (l >> 4) * 8;
    const _Float16* Ap = e16 + (size_t)arow * ED_ + koff;
    f16x8 a0 = *(const f16x8*)(Ap);
    f16x8 a1 = *(const f16x8*)(Ap + 32);
    f32x4 acc[4];
#pragma unroll
    for (int nt = 0; nt < 4; ++nt) {
        const _Float16* bp = ew3T16 + (size_t)(nt * 16 + (l & 15)) * 64 + koff;
        f16x8 b0 = *(const f16x8*)(bp);
        f16x8 b1 = *(const f16x8*)(bp + 32);
        f32x4 z = {};
        z = __builtin_amdgcn_mfma_f32_16x16x32_f16(a0, b0, z, 0, 0, 0);
        z = __builtin_amdgcn_mfma_f32_16x16x32_f16(a1, b1, z, 0, 0, 0);
        acc[nt] = z;
    }
    int rbase = bm + w * 16 + (l >> 4) * 4;
#pragma unroll
    for (int r = 0; r < 4; ++r) {
        int row = rbase + r;
        int s = srcp[row], d = dstp[row];
        float v4[4], ss = 0.f;
#pragma unroll
        for (int nt = 0; nt < 4; ++nt) {
            int col = nt * 16 + (l & 15);
            float vv = acc[nt][r] + (float)hsd16[(size_t)s * 128 + col]
                     + (float)hsd16[(size_t)d * 128 + 64 + col] + eb[col];
            vv = vv / (1.f + expf(-vv));
            v4[nt] = vv;
            ss += vv;
        }
        ss += __shfl_xor(ss, 1); ss += __shfl_xor(ss, 2);
        ss += __shfl_xor(ss, 4); ss += __shfl_xor(ss, 8);
        float mu = ss * (1.f / 64.f);
        float q = 0.f;
#pragma unroll
        for (int nt = 0; nt < 4; ++nt) { float dv = v4[nt] - mu; q += dv * dv; }
        q += __shfl_xor(q, 1); q += __shfl_xor(q, 2);
        q += __shfl_xor(q, 4); q += __shfl_xor(q, 8);
        float rs = rsqrtf(q * (1.f / 64.f) + 1e-5f);
#pragma unroll
        for (int nt = 0; nt < 4; ++nt) {
            int col = nt * 16 + (l & 15);
            e16[(size_t)row * ED_ + col] = (_Float16)((v4[nt] - mu) * rs * gs[col] + gb[col]);
        }
    }
}

// ---------------- node silu + LN (final JK output; f32 + f16 outs) ----------
__global__ __launch_bounds__(256) void node_silu_ln(const float* __restrict__ inp,
                                                    const float* __restrict__ gs,
                                                    const float* __restrict__ gb,
                                                    float* __restrict__ outp,
                                                    _Float16* __restrict__ outp16) {
    int n = blockIdx.x, t = threadIdx.x;
    float v = inp[(size_t)n * D_ + t];
    v = v / (1.f + expf(-v));
    __shared__ float red[4];
    float s = v;
#pragma unroll
    for (int o = 32; o; o >>= 1) s += __shfl_xor(s, o);
    if ((t & 63) == 0) red[t >> 6] = s;
    __syncthreads();
    float mu = (red[0] + red[1] + red[2] + red[3]) * (1.f / 256.f);
    __syncthreads();
    float dv = v - mu;
    float q = dv * dv;
#pragma unroll
    for (int o = 32; o; o >>= 1) q += __shfl_xor(q, o);
    if ((t & 63) == 0) red[t >> 6] = q;
    __syncthreads();
    float var = (red[0] + red[1] + red[2] + red[3]) * (1.f / 256.f);
    float r = dv * rsqrtf(var + 1e-5f) * gs[t] + gb[t];
    outp[(size_t)n * D_ + t] = r;
    outp16[(size_t)n * D_ + t] = (_Float16)r;
}

// ---------------- gate lite: silu(hid)·gW2 reduce (no atomics) ---------------
__global__ __launch_bounds__(256) void gate_lite(const float* __restrict__ hid,
                                                 const float* __restrict__ gW2,
                                                 const float* __restrict__ gb2,
                                                 float* __restrict__ g) {
    int t = threadIdx.x;
    int w = t >> 6, lane = t & 63;
    int n = blockIdx.x * 4 + w;
    if (n >= N_) return;
    float2 h2 = *(const float2*)&hid[(size_t)n * 128 + lane * 2];
    float w0 = gW2[lane * 2], w1 = gW2[lane * 2 + 1];
    float s0 = h2.x / (1.f + expf(-h2.x));
    float s1 = h2.y / (1.f + expf(-h2.y));
    float v = s0 * w0 + s1 * w1;
#pragma unroll
    for (int o = 32; o; o >>= 1) v += __shfl_xor(v, o);
    if (lane == 0) g[n] = v + gb2[0];
}

// ---------------- fused per-graph pool: denom + weighted sum + head ----------
__global__ __launch_bounds__(256) void graphpool(const float* __restrict__ hfin,
                                                 const float* __restrict__ g,
                                                 const int* __restrict__ goff,
                                                 const float* __restrict__ hW,
                                                 const float* __restrict__ hb,
                                                 float* __restrict__ out) {
    int b = blockIdx.x, t = threadIdx.x;
    int w = t >> 6, lane = t & 63;
    int beg = goff[b], end = goff[b + 1];
    __shared__ float red[4];
    __shared__ float wls[256];
    // pass 1: softmax denominator
    float den = 0.f;
    for (int n = beg + t; n < end; n += 256) den += expf(g[n]);
#pragma unroll
    for (int o = 32; o; o >>= 1) den += __shfl_xor(den, o);
    if (lane == 0) red[w] = den;
    __syncthreads();
    float dtot = red[0] + red[1] + red[2] + red[3];
    float inv = 1.f / (dtot + 1e-16f);
    // pass 2: weighted feature sum (thread t owns col t), chunked via LDS
    float acc = 0.f;
    for (int c0 = beg; c0 < end; c0 += 256) {
        int nn = min(256, end - c0);
        __syncthreads();
        if (t < nn) wls[t] = expf(g[c0 + t]) * inv;
        __syncthreads();
        for (int j = 0; j < nn; ++j)
            acc += wls[j] * hfin[(size_t)(c0 + j) * D_ + t];
    }
    // head: out[b] = sum_c acc_c * hW[c] + hb
    float v = acc * hW[t];
#pragma unroll
    for (int o = 32; o; o >>= 1) v += __shfl_xor(v, o);
    __syncthreads();
    if (lane == 0) red[w] = v;
    __syncthreads();
    if (t == 0) out[b] = red[0] + red[1] + red[2] + red[3] + hb[0];
}

// ---------------- host launch ----------------
extern "C" void kernel_launch(void* const* d_in, const int* in_sizes, int n_in,
                              void* d_out, int out_size, void* d_ws, size_t ws_size,
                              hipStream_t stream) {
    const float* x     = (const float*)d_in[0];
    const int*   eidx  = (const int*)d_in[1];
    const float* eattr = (const float*)d_in[2];
    const int*   batch = (const int*)d_in[3];
    const float* atomW = (const float*)d_in[4];
    const float* atomB = (const float*)d_in[5];
    const float* bondW = (const float*)d_in[6];
    const float* bondB = (const float*)d_in[7];
    const float* Wl    = (const float*)d_in[8];
    const float* bl    = (const float*)d_in[9];
    const float* Wr    = (const float*)d_in[10];
    const float* br    = (const float*)d_in[11];
    const float* We    = (const float*)d_in[12];
    const float* att   = (const float*)d_in[13];
    const float* bias  = (const float*)d_in[14];
    const float* ln1s  = (const float*)d_in[15];
    const float* ln1b  = (const float*)d_in[16];
    const float* eW    = (const float*)d_in[17];
    const float* eb    = (const float*)d_in[18];
    const float* ln2s  = (const float*)d_in[19];
    const float* ln2b  = (const float*)d_in[20];
    const float* jkW   = (const float*)d_in[21];
    const float* jkb   = (const float*)d_in[22];
    const float* ln3s  = (const float*)d_in[23];
    const float* ln3b  = (const float*)d_in[24];
    const float* gW1   = (const float*)d_in[25];
    const float* gb1   = (const float*)d_in[26];
    const float* gW2   = (const float*)d_in[27];
    const float* gb2   = (const float*)d_in[28];
    const float* hW    = (const float*)d_in[29];
    const float* hb    = (const float*)d_in[30];

    const int* src = eidx;
    const int* dst = eidx + E_;

    // ---- workspace layout ----
    char* wp = (char*)d_ws;
    auto take = [&](size_t bytes) {
        char* p = wp;
        wp += (bytes + 255) & ~(size_t)255;
        return (void*)p;
    };
    _Float16*  e16     = (_Float16*)take((size_t)E_ * ED_ * 2);  // 40.96 MB, CSR-permuted
    _Float16*  xlr16   = (_Float16*)take((size_t)N_ * 512 * 2);  // 20.48 MB (xl|xr packed)
    float*     jkacc   = (float*)take((size_t)N_ * D_ * 4);      // 20.48 MB
    _Float16*  loopW16 = (_Float16*)take((size_t)N_ * D_ * 2);   // 10.24 MB
    float*     hfin    = (float*)take((size_t)N_ * D_ * 4);      // 20.48 MB
    _Float16*  hfin16  = (_Float16*)take((size_t)N_ * D_ * 2);   // 10.24 MB
    float*     hid     = (float*)take((size_t)N_ * 128 * 4);     // 10.24 MB
    _Float16*  h16A    = (_Float16*)take((size_t)N_ * D_ * 2);   // 10.24 MB
    _Float16*  h16B    = (_Float16*)take((size_t)N_ * D_ * 2);   // 10.24 MB
    _Float16*  hsd16   = (_Float16*)take((size_t)N_ * 128 * 2);  // 5.12 MB (hsW|hdW packed)
    float*     exlog   = (float*)take((size_t)E_ * H_ * 4);      // 5.12 MB
    _Float16*  esum16  = (_Float16*)take((size_t)N_ * ED_ * 2);  // 2.56 MB
    _Float16*  wlrT16  = (_Float16*)take((size_t)L_ * 512 * D_ * 2);
    _Float16*  weT16   = (_Float16*)take((size_t)L_ * ED_ * D_ * 2);
    _Float16*  ewsdT16 = (_Float16*)take((size_t)L_ * 128 * D_ * 2);
    _Float16*  ew3T16  = (_Float16*)take((size_t)L_ * ED_ * ED_ * 2);
    _Float16*  jkwT16  = (_Float16*)take((size_t)L_ * D_ * D_ * 2);
    _Float16*  g1T16   = (_Float16*)take((size_t)D_ * 128 * 2);
    float*     blr     = (float*)take((size_t)L_ * 512 * 4);
    int*   deg_i   = (int*)take((size_t)N_ * 4);
    int*   fill    = (int*)take((size_t)N_ * 4);
    int*   row_off = (int*)take((size_t)(N_ + 1) * 4);
    int*   goff    = (int*)take((size_t)(G_ + 1) * 4);
    int*   perm    = (int*)take((size_t)E_ * 4);
    int*   srcp    = (int*)take((size_t)E_ * 4);
    int*   dstp    = (int*)take((size_t)E_ * 4);
    float* g       = (float*)take((size_t)N_ * 4);

    // ---- weight pre-pack (f32 -> transposed f16) ----
    auto pack = [&](const float* W, _Float16* WT, int K, int Nn) {
        pack_wT<<<(K * Nn + 255) / 256, 256, 0, stream>>>(W, WT, K, Nn);
    };
    for (int l = 0; l < L_; ++l) {
        // Wl|Wr -> wlrT16 [512][256]
        pack(Wl + (size_t)l * D_ * D_, wlrT16 + (size_t)l * 512 * D_, D_, D_);
        pack(Wr + (size_t)l * D_ * D_, wlrT16 + (size_t)l * 512 * D_ + (size_t)D_ * D_, D_, D_);
        pack(We + (size_t)l * ED_ * D_, weT16 + (size_t)l * ED_ * D_, ED_, D_);
        const float* eW_l = eW + (size_t)l * (2 * D_ + ED_) * ED_;
        // eWs|eWd -> ewsdT16 [128][256]
        pack(eW_l,                        ewsdT16 + (size_t)l * 128 * D_, D_, ED_);
        pack(eW_l + (size_t)D_ * ED_,     ewsdT16 + (size_t)l * 128 * D_ + (size_t)ED_ * D_, D_, ED_);
        pack(eW_l + (size_t)2 * D_ * ED_, ew3T16 + (size_t)l * ED_ * ED_, ED_, ED_);
        pack(jkW + (size_t)l * D_ * D_,   jkwT16 + (size_t)l * D_ * D_, D_, D_);
        // combined bias blr[l] = [bl_l | br_l]
        hipMemcpyAsync(blr + (size_t)l * 512,       bl + (size_t)l * D_, D_ * 4,
                       hipMemcpyDeviceToDevice, stream);
        hipMemcpyAsync(blr + (size_t)l * 512 + D_,  br + (size_t)l * D_, D_ * 4,
                       hipMemcpyDeviceToDevice, stream);
    }
    pack(gW1, g1T16, D_, 128);

    // ---- CSR build + graph boundaries ----
    hipMemsetAsync(deg_i, 0, (size_t)N_ * 4, stream);
    hipMemsetAsync(fill, 0, (size_t)N_ * 4, stream);
    count_kernel<<<(E_ + 255) / 256, 256, 0, stream>>>(dst, deg_i);
    scan_kernel<<<1, 1024, 0, stream>>>(deg_i, row_off);
    fill_kernel<<<(E_ + 255) / 256, 256, 0, stream>>>(src, dst, row_off, fill,
                                                      perm, srcp, dstp);
    goff_kernel<<<1, 256, 0, stream>>>(batch, goff);

    // encoders
    atom_enc<<<N_, 256, 0, stream>>>(x, atomW, atomB, h16A);
    bond_enc_perm<<<(E_ * ED_ + 255) / 256, 256, 0, stream>>>(eattr, bondW, bondB,
                                                              perm, e16);

    const int MB = (N_ + 63) / 64;  // 313
    const _Float16* h16_prev = h16A;
    for (int l = 0; l < L_; ++l) {
        const float* att_l = att + (size_t)l * H_ * C_;
        const float* bias_l = bias + (size_t)l * D_;
        const float* ln1s_l = ln1s + (size_t)l * D_;
        const float* ln1b_l = ln1b + (size_t)l * D_;
        const float* eb_l = eb + (size_t)l * ED_;
        const float* ln2s_l = ln2s + (size_t)l * ED_;
        const float* ln2b_l = ln2b + (size_t)l * ED_;
        const _Float16* weT_l = weT16 + (size_t)l * ED_ * D_;
        _Float16* hn16_l = (l & 1) ? h16A : h16B;

        // xl|xr projection (single MFMA GEMM, N=512, f16 out with combined bias)
        mfma_gemm16<<<dim3(MB, 8), 256, 0, stream>>>(h16_prev,
                                                     wlrT16 + (size_t)l * 512 * D_,
                                                     blr + (size_t)l * 512,
                                                     xlr16, N_, D_, 512);

        // self-loop: esum16 @ We -> loopW16 (f16)
        esum_kernel<<<(N_ + 3) / 4, 256, 0, stream>>>(e16, row_off, esum16);
        mfma_gemm16<<<dim3(MB, 4), 256, 0, stream>>>(esum16, weT_l, nullptr,
                                                     loopW16, N_, ED_, D_);

        // phase A: fused MFMA edge logits
        edge_logits_mfma<<<E_ / 64, 256, 0, stream>>>(e16, weT_l, xlr16,
                                                      srcp, dstp, att_l, exlog);

        // phase B: wave-per-dst softmax + aggregation + silu/LN -> hn16
        gat_agg4<<<(N_ + 3) / 4, 256, 0, stream>>>(xlr16, loopW16, row_off, srcp,
                                                   exlog, att_l, bias_l,
                                                   ln1s_l, ln1b_l, hn16_l);

        // edge MLP: hsd16 = hn@[eWs|eWd] (one GEMM), then fused MFMA+LN in-place
        mfma_gemm16<<<dim3(MB, 2), 256, 0, stream>>>(hn16_l,
                                                     ewsdT16 + (size_t)l * 128 * D_,
                                                     nullptr, hsd16, N_, D_, 128);
        edge_mlp_mfma<<<E_ / 64, 256, 0, stream>>>(e16, ew3T16 + (size_t)l * ED_ * ED_,
                                                   hsd16, srcp, dstp,
                                                   eb_l, ln2s_l, ln2b_l);

        // incremental JK: jkacc (+)= hn @ jkW_l (f32 accum)
        mfma_gemm<<<dim3(MB, 4), 256, 0, stream>>>(hn16_l, jkwT16 + (size_t)l * D_ * D_,
                                                   (l == 0) ? jkb : nullptr,
                                                   jkacc, N_, D_, D_, (l == 0) ? 0 : 1);

        h16_prev = hn16_l;
    }

    node_silu_ln<<<N_, 256, 0, stream>>>(jkacc, ln3s, ln3b, hfin, hfin16);

    // gate MLP (MFMA) -> per-node logit -> fused per-graph pool + head
    mfma_gemm<<<dim3(MB, 2), 256, 0, stream>>>(hfin16, g1T16, gb1, hid, N_, D_, 128, 0);
    gate_lite<<<(N_ + 3) / 4, 256, 0, stream>>>(hid, gW2, gb2, g);
    graphpool<<<G_, 256, 0, stream>>>(hfin, g, goff, hW, hb, (float*)d_out);
}

// Round 12
// 1380.371 us; speedup vs baseline: 8.7354x; 1.0423x over previous
//
#include <hip/hip_runtime.h>
#include <hip/hip_bf16.h>

// Problem constants
#define N_ 20000
#define E_ 320000
#define G_ 128
#define H_ 4
#define C_ 64
#define D_ 256
#define ED_ 64
#define L_ 4

typedef _Float16 f16x8 __attribute__((ext_vector_type(8)));
typedef _Float16 f16x4 __attribute__((ext_vector_type(4)));
typedef float f32x4 __attribute__((ext_vector_type(4)));

// ---------------- encoders ----------------
__global__ __launch_bounds__(256) void atom_enc(const float* __restrict__ x,
                                                const float* __restrict__ W,
                                                const float* __restrict__ b,
                                                _Float16* __restrict__ h16) {
    int n = blockIdx.x, t = threadIdx.x;
    float acc = b[t];
#pragma unroll
    for (int k = 0; k < 9; ++k) acc += x[n * 9 + k] * W[k * D_ + t];
    h16[(size_t)n * D_ + t] = (_Float16)acc;
}

__global__ __launch_bounds__(256) void bond_enc_perm(const float* __restrict__ ea,
                                                     const float* __restrict__ W,
                                                     const float* __restrict__ b,
                                                     const int* __restrict__ perm,
                                                     _Float16* __restrict__ e16) {
    int idx = blockIdx.x * 256 + threadIdx.x;
    if (idx >= E_ * ED_) return;
    int pos = idx >> 6, j = idx & 63;
    int orig = perm[pos];
    float acc = b[j];
#pragma unroll
    for (int k = 0; k < 3; ++k) acc += ea[orig * 3 + k] * W[k * ED_ + j];
    e16[idx] = (_Float16)acc;
}

// ---------------- CSR build (dst-sorted) ----------------
__global__ __launch_bounds__(256) void count_kernel(const int* __restrict__ dst,
                                                    int* __restrict__ deg) {
    int e = blockIdx.x * 256 + threadIdx.x;
    if (e >= E_) return;
    atomicAdd(&deg[dst[e]], 1);
}

__global__ __launch_bounds__(1024) void scan_kernel(const int* __restrict__ deg,
                                                    int* __restrict__ row_off) {
    __shared__ int part[1024];
    int t = threadIdx.x;
    const int CH = (N_ + 1023) / 1024;  // 20
    int s = 0;
    for (int i = 0; i < CH; ++i) {
        int idx = t * CH + i;
        if (idx < N_) s += deg[idx];
    }
    part[t] = s;
    __syncthreads();
    for (int off = 1; off < 1024; off <<= 1) {
        int v = (t >= off) ? part[t - off] : 0;
        __syncthreads();
        part[t] += v;
        __syncthreads();
    }
    int base = (t == 0) ? 0 : part[t - 1];
    for (int i = 0; i < CH; ++i) {
        int idx = t * CH + i;
        if (idx < N_) { row_off[idx] = base; base += deg[idx]; }
    }
    if (t == 0) row_off[N_] = part[1023];
}

__global__ __launch_bounds__(256) void fill_kernel(const int* __restrict__ src,
                                                   const int* __restrict__ dst,
                                                   const int* __restrict__ row_off,
                                                   int* __restrict__ fill,
                                                   int* __restrict__ perm,
                                                   int* __restrict__ srcp,
                                                   int* __restrict__ dstp) {
    int e = blockIdx.x * 256 + threadIdx.x;
    if (e >= E_) return;
    int d = dst[e];
    int pos = row_off[d] + atomicAdd(&fill[d], 1);
    perm[pos] = e;
    srcp[pos] = src[e];
    dstp[pos] = d;
}

// graph boundaries via binary search (batch is sorted ascending)
__global__ __launch_bounds__(256) void goff_kernel(const int* __restrict__ batch,
                                                   int* __restrict__ goff) {
    int t = threadIdx.x;
    if (t > G_) return;
    int lo = 0, hi = N_;
    while (lo < hi) { int mid = (lo + hi) >> 1; if (batch[mid] < t) lo = mid + 1; else hi = mid; }
    goff[t] = lo;
}

// ---------------- weight pre-pack: W[K][N] f32 -> WT[N][K] f16 ----------------
__global__ __launch_bounds__(256) void pack_wT(const float* __restrict__ W,
                                               _Float16* __restrict__ WT,
                                               int K, int Nn) {
    int idx = blockIdx.x * 256 + threadIdx.x;
    if (idx >= K * Nn) return;
    int n = idx / K, k = idx - n * K;
    WT[idx] = (_Float16)W[(size_t)k * Nn + n];
}

// permuted pack for edge_logits: fragment slot q = hw*64 + nt*16 + cgrp holds
// actual col n = hw*64 + cgrp*4 + nt  (K=64, Nn=256 fixed)
__global__ __launch_bounds__(256) void pack_wT_perm(const float* __restrict__ W,
                                                    _Float16* __restrict__ WTp) {
    int idx = blockIdx.x * 256 + threadIdx.x;
    if (idx >= 64 * 256) return;
    int q = idx >> 6, k = idx & 63;
    int hw = q >> 6, qq = q & 63;
    int nt = qq >> 4, cgrp = qq & 15;
    int n = hw * 64 + cgrp * 4 + nt;
    WTp[idx] = (_Float16)W[(size_t)k * 256 + n];
}

// ---------------- MFMA f16 GEMM (f32 out, bias, accum) ----------------
__global__ __launch_bounds__(256) void mfma_gemm(const _Float16* __restrict__ A16,
                                                 const _Float16* __restrict__ BT16,
                                                 const float* __restrict__ bias,
                                                 float* __restrict__ C,
                                                 int M, int K, int Nn, int accum) {
    int t = threadIdx.x;
    int w = t >> 6, l = t & 63;
    int bm = blockIdx.x * 64, bn = blockIdx.y * 64;
    int row0 = bm + w * 16 + (l & 15);
    int arow = row0 < M ? row0 : M - 1;
    int koff = (l >> 4) * 8;
    const _Float16* Ap = A16 + (size_t)arow * K + koff;
    f32x4 acc0 = {}, acc1 = {}, acc2 = {}, acc3 = {};
    for (int ks = 0; ks < K; ks += 32) {
        f16x8 a = *(const f16x8*)(Ap + ks);
        const _Float16* Bp = BT16 + (size_t)(bn + (l & 15)) * K + ks + koff;
        f16x8 b0 = *(const f16x8*)(Bp);
        f16x8 b1 = *(const f16x8*)(Bp + (size_t)16 * K);
        f16x8 b2 = *(const f16x8*)(Bp + (size_t)32 * K);
        f16x8 b3 = *(const f16x8*)(Bp + (size_t)48 * K);
        acc0 = __builtin_amdgcn_mfma_f32_16x16x32_f16(a, b0, acc0, 0, 0, 0);
        acc1 = __builtin_amdgcn_mfma_f32_16x16x32_f16(a, b1, acc1, 0, 0, 0);
        acc2 = __builtin_amdgcn_mfma_f32_16x16x32_f16(a, b2, acc2, 0, 0, 0);
        acc3 = __builtin_amdgcn_mfma_f32_16x16x32_f16(a, b3, acc3, 0, 0, 0);
    }
    f32x4 accs[4] = {acc0, acc1, acc2, acc3};
#pragma unroll
    for (int ct = 0; ct < 4; ++ct) {
        int col = bn + ct * 16 + (l & 15);
#pragma unroll
        for (int r = 0; r < 4; ++r) {
            int row = bm + w * 16 + (l >> 4) * 4 + r;
            if (row < M) {
                float v = accs[ct][r] + (bias ? bias[col] : 0.f);
                if (accum) C[(size_t)row * Nn + col] += v;
                else       C[(size_t)row * Nn + col] = v;
            }
        }
    }
}

// ---------------- MFMA f16 GEMM, f16 out, optional bias ----------------
__global__ __launch_bounds__(256) void mfma_gemm16(const _Float16* __restrict__ A16,
                                                   const _Float16* __restrict__ BT16,
                                                   const float* __restrict__ bias,
                                                   _Float16* __restrict__ C16,
                                                   int M, int K, int Nn) {
    int t = threadIdx.x;
    int w = t >> 6, l = t & 63;
    int bm = blockIdx.x * 64, bn = blockIdx.y * 64;
    int row0 = bm + w * 16 + (l & 15);
    int arow = row0 < M ? row0 : M - 1;
    int koff = (l >> 4) * 8;
    const _Float16* Ap = A16 + (size_t)arow * K + koff;
    f32x4 acc0 = {}, acc1 = {}, acc2 = {}, acc3 = {};
    for (int ks = 0; ks < K; ks += 32) {
        f16x8 a = *(const f16x8*)(Ap + ks);
        const _Float16* Bp = BT16 + (size_t)(bn + (l & 15)) * K + ks + koff;
        f16x8 b0 = *(const f16x8*)(Bp);
        f16x8 b1 = *(const f16x8*)(Bp + (size_t)16 * K);
        f16x8 b2 = *(const f16x8*)(Bp + (size_t)32 * K);
        f16x8 b3 = *(const f16x8*)(Bp + (size_t)48 * K);
        acc0 = __builtin_amdgcn_mfma_f32_16x16x32_f16(a, b0, acc0, 0, 0, 0);
        acc1 = __builtin_amdgcn_mfma_f32_16x16x32_f16(a, b1, acc1, 0, 0, 0);
        acc2 = __builtin_amdgcn_mfma_f32_16x16x32_f16(a, b2, acc2, 0, 0, 0);
        acc3 = __builtin_amdgcn_mfma_f32_16x16x32_f16(a, b3, acc3, 0, 0, 0);
    }
    f32x4 accs[4] = {acc0, acc1, acc2, acc3};
#pragma unroll
    for (int ct = 0; ct < 4; ++ct) {
        int col = bn + ct * 16 + (l & 15);
        float bv = bias ? bias[col] : 0.f;
#pragma unroll
        for (int r = 0; r < 4; ++r) {
            int row = bm + w * 16 + (l >> 4) * 4 + r;
            if (row < M) C16[(size_t)row * Nn + col] = (_Float16)(accs[ct][r] + bv);
        }
    }
}

// ---------------- fused MFMA edge logits (no LDS tile, vectorized gathers) ----
// A-fragments read direct from global e16 (wave pattern = 16 rows x 128 B,
// coalesced; 4 waves share the tile via L1). B from PERMUTED weTp so lane's
// 4 acc columns are contiguous: col = w*64 + cgrp*4 + nt  => xl/xr epilogue
// gathers are single f16x4 loads; att is one float4.
__global__ __launch_bounds__(256) void edge_logits_mfma(const _Float16* __restrict__ e16,
                                                        const _Float16* __restrict__ weTp16,
                                                        const _Float16* __restrict__ xlr16,
                                                        const int* __restrict__ srcp,
                                                        const int* __restrict__ dstp,
                                                        const float* __restrict__ att,
                                                        float* __restrict__ exlog) {
    __shared__ int ssrc[64], sdst[64];
    int t = threadIdx.x;
    int w = t >> 6, l = t & 63;
    int base = blockIdx.x * 64;
    if (t < 64) { ssrc[t] = srcp[base + t]; sdst[t] = dstp[base + t]; }
    int koff = (l >> 4) * 8;
    int cgrp = l & 15;
    // B fragments (permuted)
    f16x8 bf[4][2];
#pragma unroll
    for (int nt = 0; nt < 4; ++nt) {
        const _Float16* bp = weTp16 + (size_t)(w * 64 + nt * 16 + cgrp) * 64 + koff;
        bf[nt][0] = *(const f16x8*)(bp);
        bf[nt][1] = *(const f16x8*)(bp + 32);
    }
    float4 av4 = *(const float4*)&att[w * 64 + cgrp * 4];
    float av[4] = {av4.x, av4.y, av4.z, av4.w};
    __syncthreads();
#pragma unroll
    for (int mt = 0; mt < 4; ++mt) {
        const _Float16* ap = e16 + (size_t)(base + mt * 16 + cgrp) * ED_ + koff;
        f16x8 a0 = *(const f16x8*)(ap);
        f16x8 a1 = *(const f16x8*)(ap + 32);
        f32x4 acc[4];
#pragma unroll
        for (int nt = 0; nt < 4; ++nt) {
            f32x4 z = {};
            z = __builtin_amdgcn_mfma_f32_16x16x32_f16(a0, bf[nt][0], z, 0, 0, 0);
            z = __builtin_amdgcn_mfma_f32_16x16x32_f16(a1, bf[nt][1], z, 0, 0, 0);
            acc[nt] = z;
        }
#pragma unroll
        for (int r = 0; r < 4; ++r) {
            int eidx = mt * 16 + (l >> 4) * 4 + r;
            int s = ssrc[eidx], d = sdst[eidx];
            f16x4 xlv = *(const f16x4*)&xlr16[(size_t)s * 512 + w * 64 + cgrp * 4];
            f16x4 xrv = *(const f16x4*)&xlr16[(size_t)d * 512 + 256 + w * 64 + cgrp * 4];
            float v = 0.f;
#pragma unroll
            for (int j = 0; j < 4; ++j) {
                float m = (float)xlv[j] + (float)xrv[j] + acc[j][r];
                m = (m > 0.f) ? m : 0.2f * m;
                v += m * av[j];
            }
            v += __shfl_xor(v, 1); v += __shfl_xor(v, 2);
            v += __shfl_xor(v, 4); v += __shfl_xor(v, 8);
            if (cgrp == 0) exlog[(size_t)(base + eidx) * H_ + w] = expf(v);
        }
    }
}

// ---------------- esum16: per-dst segment sum of e rows ----------------
__global__ __launch_bounds__(256) void esum_kernel(const _Float16* __restrict__ e16,
                                                   const int* __restrict__ row_off,
                                                   _Float16* __restrict__ esum16) {
    int d = blockIdx.x * 4 + (threadIdx.x >> 6);
    int lane = threadIdx.x & 63;
    if (d >= N_) return;
    int beg = row_off[d], end = row_off[d + 1];
    float s = 0.f;
    for (int i = beg; i < end; ++i) s += (float)e16[(size_t)i * ED_ + lane];
    esum16[(size_t)d * ED_ + lane] = (_Float16)s;
}

// ---------------- phase B: wave-per-dst softmax + aggregation + silu/LN ------
__global__ __launch_bounds__(256) void gat_agg4(const _Float16* __restrict__ xlr16,
                                                const _Float16* __restrict__ loopW16,
                                                const int* __restrict__ row_off,
                                                const int* __restrict__ srcp,
                                                const float* __restrict__ exlog,
                                                const float* __restrict__ att,
                                                const float* __restrict__ bias,
                                                const float* __restrict__ gs,
                                                const float* __restrict__ gb,
                                                _Float16* __restrict__ hn16) {
    int t = threadIdx.x;
    int w = t >> 6, lane = t & 63;
    int d = blockIdx.x * 4 + w;
    if (d >= N_) return;
    int beg = row_off[d], end = row_off[d + 1];
    int deg = end - beg;
    int hh = lane >> 4;
    float4 av = *(const float4*)&att[lane * 4];
    f16x4 xld_h = *(const f16x4*)&xlr16[(size_t)d * 512 + lane * 4];
    f16x4 xrd_h = *(const f16x4*)&xlr16[(size_t)d * 512 + 256 + lane * 4];
    float xld[4], xrd[4];
#pragma unroll
    for (int j = 0; j < 4; ++j) { xld[j] = (float)xld_h[j]; xrd[j] = (float)xrd_h[j]; }
    float den = 0.f;
    float out[4] = {0.f, 0.f, 0.f, 0.f};
    int i = beg;
    for (; i + 4 <= end; i += 4) {
        int s0 = srcp[i], s1 = srcp[i + 1], s2 = srcp[i + 2], s3 = srcp[i + 3];
        float ex0 = exlog[(size_t)i * H_ + hh];
        float ex1 = exlog[(size_t)(i + 1) * H_ + hh];
        float ex2 = exlog[(size_t)(i + 2) * H_ + hh];
        float ex3 = exlog[(size_t)(i + 3) * H_ + hh];
        f16x4 x0 = *(const f16x4*)&xlr16[(size_t)s0 * 512 + lane * 4];
        f16x4 x1 = *(const f16x4*)&xlr16[(size_t)s1 * 512 + lane * 4];
        f16x4 x2 = *(const f16x4*)&xlr16[(size_t)s2 * 512 + lane * 4];
        f16x4 x3 = *(const f16x4*)&xlr16[(size_t)s3 * 512 + lane * 4];
        den += (ex0 + ex1) + (ex2 + ex3);
#pragma unroll
        for (int j = 0; j < 4; ++j)
            out[j] += ex0 * (float)x0[j] + ex1 * (float)x1[j] +
                      ex2 * (float)x2[j] + ex3 * (float)x3[j];
    }
    for (; i < end; ++i) {
        int s0 = srcp[i];
        float ex0 = exlog[(size_t)i * H_ + hh];
        f16x4 x0 = *(const f16x4*)&xlr16[(size_t)s0 * 512 + lane * 4];
        den += ex0;
#pragma unroll
        for (int j = 0; j < 4; ++j) out[j] += ex0 * (float)x0[j];
    }
    // self loop
    f16x4 lw4 = *(const f16x4*)&loopW16[(size_t)d * D_ + lane * 4];
    float idg = (deg > 0) ? 1.f / (float)deg : 0.f;
    {
        float v = 0.f;
        float avv[4] = {av.x, av.y, av.z, av.w};
#pragma unroll
        for (int j = 0; j < 4; ++j) {
            float m = xld[j] + xrd[j] + (float)lw4[j] * idg;
            m = (m > 0.f) ? m : 0.2f * m;
            v += m * avv[j];
        }
        v += __shfl_xor(v, 1); v += __shfl_xor(v, 2);
        v += __shfl_xor(v, 4); v += __shfl_xor(v, 8);  // 16-lane head group
        float eself = expf(v);
        den += eself;
#pragma unroll
        for (int j = 0; j < 4; ++j) out[j] += eself * xld[j];
    }
    float inv = 1.f / (den + 1e-16f);
    float4 b4 = *(const float4*)&bias[lane * 4];
    float bv[4] = {b4.x, b4.y, b4.z, b4.w};
    float v4[4], s = 0.f;
#pragma unroll
    for (int j = 0; j < 4; ++j) {
        float v = out[j] * inv + bv[j];
        v = v / (1.f + expf(-v));
        v4[j] = v;
        s += v;
    }
#pragma unroll
    for (int o = 32; o; o >>= 1) s += __shfl_xor(s, o);
    float mu = s * (1.f / 256.f);
    float q = 0.f;
#pragma unroll
    for (int j = 0; j < 4; ++j) { float dv = v4[j] - mu; q += dv * dv; }
#pragma unroll
    for (int o = 32; o; o >>= 1) q += __shfl_xor(q, o);
    float rs = rsqrtf(q * (1.f / 256.f) + 1e-5f);
    float4 g4 = *(const float4*)&gs[lane * 4];
    float4 gb4 = *(const float4*)&gb[lane * 4];
    f16x4 o4;
    float gsv[4] = {g4.x, g4.y, g4.z, g4.w};
    float gbv[4] = {gb4.x, gb4.y, gb4.z, gb4.w};
#pragma unroll
    for (int j = 0; j < 4; ++j) o4[j] = (_Float16)((v4[j] - mu) * rs * gsv[j] + gbv[j]);
    *(f16x4*)&hn16[(size_t)d * D_ + lane * 4] = o4;
}

// ---------------- fused edge MLP: e16 <- LN(silu(e16@eW3 + hsd gathers + eb)) --
__global__ __launch_bounds__(256) void edge_mlp_mfma(_Float16* __restrict__ e16,
                                                     const _Float16* __restrict__ ew3T16,
                                                     const _Float16* __restrict__ hsd16,
                                                     const int* __restrict__ srcp,
                                                     const int* __restrict__ dstp,
                                                     const float* __restrict__ eb,
                                                     const float* __restrict__ gs,
                                                     const float* __restrict__ gb) {
    int t = threadIdx.x;
    int w = t >> 6, l = t & 63;
    int bm = blockIdx.x * 64;
    int arow = bm + w * 16 + (l & 15);
    int koff = (l >> 4) * 8;
    const _Float16* Ap = e16 + (size_t)arow * ED_ + koff;
    f16x8 a0 = *(const f16x8*)(Ap);
    f16x8 a1 = *(const f16x8*)(Ap + 32);
    f32x4 acc[4];
#pragma unroll
    for (int nt = 0; nt < 4; ++nt) {
        const _Float16* bp = ew3T16 + (size_t)(nt * 16 + (l & 15)) * 64 + koff;
        f16x8 b0 = *(const f16x8*)(bp);
        f16x8 b1 = *(const f16x8*)(bp + 32);
        f32x4 z = {};
        z = __builtin_amdgcn_mfma_f32_16x16x32_f16(a0, b0, z, 0, 0, 0);
        z = __builtin_amdgcn_mfma_f32_16x16x32_f16(a1, b1, z, 0, 0, 0);
        acc[nt] = z;
    }
    int rbase = bm + w * 16 + (l >> 4) * 4;
#pragma unroll
    for (int r = 0; r < 4; ++r) {
        int row = rbase + r;
        int s = srcp[row], d = dstp[row];
        float v4[4], ss = 0.f;
#pragma unroll
        for (int nt = 0; nt < 4; ++nt) {
            int col = nt * 16 + (l & 15);
            float vv = acc[nt][r] + (float)hsd16[(size_t)s * 128 + col]
                     + (float)hsd16[(size_t)d * 128 + 64 + col] + eb[col];
            vv = vv / (1.f + expf(-vv));
            v4[nt] = vv;
            ss += vv;
        }
        ss += __shfl_xor(ss, 1); ss += __shfl_xor(ss, 2);
        ss += __shfl_xor(ss, 4); ss += __shfl_xor(ss, 8);
        float mu = ss * (1.f / 64.f);
        float q = 0.f;
#pragma unroll
        for (int nt = 0; nt < 4; ++nt) { float dv = v4[nt] - mu; q += dv * dv; }
        q += __shfl_xor(q, 1); q += __shfl_xor(q, 2);
        q += __shfl_xor(q, 4); q += __shfl_xor(q, 8);
        float rs = rsqrtf(q * (1.f / 64.f) + 1e-5f);
#pragma unroll
        for (int nt = 0; nt < 4; ++nt) {
            int col = nt * 16 + (l & 15);
            e16[(size_t)row * ED_ + col] = (_Float16)((v4[nt] - mu) * rs * gs[col] + gb[col]);
        }
    }
}

// ---------------- node silu + LN (final JK output; f32 + f16 outs) ----------
__global__ __launch_bounds__(256) void node_silu_ln(const float* __restrict__ inp,
                                                    const float* __restrict__ gs,
                                                    const float* __restrict__ gb,
                                                    float* __restrict__ outp,
                                                    _Float16* __restrict__ outp16) {
    int n = blockIdx.x, t = threadIdx.x;
    float v = inp[(size_t)n * D_ + t];
    v = v / (1.f + expf(-v));
    __shared__ float red[4];
    float s = v;
#pragma unroll
    for (int o = 32; o; o >>= 1) s += __shfl_xor(s, o);
    if ((t & 63) == 0) red[t >> 6] = s;
    __syncthreads();
    float mu = (red[0] + red[1] + red[2] + red[3]) * (1.f / 256.f);
    __syncthreads();
    float dv = v - mu;
    float q = dv * dv;
#pragma unroll
    for (int o = 32; o; o >>= 1) q += __shfl_xor(q, o);
    if ((t & 63) == 0) red[t >> 6] = q;
    __syncthreads();
    float var = (red[0] + red[1] + red[2] + red[3]) * (1.f / 256.f);
    float r = dv * rsqrtf(var + 1e-5f) * gs[t] + gb[t];
    outp[(size_t)n * D_ + t] = r;
    outp16[(size_t)n * D_ + t] = (_Float16)r;
}

// ---------------- gate lite: silu(hid)·gW2 reduce (no atomics) ---------------
__global__ __launch_bounds__(256) void gate_lite(const float* __restrict__ hid,
                                                 const float* __restrict__ gW2,
                                                 const float* __restrict__ gb2,
                                                 float* __restrict__ g) {
    int t = threadIdx.x;
    int w = t >> 6, lane = t & 63;
    int n = blockIdx.x * 4 + w;
    if (n >= N_) return;
    float2 h2 = *(const float2*)&hid[(size_t)n * 128 + lane * 2];
    float w0 = gW2[lane * 2], w1 = gW2[lane * 2 + 1];
    float s0 = h2.x / (1.f + expf(-h2.x));
    float s1 = h2.y / (1.f + expf(-h2.y));
    float v = s0 * w0 + s1 * w1;
#pragma unroll
    for (int o = 32; o; o >>= 1) v += __shfl_xor(v, o);
    if (lane == 0) g[n] = v + gb2[0];
}

// ---------------- fused per-graph pool: denom + weighted sum + head ----------
__global__ __launch_bounds__(256) void graphpool(const float* __restrict__ hfin,
                                                 const float* __restrict__ g,
                                                 const int* __restrict__ goff,
                                                 const float* __restrict__ hW,
                                                 const float* __restrict__ hb,
                                                 float* __restrict__ out) {
    int b = blockIdx.x, t = threadIdx.x;
    int w = t >> 6, lane = t & 63;
    int beg = goff[b], end = goff[b + 1];
    __shared__ float red[4];
    __shared__ float wls[256];
    float den = 0.f;
    for (int n = beg + t; n < end; n += 256) den += expf(g[n]);
#pragma unroll
    for (int o = 32; o; o >>= 1) den += __shfl_xor(den, o);
    if (lane == 0) red[w] = den;
    __syncthreads();
    float dtot = red[0] + red[1] + red[2] + red[3];
    float inv = 1.f / (dtot + 1e-16f);
    float acc = 0.f;
    for (int c0 = beg; c0 < end; c0 += 256) {
        int nn = min(256, end - c0);
        __syncthreads();
        if (t < nn) wls[t] = expf(g[c0 + t]) * inv;
        __syncthreads();
        for (int j = 0; j < nn; ++j)
            acc += wls[j] * hfin[(size_t)(c0 + j) * D_ + t];
    }
    float v = acc * hW[t];
#pragma unroll
    for (int o = 32; o; o >>= 1) v += __shfl_xor(v, o);
    __syncthreads();
    if (lane == 0) red[w] = v;
    __syncthreads();
    if (t == 0) out[b] = red[0] + red[1] + red[2] + red[3] + hb[0];
}

// ---------------- host launch ----------------
extern "C" void kernel_launch(void* const* d_in, const int* in_sizes, int n_in,
                              void* d_out, int out_size, void* d_ws, size_t ws_size,
                              hipStream_t stream) {
    const float* x     = (const float*)d_in[0];
    const int*   eidx  = (const int*)d_in[1];
    const float* eattr = (const float*)d_in[2];
    const int*   batch = (const int*)d_in[3];
    const float* atomW = (const float*)d_in[4];
    const float* atomB = (const float*)d_in[5];
    const float* bondW = (const float*)d_in[6];
    const float* bondB = (const float*)d_in[7];
    const float* Wl    = (const float*)d_in[8];
    const float* bl    = (const float*)d_in[9];
    const float* Wr    = (const float*)d_in[10];
    const float* br    = (const float*)d_in[11];
    const float* We    = (const float*)d_in[12];
    const float* att   = (const float*)d_in[13];
    const float* bias  = (const float*)d_in[14];
    const float* ln1s  = (const float*)d_in[15];
    const float* ln1b  = (const float*)d_in[16];
    const float* eW    = (const float*)d_in[17];
    const float* eb    = (const float*)d_in[18];
    const float* ln2s  = (const float*)d_in[19];
    const float* ln2b  = (const float*)d_in[20];
    const float* jkW   = (const float*)d_in[21];
    const float* jkb   = (const float*)d_in[22];
    const float* ln3s  = (const float*)d_in[23];
    const float* ln3b  = (const float*)d_in[24];
    const float* gW1   = (const float*)d_in[25];
    const float* gb1   = (const float*)d_in[26];
    const float* gW2   = (const float*)d_in[27];
    const float* gb2   = (const float*)d_in[28];
    const float* hW    = (const float*)d_in[29];
    const float* hb    = (const float*)d_in[30];

    const int* src = eidx;
    const int* dst = eidx + E_;

    // ---- workspace layout ----
    char* wp = (char*)d_ws;
    auto take = [&](size_t bytes) {
        char* p = wp;
        wp += (bytes + 255) & ~(size_t)255;
        return (void*)p;
    };
    _Float16*  e16     = (_Float16*)take((size_t)E_ * ED_ * 2);  // 40.96 MB, CSR-permuted
    _Float16*  xlr16   = (_Float16*)take((size_t)N_ * 512 * 2);  // 20.48 MB (xl|xr packed)
    float*     jkacc   = (float*)take((size_t)N_ * D_ * 4);      // 20.48 MB
    _Float16*  loopW16 = (_Float16*)take((size_t)N_ * D_ * 2);   // 10.24 MB
    float*     hfin    = (float*)take((size_t)N_ * D_ * 4);      // 20.48 MB
    _Float16*  hfin16  = (_Float16*)take((size_t)N_ * D_ * 2);   // 10.24 MB
    float*     hid     = (float*)take((size_t)N_ * 128 * 4);     // 10.24 MB
    _Float16*  h16A    = (_Float16*)take((size_t)N_ * D_ * 2);   // 10.24 MB
    _Float16*  h16B    = (_Float16*)take((size_t)N_ * D_ * 2);   // 10.24 MB
    _Float16*  hsd16   = (_Float16*)take((size_t)N_ * 128 * 2);  // 5.12 MB (hsW|hdW packed)
    float*     exlog   = (float*)take((size_t)E_ * H_ * 4);      // 5.12 MB
    _Float16*  esum16  = (_Float16*)take((size_t)N_ * ED_ * 2);  // 2.56 MB
    _Float16*  wlrT16  = (_Float16*)take((size_t)L_ * 512 * D_ * 2);
    _Float16*  weT16   = (_Float16*)take((size_t)L_ * ED_ * D_ * 2);
    _Float16*  weTp16  = (_Float16*)take((size_t)L_ * ED_ * D_ * 2);  // permuted for edge_logits
    _Float16*  ewsdT16 = (_Float16*)take((size_t)L_ * 128 * D_ * 2);
    _Float16*  ew3T16  = (_Float16*)take((size_t)L_ * ED_ * ED_ * 2);
    _Float16*  jkwT16  = (_Float16*)take((size_t)L_ * D_ * D_ * 2);
    _Float16*  g1T16   = (_Float16*)take((size_t)D_ * 128 * 2);
    float*     blr     = (float*)take((size_t)L_ * 512 * 4);
    int*   deg_i   = (int*)take((size_t)N_ * 4);
    int*   fill    = (int*)take((size_t)N_ * 4);
    int*   row_off = (int*)take((size_t)(N_ + 1) * 4);
    int*   goff    = (int*)take((size_t)(G_ + 1) * 4);
    int*   perm    = (int*)take((size_t)E_ * 4);
    int*   srcp    = (int*)take((size_t)E_ * 4);
    int*   dstp    = (int*)take((size_t)E_ * 4);
    float* g       = (float*)take((size_t)N_ * 4);

    // ---- weight pre-pack (f32 -> transposed f16) ----
    auto pack = [&](const float* W, _Float16* WT, int K, int Nn) {
        pack_wT<<<(K * Nn + 255) / 256, 256, 0, stream>>>(W, WT, K, Nn);
    };
    for (int l = 0; l < L_; ++l) {
        pack(Wl + (size_t)l * D_ * D_, wlrT16 + (size_t)l * 512 * D_, D_, D_);
        pack(Wr + (size_t)l * D_ * D_, wlrT16 + (size_t)l * 512 * D_ + (size_t)D_ * D_, D_, D_);
        pack(We + (size_t)l * ED_ * D_, weT16 + (size_t)l * ED_ * D_, ED_, D_);
        pack_wT_perm<<<(64 * 256 + 255) / 256, 256, 0, stream>>>(
            We + (size_t)l * ED_ * D_, weTp16 + (size_t)l * ED_ * D_);
        const float* eW_l = eW + (size_t)l * (2 * D_ + ED_) * ED_;
        pack(eW_l,                        ewsdT16 + (size_t)l * 128 * D_, D_, ED_);
        pack(eW_l + (size_t)D_ * ED_,     ewsdT16 + (size_t)l * 128 * D_ + (size_t)ED_ * D_, D_, ED_);
        pack(eW_l + (size_t)2 * D_ * ED_, ew3T16 + (size_t)l * ED_ * ED_, ED_, ED_);
        pack(jkW + (size_t)l * D_ * D_,   jkwT16 + (size_t)l * D_ * D_, D_, D_);
        hipMemcpyAsync(blr + (size_t)l * 512,       bl + (size_t)l * D_, D_ * 4,
                       hipMemcpyDeviceToDevice, stream);
        hipMemcpyAsync(blr + (size_t)l * 512 + D_,  br + (size_t)l * D_, D_ * 4,
                       hipMemcpyDeviceToDevice, stream);
    }
    pack(gW1, g1T16, D_, 128);

    // ---- CSR build + graph boundaries ----
    hipMemsetAsync(deg_i, 0, (size_t)N_ * 4, stream);
    hipMemsetAsync(fill, 0, (size_t)N_ * 4, stream);
    count_kernel<<<(E_ + 255) / 256, 256, 0, stream>>>(dst, deg_i);
    scan_kernel<<<1, 1024, 0, stream>>>(deg_i, row_off);
    fill_kernel<<<(E_ + 255) / 256, 256, 0, stream>>>(src, dst, row_off, fill,
                                                      perm, srcp, dstp);
    goff_kernel<<<1, 256, 0, stream>>>(batch, goff);

    // encoders
    atom_enc<<<N_, 256, 0, stream>>>(x, atomW, atomB, h16A);
    bond_enc_perm<<<(E_ * ED_ + 255) / 256, 256, 0, stream>>>(eattr, bondW, bondB,
                                                              perm, e16);

    const int MB = (N_ + 63) / 64;  // 313
    const _Float16* h16_prev = h16A;
    for (int l = 0; l < L_; ++l) {
        const float* att_l = att + (size_t)l * H_ * C_;
        const float* bias_l = bias + (size_t)l * D_;
        const float* ln1s_l = ln1s + (size_t)l * D_;
        const float* ln1b_l = ln1b + (size_t)l * D_;
        const float* eb_l = eb + (size_t)l * ED_;
        const float* ln2s_l = ln2s + (size_t)l * ED_;
        const float* ln2b_l = ln2b + (size_t)l * ED_;
        const _Float16* weT_l = weT16 + (size_t)l * ED_ * D_;
        _Float16* hn16_l = (l & 1) ? h16A : h16B;

        // xl|xr projection (single MFMA GEMM, N=512, f16 out with combined bias)
        mfma_gemm16<<<dim3(MB, 8), 256, 0, stream>>>(h16_prev,
                                                     wlrT16 + (size_t)l * 512 * D_,
                                                     blr + (size_t)l * 512,
                                                     xlr16, N_, D_, 512);

        // self-loop: esum16 @ We -> loopW16 (f16)
        esum_kernel<<<(N_ + 3) / 4, 256, 0, stream>>>(e16, row_off, esum16);
        mfma_gemm16<<<dim3(MB, 4), 256, 0, stream>>>(esum16, weT_l, nullptr,
                                                     loopW16, N_, ED_, D_);

        // phase A: fused MFMA edge logits (no-LDS, permuted weights)
        edge_logits_mfma<<<E_ / 64, 256, 0, stream>>>(e16,
                                                      weTp16 + (size_t)l * ED_ * D_,
                                                      xlr16, srcp, dstp, att_l, exlog);

        // phase B: wave-per-dst softmax + aggregation + silu/LN -> hn16
        gat_agg4<<<(N_ + 3) / 4, 256, 0, stream>>>(xlr16, loopW16, row_off, srcp,
                                                   exlog, att_l, bias_l,
                                                   ln1s_l, ln1b_l, hn16_l);

        // edge MLP: hsd16 = hn@[eWs|eWd] (one GEMM), then fused MFMA+LN in-place
        mfma_gemm16<<<dim3(MB, 2), 256, 0, stream>>>(hn16_l,
                                                     ewsdT16 + (size_t)l * 128 * D_,
                                                     nullptr, hsd16, N_, D_, 128);
        edge_mlp_mfma<<<E_ / 64, 256, 0, stream>>>(e16, ew3T16 + (size_t)l * ED_ * ED_,
                                                   hsd16, srcp, dstp,
                                                   eb_l, ln2s_l, ln2b_l);

        // incremental JK: jkacc (+)= hn @ jkW_l (f32 accum)
        mfma_gemm<<<dim3(MB, 4), 256, 0, stream>>>(hn16_l, jkwT16 + (size_t)l * D_ * D_,
                                                   (l == 0) ? jkb : nullptr,
                                                   jkacc, N_, D_, D_, (l == 0) ? 0 : 1);

        h16_prev = hn16_l;
    }

    node_silu_ln<<<N_, 256, 0, stream>>>(jkacc, ln3s, ln3b, hfin, hfin16);

    // gate MLP (MFMA) -> per-node logit -> fused per-graph pool + head
    mfma_gemm<<<dim3(MB, 2), 256, 0, stream>>>(hfin16, g1T16, gb1, hid, N_, D_, 128, 0);
    gate_lite<<<(N_ + 3) / 4, 256, 0, stream>>>(hid, gW2, gb2, g);
    graphpool<<<G_, 256, 0, stream>>>(hfin, g, goff, hW, hb, (float*)d_out);
}

// Round 13
// 1354.313 us; speedup vs baseline: 8.9035x; 1.0192x over previous
//
#include <hip/hip_runtime.h>
#include <hip/hip_bf16.h>

// Problem constants
#define N_ 20000
#define E_ 320000
#define G_ 128
#define H_ 4
#define C_ 64
#define D_ 256
#define ED_ 64
#define L_ 4

typedef _Float16 f16x8 __attribute__((ext_vector_type(8)));
typedef _Float16 f16x4 __attribute__((ext_vector_type(4)));
typedef _Float16 f16x2 __attribute__((ext_vector_type(2)));
typedef float f32x4 __attribute__((ext_vector_type(4)));

// ---------------- encoders ----------------
__global__ __launch_bounds__(256) void atom_enc(const float* __restrict__ x,
                                                const float* __restrict__ W,
                                                const float* __restrict__ b,
                                                _Float16* __restrict__ h16) {
    int n = blockIdx.x, t = threadIdx.x;
    float acc = b[t];
#pragma unroll
    for (int k = 0; k < 9; ++k) acc += x[n * 9 + k] * W[k * D_ + t];
    h16[(size_t)n * D_ + t] = (_Float16)acc;
}

__global__ __launch_bounds__(256) void bond_enc_perm(const float* __restrict__ ea,
                                                     const float* __restrict__ W,
                                                     const float* __restrict__ b,
                                                     const int* __restrict__ perm,
                                                     _Float16* __restrict__ e16) {
    int idx = blockIdx.x * 256 + threadIdx.x;
    if (idx >= E_ * ED_) return;
    int pos = idx >> 6, j = idx & 63;
    int orig = perm[pos];
    float acc = b[j];
#pragma unroll
    for (int k = 0; k < 3; ++k) acc += ea[orig * 3 + k] * W[k * ED_ + j];
    e16[idx] = (_Float16)acc;
}

// ---------------- CSR build (dst-sorted) ----------------
__global__ __launch_bounds__(256) void count_kernel(const int* __restrict__ dst,
                                                    int* __restrict__ deg) {
    int e = blockIdx.x * 256 + threadIdx.x;
    if (e >= E_) return;
    atomicAdd(&deg[dst[e]], 1);
}

__global__ __launch_bounds__(1024) void scan_kernel(const int* __restrict__ deg,
                                                    int* __restrict__ row_off) {
    __shared__ int part[1024];
    int t = threadIdx.x;
    const int CH = (N_ + 1023) / 1024;  // 20
    int s = 0;
    for (int i = 0; i < CH; ++i) {
        int idx = t * CH + i;
        if (idx < N_) s += deg[idx];
    }
    part[t] = s;
    __syncthreads();
    for (int off = 1; off < 1024; off <<= 1) {
        int v = (t >= off) ? part[t - off] : 0;
        __syncthreads();
        part[t] += v;
        __syncthreads();
    }
    int base = (t == 0) ? 0 : part[t - 1];
    for (int i = 0; i < CH; ++i) {
        int idx = t * CH + i;
        if (idx < N_) { row_off[idx] = base; base += deg[idx]; }
    }
    if (t == 0) row_off[N_] = part[1023];
}

__global__ __launch_bounds__(256) void fill_kernel(const int* __restrict__ src,
                                                   const int* __restrict__ dst,
                                                   const int* __restrict__ row_off,
                                                   int* __restrict__ fill,
                                                   int* __restrict__ perm,
                                                   int* __restrict__ srcp,
                                                   int* __restrict__ dstp) {
    int e = blockIdx.x * 256 + threadIdx.x;
    if (e >= E_) return;
    int d = dst[e];
    int pos = row_off[d] + atomicAdd(&fill[d], 1);
    perm[pos] = e;
    srcp[pos] = src[e];
    dstp[pos] = d;
}

// graph boundaries via binary search (batch is sorted ascending)
__global__ __launch_bounds__(256) void goff_kernel(const int* __restrict__ batch,
                                                   int* __restrict__ goff) {
    int t = threadIdx.x;
    if (t > G_) return;
    int lo = 0, hi = N_;
    while (lo < hi) { int mid = (lo + hi) >> 1; if (batch[mid] < t) lo = mid + 1; else hi = mid; }
    goff[t] = lo;
}

// ---------------- weight pre-pack: W[K][N] f32 -> WT[N][K] f16 ----------------
__global__ __launch_bounds__(256) void pack_wT(const float* __restrict__ W,
                                               _Float16* __restrict__ WT,
                                               int K, int Nn) {
    int idx = blockIdx.x * 256 + threadIdx.x;
    if (idx >= K * Nn) return;
    int n = idx / K, k = idx - n * K;
    WT[idx] = (_Float16)W[(size_t)k * Nn + n];
}

// permuted pack for edge_logits: fragment slot q = hw*64 + nt*16 + cgrp holds
// actual col n = hw*64 + cgrp*4 + nt  (K=64, Nn=256 fixed)
__global__ __launch_bounds__(256) void pack_wT_perm(const float* __restrict__ W,
                                                    _Float16* __restrict__ WTp) {
    int idx = blockIdx.x * 256 + threadIdx.x;
    if (idx >= 64 * 256) return;
    int q = idx >> 6, k = idx & 63;
    int hw = q >> 6, qq = q & 63;
    int nt = qq >> 4, cgrp = qq & 15;
    int n = hw * 64 + cgrp * 4 + nt;
    WTp[idx] = (_Float16)W[(size_t)k * 256 + n];
}

// permuted pack, K=64 Nn=64 (for eW3): slot q = nt*16+cgrp <- col cgrp*4+nt
__global__ __launch_bounds__(256) void pack_wT_perm64(const float* __restrict__ W,
                                                      _Float16* __restrict__ WTp) {
    int idx = blockIdx.x * 256 + threadIdx.x;
    if (idx >= 64 * 64) return;
    int q = idx >> 6, k = idx & 63;
    int n = (q & 15) * 4 + (q >> 4);
    WTp[idx] = (_Float16)W[(size_t)k * 64 + n];
}

// ---------------- MFMA f16 GEMM (f32 out, bias, accum) ----------------
__global__ __launch_bounds__(256) void mfma_gemm(const _Float16* __restrict__ A16,
                                                 const _Float16* __restrict__ BT16,
                                                 const float* __restrict__ bias,
                                                 float* __restrict__ C,
                                                 int M, int K, int Nn, int accum) {
    int t = threadIdx.x;
    int w = t >> 6, l = t & 63;
    int bm = blockIdx.x * 64, bn = blockIdx.y * 64;
    int row0 = bm + w * 16 + (l & 15);
    int arow = row0 < M ? row0 : M - 1;
    int koff = (l >> 4) * 8;
    const _Float16* Ap = A16 + (size_t)arow * K + koff;
    f32x4 acc0 = {}, acc1 = {}, acc2 = {}, acc3 = {};
    for (int ks = 0; ks < K; ks += 32) {
        f16x8 a = *(const f16x8*)(Ap + ks);
        const _Float16* Bp = BT16 + (size_t)(bn + (l & 15)) * K + ks + koff;
        f16x8 b0 = *(const f16x8*)(Bp);
        f16x8 b1 = *(const f16x8*)(Bp + (size_t)16 * K);
        f16x8 b2 = *(const f16x8*)(Bp + (size_t)32 * K);
        f16x8 b3 = *(const f16x8*)(Bp + (size_t)48 * K);
        acc0 = __builtin_amdgcn_mfma_f32_16x16x32_f16(a, b0, acc0, 0, 0, 0);
        acc1 = __builtin_amdgcn_mfma_f32_16x16x32_f16(a, b1, acc1, 0, 0, 0);
        acc2 = __builtin_amdgcn_mfma_f32_16x16x32_f16(a, b2, acc2, 0, 0, 0);
        acc3 = __builtin_amdgcn_mfma_f32_16x16x32_f16(a, b3, acc3, 0, 0, 0);
    }
    f32x4 accs[4] = {acc0, acc1, acc2, acc3};
#pragma unroll
    for (int ct = 0; ct < 4; ++ct) {
        int col = bn + ct * 16 + (l & 15);
#pragma unroll
        for (int r = 0; r < 4; ++r) {
            int row = bm + w * 16 + (l >> 4) * 4 + r;
            if (row < M) {
                float v = accs[ct][r] + (bias ? bias[col] : 0.f);
                if (accum) C[(size_t)row * Nn + col] += v;
                else       C[(size_t)row * Nn + col] = v;
            }
        }
    }
}

// ---------------- MFMA f16 GEMM, f16 out, optional bias ----------------
__global__ __launch_bounds__(256) void mfma_gemm16(const _Float16* __restrict__ A16,
                                                   const _Float16* __restrict__ BT16,
                                                   const float* __restrict__ bias,
                                                   _Float16* __restrict__ C16,
                                                   int M, int K, int Nn) {
    int t = threadIdx.x;
    int w = t >> 6, l = t & 63;
    int bm = blockIdx.x * 64, bn = blockIdx.y * 64;
    int row0 = bm + w * 16 + (l & 15);
    int arow = row0 < M ? row0 : M - 1;
    int koff = (l >> 4) * 8;
    const _Float16* Ap = A16 + (size_t)arow * K + koff;
    f32x4 acc0 = {}, acc1 = {}, acc2 = {}, acc3 = {};
    for (int ks = 0; ks < K; ks += 32) {
        f16x8 a = *(const f16x8*)(Ap + ks);
        const _Float16* Bp = BT16 + (size_t)(bn + (l & 15)) * K + ks + koff;
        f16x8 b0 = *(const f16x8*)(Bp);
        f16x8 b1 = *(const f16x8*)(Bp + (size_t)16 * K);
        f16x8 b2 = *(const f16x8*)(Bp + (size_t)32 * K);
        f16x8 b3 = *(const f16x8*)(Bp + (size_t)48 * K);
        acc0 = __builtin_amdgcn_mfma_f32_16x16x32_f16(a, b0, acc0, 0, 0, 0);
        acc1 = __builtin_amdgcn_mfma_f32_16x16x32_f16(a, b1, acc1, 0, 0, 0);
        acc2 = __builtin_amdgcn_mfma_f32_16x16x32_f16(a, b2, acc2, 0, 0, 0);
        acc3 = __builtin_amdgcn_mfma_f32_16x16x32_f16(a, b3, acc3, 0, 0, 0);
    }
    f32x4 accs[4] = {acc0, acc1, acc2, acc3};
#pragma unroll
    for (int ct = 0; ct < 4; ++ct) {
        int col = bn + ct * 16 + (l & 15);
        float bv = bias ? bias[col] : 0.f;
#pragma unroll
        for (int r = 0; r < 4; ++r) {
            int row = bm + w * 16 + (l >> 4) * 4 + r;
            if (row < M) C16[(size_t)row * Nn + col] = (_Float16)(accs[ct][r] + bv);
        }
    }
}

// ---------------- fused MFMA edge logits (no LDS tile, vectorized gathers) ----
__global__ __launch_bounds__(256) void edge_logits_mfma(const _Float16* __restrict__ e16,
                                                        const _Float16* __restrict__ weTp16,
                                                        const _Float16* __restrict__ xlr16,
                                                        const int* __restrict__ srcp,
                                                        const int* __restrict__ dstp,
                                                        const float* __restrict__ att,
                                                        float* __restrict__ exlog) {
    __shared__ int ssrc[64], sdst[64];
    int t = threadIdx.x;
    int w = t >> 6, l = t & 63;
    int base = blockIdx.x * 64;
    if (t < 64) { ssrc[t] = srcp[base + t]; sdst[t] = dstp[base + t]; }
    int koff = (l >> 4) * 8;
    int cgrp = l & 15;
    f16x8 bf[4][2];
#pragma unroll
    for (int nt = 0; nt < 4; ++nt) {
        const _Float16* bp = weTp16 + (size_t)(w * 64 + nt * 16 + cgrp) * 64 + koff;
        bf[nt][0] = *(const f16x8*)(bp);
        bf[nt][1] = *(const f16x8*)(bp + 32);
    }
    float4 av4 = *(const float4*)&att[w * 64 + cgrp * 4];
    float av[4] = {av4.x, av4.y, av4.z, av4.w};
    __syncthreads();
#pragma unroll
    for (int mt = 0; mt < 4; ++mt) {
        const _Float16* ap = e16 + (size_t)(base + mt * 16 + cgrp) * ED_ + koff;
        f16x8 a0 = *(const f16x8*)(ap);
        f16x8 a1 = *(const f16x8*)(ap + 32);
        f32x4 acc[4];
#pragma unroll
        for (int nt = 0; nt < 4; ++nt) {
            f32x4 z = {};
            z = __builtin_amdgcn_mfma_f32_16x16x32_f16(a0, bf[nt][0], z, 0, 0, 0);
            z = __builtin_amdgcn_mfma_f32_16x16x32_f16(a1, bf[nt][1], z, 0, 0, 0);
            acc[nt] = z;
        }
#pragma unroll
        for (int r = 0; r < 4; ++r) {
            int eidx = mt * 16 + (l >> 4) * 4 + r;
            int s = ssrc[eidx], d = sdst[eidx];
            f16x4 xlv = *(const f16x4*)&xlr16[(size_t)s * 512 + w * 64 + cgrp * 4];
            f16x4 xrv = *(const f16x4*)&xlr16[(size_t)d * 512 + 256 + w * 64 + cgrp * 4];
            float v = 0.f;
#pragma unroll
            for (int j = 0; j < 4; ++j) {
                float m = (float)xlv[j] + (float)xrv[j] + acc[j][r];
                m = fmaxf(m, 0.2f * m);   // leaky_relu, branchless
                v += m * av[j];
            }
            v += __shfl_xor(v, 1); v += __shfl_xor(v, 2);
            v += __shfl_xor(v, 4); v += __shfl_xor(v, 8);
            if (cgrp == 0) exlog[(size_t)(base + eidx) * H_ + w] = expf(v);
        }
    }
}

// ---------------- esum16: per-dst segment sum of e rows ----------------
__global__ __launch_bounds__(256) void esum_kernel(const _Float16* __restrict__ e16,
                                                   const int* __restrict__ row_off,
                                                   _Float16* __restrict__ esum16) {
    int d = blockIdx.x * 4 + (threadIdx.x >> 6);
    int lane = threadIdx.x & 63;
    if (d >= N_) return;
    int beg = row_off[d], end = row_off[d + 1];
    float s = 0.f;
    for (int i = beg; i < end; ++i) s += (float)e16[(size_t)i * ED_ + lane];
    esum16[(size_t)d * ED_ + lane] = (_Float16)s;
}

// ---------------- phase B: wave-per-dst softmax + aggregation + silu/LN ------
__global__ __launch_bounds__(256) void gat_agg4(const _Float16* __restrict__ xlr16,
                                                const _Float16* __restrict__ loopW16,
                                                const int* __restrict__ row_off,
                                                const int* __restrict__ srcp,
                                                const float* __restrict__ exlog,
                                                const float* __restrict__ att,
                                                const float* __restrict__ bias,
                                                const float* __restrict__ gs,
                                                const float* __restrict__ gb,
                                                _Float16* __restrict__ hn16) {
    int t = threadIdx.x;
    int w = t >> 6, lane = t & 63;
    int d = blockIdx.x * 4 + w;
    if (d >= N_) return;
    int beg = row_off[d], end = row_off[d + 1];
    int deg = end - beg;
    int hh = lane >> 4;
    float4 av = *(const float4*)&att[lane * 4];
    f16x4 xld_h = *(const f16x4*)&xlr16[(size_t)d * 512 + lane * 4];
    f16x4 xrd_h = *(const f16x4*)&xlr16[(size_t)d * 512 + 256 + lane * 4];
    float xld[4], xrd[4];
#pragma unroll
    for (int j = 0; j < 4; ++j) { xld[j] = (float)xld_h[j]; xrd[j] = (float)xrd_h[j]; }
    float den = 0.f;
    float out[4] = {0.f, 0.f, 0.f, 0.f};
    int i = beg;
    for (; i + 4 <= end; i += 4) {
        int s0 = srcp[i], s1 = srcp[i + 1], s2 = srcp[i + 2], s3 = srcp[i + 3];
        float ex0 = exlog[(size_t)i * H_ + hh];
        float ex1 = exlog[(size_t)(i + 1) * H_ + hh];
        float ex2 = exlog[(size_t)(i + 2) * H_ + hh];
        float ex3 = exlog[(size_t)(i + 3) * H_ + hh];
        f16x4 x0 = *(const f16x4*)&xlr16[(size_t)s0 * 512 + lane * 4];
        f16x4 x1 = *(const f16x4*)&xlr16[(size_t)s1 * 512 + lane * 4];
        f16x4 x2 = *(const f16x4*)&xlr16[(size_t)s2 * 512 + lane * 4];
        f16x4 x3 = *(const f16x4*)&xlr16[(size_t)s3 * 512 + lane * 4];
        den += (ex0 + ex1) + (ex2 + ex3);
#pragma unroll
        for (int j = 0; j < 4; ++j)
            out[j] += ex0 * (float)x0[j] + ex1 * (float)x1[j] +
                      ex2 * (float)x2[j] + ex3 * (float)x3[j];
    }
    for (; i < end; ++i) {
        int s0 = srcp[i];
        float ex0 = exlog[(size_t)i * H_ + hh];
        f16x4 x0 = *(const f16x4*)&xlr16[(size_t)s0 * 512 + lane * 4];
        den += ex0;
#pragma unroll
        for (int j = 0; j < 4; ++j) out[j] += ex0 * (float)x0[j];
    }
    // self loop
    f16x4 lw4 = *(const f16x4*)&loopW16[(size_t)d * D_ + lane * 4];
    float idg = (deg > 0) ? 1.f / (float)deg : 0.f;
    {
        float v = 0.f;
        float avv[4] = {av.x, av.y, av.z, av.w};
#pragma unroll
        for (int j = 0; j < 4; ++j) {
            float m = xld[j] + xrd[j] + (float)lw4[j] * idg;
            m = fmaxf(m, 0.2f * m);
            v += m * avv[j];
        }
        v += __shfl_xor(v, 1); v += __shfl_xor(v, 2);
        v += __shfl_xor(v, 4); v += __shfl_xor(v, 8);  // 16-lane head group
        float eself = expf(v);
        den += eself;
#pragma unroll
        for (int j = 0; j < 4; ++j) out[j] += eself * xld[j];
    }
    float inv = 1.f / (den + 1e-16f);
    float4 b4 = *(const float4*)&bias[lane * 4];
    float bv[4] = {b4.x, b4.y, b4.z, b4.w};
    float v4[4], s = 0.f;
#pragma unroll
    for (int j = 0; j < 4; ++j) {
        float v = out[j] * inv + bv[j];
        v = v / (1.f + expf(-v));
        v4[j] = v;
        s += v;
    }
#pragma unroll
    for (int o = 32; o; o >>= 1) s += __shfl_xor(s, o);
    float mu = s * (1.f / 256.f);
    float q = 0.f;
#pragma unroll
    for (int j = 0; j < 4; ++j) { float dv = v4[j] - mu; q += dv * dv; }
#pragma unroll
    for (int o = 32; o; o >>= 1) q += __shfl_xor(q, o);
    float rs = rsqrtf(q * (1.f / 256.f) + 1e-5f);
    float4 g4 = *(const float4*)&gs[lane * 4];
    float4 gb4 = *(const float4*)&gb[lane * 4];
    f16x4 o4;
    float gsv[4] = {g4.x, g4.y, g4.z, g4.w};
    float gbv[4] = {gb4.x, gb4.y, gb4.z, gb4.w};
#pragma unroll
    for (int j = 0; j < 4; ++j) o4[j] = (_Float16)((v4[j] - mu) * rs * gsv[j] + gbv[j]);
    *(f16x4*)&hn16[(size_t)d * D_ + lane * 4] = o4;
}

// ---------------- fused edge MLP (permuted eW3; vectorized gathers/stores) ----
// Lane's 4 cols are contiguous: col = cgrp*4 + nt. hsd gathers = 2x f16x4;
// eb/gs/gb hoisted float4; e16 store = 1x f16x4 per row (16 lanes -> 128 B).
// LN: the 16-lane group's slots cover all 64 cols (bijection) -> shfl reduce.
__global__ __launch_bounds__(256) void edge_mlp_mfma(_Float16* __restrict__ e16,
                                                     const _Float16* __restrict__ ew3Tp16,
                                                     const _Float16* __restrict__ hsd16,
                                                     const int* __restrict__ srcp,
                                                     const int* __restrict__ dstp,
                                                     const float* __restrict__ eb,
                                                     const float* __restrict__ gs,
                                                     const float* __restrict__ gb) {
    int t = threadIdx.x;
    int w = t >> 6, l = t & 63;
    int bm = blockIdx.x * 64;
    int cgrp = l & 15;
    int arow = bm + w * 16 + cgrp;
    int koff = (l >> 4) * 8;
    const _Float16* Ap = e16 + (size_t)arow * ED_ + koff;
    f16x8 a0 = *(const f16x8*)(Ap);
    f16x8 a1 = *(const f16x8*)(Ap + 32);
    f32x4 acc[4];
#pragma unroll
    for (int nt = 0; nt < 4; ++nt) {
        const _Float16* bp = ew3Tp16 + (size_t)(nt * 16 + cgrp) * 64 + koff;
        f16x8 b0 = *(const f16x8*)(bp);
        f16x8 b1 = *(const f16x8*)(bp + 32);
        f32x4 z = {};
        z = __builtin_amdgcn_mfma_f32_16x16x32_f16(a0, b0, z, 0, 0, 0);
        z = __builtin_amdgcn_mfma_f32_16x16x32_f16(a1, b1, z, 0, 0, 0);
        acc[nt] = z;
    }
    f32x4 ebv = *(const f32x4*)&eb[cgrp * 4];
    f32x4 gsv = *(const f32x4*)&gs[cgrp * 4];
    f32x4 gbv = *(const f32x4*)&gb[cgrp * 4];
    int rbase = bm + w * 16 + (l >> 4) * 4;
#pragma unroll
    for (int r = 0; r < 4; ++r) {
        int row = rbase + r;
        int s = srcp[row], d = dstp[row];
        f16x4 hs = *(const f16x4*)&hsd16[(size_t)s * 128 + cgrp * 4];
        f16x4 hd = *(const f16x4*)&hsd16[(size_t)d * 128 + 64 + cgrp * 4];
        float v4[4], ss = 0.f;
#pragma unroll
        for (int nt = 0; nt < 4; ++nt) {
            float vv = acc[nt][r] + (float)hs[nt] + (float)hd[nt] + ebv[nt];
            vv = vv / (1.f + expf(-vv));
            v4[nt] = vv;
            ss += vv;
        }
        ss += __shfl_xor(ss, 1); ss += __shfl_xor(ss, 2);
        ss += __shfl_xor(ss, 4); ss += __shfl_xor(ss, 8);
        float mu = ss * (1.f / 64.f);
        float q = 0.f;
#pragma unroll
        for (int nt = 0; nt < 4; ++nt) { float dv = v4[nt] - mu; q += dv * dv; }
        q += __shfl_xor(q, 1); q += __shfl_xor(q, 2);
        q += __shfl_xor(q, 4); q += __shfl_xor(q, 8);
        float rsd = rsqrtf(q * (1.f / 64.f) + 1e-5f);
        f16x4 o4;
#pragma unroll
        for (int nt = 0; nt < 4; ++nt)
            o4[nt] = (_Float16)((v4[nt] - mu) * rsd * gsv[nt] + gbv[nt]);
        *(f16x4*)&e16[(size_t)row * ED_ + cgrp * 4] = o4;
    }
}

// ---------------- node silu + LN (final JK output; f32 + f16 outs) ----------
__global__ __launch_bounds__(256) void node_silu_ln(const float* __restrict__ inp,
                                                    const float* __restrict__ gs,
                                                    const float* __restrict__ gb,
                                                    float* __restrict__ outp,
                                                    _Float16* __restrict__ outp16) {
    int n = blockIdx.x, t = threadIdx.x;
    float v = inp[(size_t)n * D_ + t];
    v = v / (1.f + expf(-v));
    __shared__ float red[4];
    float s = v;
#pragma unroll
    for (int o = 32; o; o >>= 1) s += __shfl_xor(s, o);
    if ((t & 63) == 0) red[t >> 6] = s;
    __syncthreads();
    float mu = (red[0] + red[1] + red[2] + red[3]) * (1.f / 256.f);
    __syncthreads();
    float dv = v - mu;
    float q = dv * dv;
#pragma unroll
    for (int o = 32; o; o >>= 1) q += __shfl_xor(q, o);
    if ((t & 63) == 0) red[t >> 6] = q;
    __syncthreads();
    float var = (red[0] + red[1] + red[2] + red[3]) * (1.f / 256.f);
    float r = dv * rsqrtf(var + 1e-5f) * gs[t] + gb[t];
    outp[(size_t)n * D_ + t] = r;
    outp16[(size_t)n * D_ + t] = (_Float16)r;
}

// ---------------- gate lite: silu(hid)·gW2 reduce (no atomics) ---------------
__global__ __launch_bounds__(256) void gate_lite(const _Float16* __restrict__ hid16,
                                                 const float* __restrict__ gW2,
                                                 const float* __restrict__ gb2,
                                                 float* __restrict__ g) {
    int t = threadIdx.x;
    int w = t >> 6, lane = t & 63;
    int n = blockIdx.x * 4 + w;
    if (n >= N_) return;
    f16x2 h2 = *(const f16x2*)&hid16[(size_t)n * 128 + lane * 2];
    float h0 = (float)h2[0], h1 = (float)h2[1];
    float w0 = gW2[lane * 2], w1 = gW2[lane * 2 + 1];
    float s0 = h0 / (1.f + expf(-h0));
    float s1 = h1 / (1.f + expf(-h1));
    float v = s0 * w0 + s1 * w1;
#pragma unroll
    for (int o = 32; o; o >>= 1) v += __shfl_xor(v, o);
    if (lane == 0) g[n] = v + gb2[0];
}

// ---------------- fused per-graph pool: denom + weighted sum + head ----------
__global__ __launch_bounds__(256) void graphpool(const float* __restrict__ hfin,
                                                 const float* __restrict__ g,
                                                 const int* __restrict__ goff,
                                                 const float* __restrict__ hW,
                                                 const float* __restrict__ hb,
                                                 float* __restrict__ out) {
    int b = blockIdx.x, t = threadIdx.x;
    int w = t >> 6, lane = t & 63;
    int beg = goff[b], end = goff[b + 1];
    __shared__ float red[4];
    __shared__ float wls[256];
    float den = 0.f;
    for (int n = beg + t; n < end; n += 256) den += expf(g[n]);
#pragma unroll
    for (int o = 32; o; o >>= 1) den += __shfl_xor(den, o);
    if (lane == 0) red[w] = den;
    __syncthreads();
    float dtot = red[0] + red[1] + red[2] + red[3];
    float inv = 1.f / (dtot + 1e-16f);
    float acc = 0.f;
    for (int c0 = beg; c0 < end; c0 += 256) {
        int nn = min(256, end - c0);
        __syncthreads();
        if (t < nn) wls[t] = expf(g[c0 + t]) * inv;
        __syncthreads();
        for (int j = 0; j < nn; ++j)
            acc += wls[j] * hfin[(size_t)(c0 + j) * D_ + t];
    }
    float v = acc * hW[t];
#pragma unroll
    for (int o = 32; o; o >>= 1) v += __shfl_xor(v, o);
    __syncthreads();
    if (lane == 0) red[w] = v;
    __syncthreads();
    if (t == 0) out[b] = red[0] + red[1] + red[2] + red[3] + hb[0];
}

// ---------------- host launch ----------------
extern "C" void kernel_launch(void* const* d_in, const int* in_sizes, int n_in,
                              void* d_out, int out_size, void* d_ws, size_t ws_size,
                              hipStream_t stream) {
    const float* x     = (const float*)d_in[0];
    const int*   eidx  = (const int*)d_in[1];
    const float* eattr = (const float*)d_in[2];
    const int*   batch = (const int*)d_in[3];
    const float* atomW = (const float*)d_in[4];
    const float* atomB = (const float*)d_in[5];
    const float* bondW = (const float*)d_in[6];
    const float* bondB = (const float*)d_in[7];
    const float* Wl    = (const float*)d_in[8];
    const float* bl    = (const float*)d_in[9];
    const float* Wr    = (const float*)d_in[10];
    const float* br    = (const float*)d_in[11];
    const float* We    = (const float*)d_in[12];
    const float* att   = (const float*)d_in[13];
    const float* bias  = (const float*)d_in[14];
    const float* ln1s  = (const float*)d_in[15];
    const float* ln1b  = (const float*)d_in[16];
    const float* eW    = (const float*)d_in[17];
    const float* eb    = (const float*)d_in[18];
    const float* ln2s  = (const float*)d_in[19];
    const float* ln2b  = (const float*)d_in[20];
    const float* jkW   = (const float*)d_in[21];
    const float* jkb   = (const float*)d_in[22];
    const float* ln3s  = (const float*)d_in[23];
    const float* ln3b  = (const float*)d_in[24];
    const float* gW1   = (const float*)d_in[25];
    const float* gb1   = (const float*)d_in[26];
    const float* gW2   = (const float*)d_in[27];
    const float* gb2   = (const float*)d_in[28];
    const float* hW    = (const float*)d_in[29];
    const float* hb    = (const float*)d_in[30];

    const int* src = eidx;
    const int* dst = eidx + E_;

    // ---- workspace layout ----
    char* wp = (char*)d_ws;
    auto take = [&](size_t bytes) {
        char* p = wp;
        wp += (bytes + 255) & ~(size_t)255;
        return (void*)p;
    };
    _Float16*  e16     = (_Float16*)take((size_t)E_ * ED_ * 2);  // 40.96 MB, CSR-permuted
    _Float16*  xlr16   = (_Float16*)take((size_t)N_ * 512 * 2);  // 20.48 MB (xl|xr packed)
    float*     jkacc   = (float*)take((size_t)N_ * D_ * 4);      // 20.48 MB
    _Float16*  loopW16 = (_Float16*)take((size_t)N_ * D_ * 2);   // 10.24 MB
    float*     hfin    = (float*)take((size_t)N_ * D_ * 4);      // 20.48 MB
    _Float16*  hfin16  = (_Float16*)take((size_t)N_ * D_ * 2);   // 10.24 MB
    _Float16*  hid16   = (_Float16*)take((size_t)N_ * 128 * 2);  // 5.12 MB
    _Float16*  h16A    = (_Float16*)take((size_t)N_ * D_ * 2);   // 10.24 MB
    _Float16*  h16B    = (_Float16*)take((size_t)N_ * D_ * 2);   // 10.24 MB
    _Float16*  hsd16   = (_Float16*)take((size_t)N_ * 128 * 2);  // 5.12 MB (hsW|hdW packed)
    float*     exlog   = (float*)take((size_t)E_ * H_ * 4);      // 5.12 MB
    _Float16*  esum16  = (_Float16*)take((size_t)N_ * ED_ * 2);  // 2.56 MB
    _Float16*  wlrT16  = (_Float16*)take((size_t)L_ * 512 * D_ * 2);
    _Float16*  weT16   = (_Float16*)take((size_t)L_ * ED_ * D_ * 2);
    _Float16*  weTp16  = (_Float16*)take((size_t)L_ * ED_ * D_ * 2);  // permuted (edge_logits)
    _Float16*  ewsdT16 = (_Float16*)take((size_t)L_ * 128 * D_ * 2);
    _Float16*  ew3Tp16 = (_Float16*)take((size_t)L_ * ED_ * ED_ * 2); // permuted (edge_mlp)
    _Float16*  jkwT16  = (_Float16*)take((size_t)L_ * D_ * D_ * 2);
    _Float16*  g1T16   = (_Float16*)take((size_t)D_ * 128 * 2);
    float*     blr     = (float*)take((size_t)L_ * 512 * 4);
    int*   deg_i   = (int*)take((size_t)N_ * 4);
    int*   fill    = (int*)take((size_t)N_ * 4);
    int*   row_off = (int*)take((size_t)(N_ + 1) * 4);
    int*   goff    = (int*)take((size_t)(G_ + 1) * 4);
    int*   perm    = (int*)take((size_t)E_ * 4);
    int*   srcp    = (int*)take((size_t)E_ * 4);
    int*   dstp    = (int*)take((size_t)E_ * 4);
    float* g       = (float*)take((size_t)N_ * 4);

    // ---- weight pre-pack (f32 -> transposed f16) ----
    auto pack = [&](const float* W, _Float16* WT, int K, int Nn) {
        pack_wT<<<(K * Nn + 255) / 256, 256, 0, stream>>>(W, WT, K, Nn);
    };
    for (int l = 0; l < L_; ++l) {
        pack(Wl + (size_t)l * D_ * D_, wlrT16 + (size_t)l * 512 * D_, D_, D_);
        pack(Wr + (size_t)l * D_ * D_, wlrT16 + (size_t)l * 512 * D_ + (size_t)D_ * D_, D_, D_);
        pack(We + (size_t)l * ED_ * D_, weT16 + (size_t)l * ED_ * D_, ED_, D_);
        pack_wT_perm<<<(64 * 256 + 255) / 256, 256, 0, stream>>>(
            We + (size_t)l * ED_ * D_, weTp16 + (size_t)l * ED_ * D_);
        const float* eW_l = eW + (size_t)l * (2 * D_ + ED_) * ED_;
        pack(eW_l,                        ewsdT16 + (size_t)l * 128 * D_, D_, ED_);
        pack(eW_l + (size_t)D_ * ED_,     ewsdT16 + (size_t)l * 128 * D_ + (size_t)ED_ * D_, D_, ED_);
        pack_wT_perm64<<<(64 * 64 + 255) / 256, 256, 0, stream>>>(
            eW_l + (size_t)2 * D_ * ED_, ew3Tp16 + (size_t)l * ED_ * ED_);
        pack(jkW + (size_t)l * D_ * D_,   jkwT16 + (size_t)l * D_ * D_, D_, D_);
        hipMemcpyAsync(blr + (size_t)l * 512,       bl + (size_t)l * D_, D_ * 4,
                       hipMemcpyDeviceToDevice, stream);
        hipMemcpyAsync(blr + (size_t)l * 512 + D_,  br + (size_t)l * D_, D_ * 4,
                       hipMemcpyDeviceToDevice, stream);
    }
    pack(gW1, g1T16, D_, 128);

    // ---- CSR build + graph boundaries ----
    hipMemsetAsync(deg_i, 0, (size_t)N_ * 4, stream);
    hipMemsetAsync(fill, 0, (size_t)N_ * 4, stream);
    count_kernel<<<(E_ + 255) / 256, 256, 0, stream>>>(dst, deg_i);
    scan_kernel<<<1, 1024, 0, stream>>>(deg_i, row_off);
    fill_kernel<<<(E_ + 255) / 256, 256, 0, stream>>>(src, dst, row_off, fill,
                                                      perm, srcp, dstp);
    goff_kernel<<<1, 256, 0, stream>>>(batch, goff);

    // encoders
    atom_enc<<<N_, 256, 0, stream>>>(x, atomW, atomB, h16A);
    bond_enc_perm<<<(E_ * ED_ + 255) / 256, 256, 0, stream>>>(eattr, bondW, bondB,
                                                              perm, e16);

    const int MB = (N_ + 63) / 64;  // 313
    const _Float16* h16_prev = h16A;
    for (int l = 0; l < L_; ++l) {
        const float* att_l = att + (size_t)l * H_ * C_;
        const float* bias_l = bias + (size_t)l * D_;
        const float* ln1s_l = ln1s + (size_t)l * D_;
        const float* ln1b_l = ln1b + (size_t)l * D_;
        const float* eb_l = eb + (size_t)l * ED_;
        const float* ln2s_l = ln2s + (size_t)l * ED_;
        const float* ln2b_l = ln2b + (size_t)l * ED_;
        const _Float16* weT_l = weT16 + (size_t)l * ED_ * D_;
        _Float16* hn16_l = (l & 1) ? h16A : h16B;

        // xl|xr projection (single MFMA GEMM, N=512, f16 out with combined bias)
        mfma_gemm16<<<dim3(MB, 8), 256, 0, stream>>>(h16_prev,
                                                     wlrT16 + (size_t)l * 512 * D_,
                                                     blr + (size_t)l * 512,
                                                     xlr16, N_, D_, 512);

        // self-loop: esum16 @ We -> loopW16 (f16)
        esum_kernel<<<(N_ + 3) / 4, 256, 0, stream>>>(e16, row_off, esum16);
        mfma_gemm16<<<dim3(MB, 4), 256, 0, stream>>>(esum16, weT_l, nullptr,
                                                     loopW16, N_, ED_, D_);

        // phase A: fused MFMA edge logits (no-LDS, permuted weights)
        edge_logits_mfma<<<E_ / 64, 256, 0, stream>>>(e16,
                                                      weTp16 + (size_t)l * ED_ * D_,
                                                      xlr16, srcp, dstp, att_l, exlog);

        // phase B: wave-per-dst softmax + aggregation + silu/LN -> hn16
        gat_agg4<<<(N_ + 3) / 4, 256, 0, stream>>>(xlr16, loopW16, row_off, srcp,
                                                   exlog, att_l, bias_l,
                                                   ln1s_l, ln1b_l, hn16_l);

        // edge MLP: hsd16 = hn@[eWs|eWd] (one GEMM), then fused MFMA+LN in-place
        mfma_gemm16<<<dim3(MB, 2), 256, 0, stream>>>(hn16_l,
                                                     ewsdT16 + (size_t)l * 128 * D_,
                                                     nullptr, hsd16, N_, D_, 128);
        edge_mlp_mfma<<<E_ / 64, 256, 0, stream>>>(e16, ew3Tp16 + (size_t)l * ED_ * ED_,
                                                   hsd16, srcp, dstp,
                                                   eb_l, ln2s_l, ln2b_l);

        // incremental JK: jkacc (+)= hn @ jkW_l (f32 accum)
        mfma_gemm<<<dim3(MB, 4), 256, 0, stream>>>(hn16_l, jkwT16 + (size_t)l * D_ * D_,
                                                   (l == 0) ? jkb : nullptr,
                                                   jkacc, N_, D_, D_, (l == 0) ? 0 : 1);

        h16_prev = hn16_l;
    }

    node_silu_ln<<<N_, 256, 0, stream>>>(jkacc, ln3s, ln3b, hfin, hfin16);

    // gate MLP (MFMA, f16 hid) -> per-node logit -> fused per-graph pool + head
    mfma_gemm16<<<dim3(MB, 2), 256, 0, stream>>>(hfin16, g1T16, gb1, hid16, N_, D_, 128);
    gate_lite<<<(N_ + 3) / 4, 256, 0, stream>>>(hid16, gW2, gb2, g);
    graphpool<<<G_, 256, 0, stream>>>(hfin, g, goff, hW, hb, (float*)d_out);
}